// Round 13
// baseline (368.739 us; speedup 1.0000x reference)
//
#include <hip/hip_runtime.h>
#include <math.h>

// Problem constants
#define CB 2
#define CS 512
#define CD 1024
#define CH 16
#define CHD 64
#define CF 4096
#define CE 8
#define CK 2
#define CT (CB*CS)      // 1024 tokens
#define CBH (CB*CH)     // 32 (batch*heads)
#define CEPS 1e-6f
#define QKVP 3072       // packed q|k|v row pitch
#define MAXROWS 3072    // 2048 + 8*127 padded to 128
#define MAXTILES (MAXROWS/128)

typedef __attribute__((ext_vector_type(8))) short bf16x8;
typedef __attribute__((ext_vector_type(4))) float f32x4;

__device__ __forceinline__ short f2bf(float f) {
  unsigned u = __float_as_uint(f);
  unsigned r = (u + 0x7FFF + ((u >> 16) & 1)) >> 16;
  return (short)r;
}
__device__ __forceinline__ float bf2f(short h) {
  return __uint_as_float(((unsigned)(unsigned short)h) << 16);
}

__device__ __forceinline__ void gload_lds16(const void* g, void* l) {
  __builtin_amdgcn_global_load_lds(
      (const __attribute__((address_space(1))) unsigned int*)g,
      (__attribute__((address_space(3))) unsigned int*)l, 16, 0, 0);
}

// ---------------------------------------------------------------------------
// RMSNorm, hi/lo bf16 planes out.
__global__ __launch_bounds__(256) void rmsnorm_hl_kernel(
    const float* __restrict__ x, const float* __restrict__ w,
    short* __restrict__ outH, short* __restrict__ outL) {
  int t = blockIdx.x;
  int tid = threadIdx.x;
  float4 xv = ((const float4*)(x + (size_t)t * CD))[tid];
  float ss = xv.x*xv.x + xv.y*xv.y + xv.z*xv.z + xv.w*xv.w;
  for (int off = 32; off > 0; off >>= 1) ss += __shfl_down(ss, off);
  __shared__ float red[4];
  __shared__ float s_scale;
  int lane = tid & 63, wid = tid >> 6;
  if (lane == 0) red[wid] = ss;
  __syncthreads();
  if (tid == 0) {
    float tot = red[0] + red[1] + red[2] + red[3];
    s_scale = rsqrtf(tot / (float)CD + CEPS);
  }
  __syncthreads();
  float sc = s_scale;
  float4 wv = ((const float4*)w)[tid];
  float o[4] = {xv.x * sc * wv.x, xv.y * sc * wv.y,
                xv.z * sc * wv.z, xv.w * sc * wv.w};
  short4 hi, lo;
  short* hp = (short*)&hi; short* lp = (short*)&lo;
#pragma unroll
  for (int i = 0; i < 4; ++i) {
    short h = f2bf(o[i]);
    hp[i] = h;
    lp[i] = f2bf(o[i] - bf2f(h));
  }
  ((short4*)(outH + (size_t)t * CD))[tid] = hi;
  ((short4*)(outL + (size_t)t * CD))[tid] = lo;
}

// ---------------------------------------------------------------------------
// Tiled transpose+convert, 64x64 tile, 16B short8 stores:
// W[e][Kd][Nd] f32 -> Wth[e][Nd][Kd] bf16 (+ optional lo plane).
__global__ __launch_bounds__(256) void transpose_convert_kernel(
    const float* __restrict__ W, short* __restrict__ Wth,
    short* __restrict__ Wtl, int Kd, int Nd) {
  int e = blockIdx.z;
  const float* Wb = W + (size_t)e * Kd * Nd;
  size_t obase = (size_t)e * Kd * Nd;
  int n0 = blockIdx.x * 64, k0 = blockIdx.y * 64;
  __shared__ float t[64][65];
  int tid = threadIdx.x;
#pragma unroll
  for (int i = 0; i < 4; ++i) {
    int idx = i * 256 + tid;
    int r = idx >> 4, c4 = (idx & 15) * 4;
    float4 v = *(const float4*)(Wb + (size_t)(k0 + r) * Nd + n0 + c4);
    t[r][c4] = v.x; t[r][c4 + 1] = v.y; t[r][c4 + 2] = v.z; t[r][c4 + 3] = v.w;
  }
  __syncthreads();
  int n = tid >> 2, k16 = (tid & 3) * 16;
  short th[16], tl[16];
#pragma unroll
  for (int j = 0; j < 16; ++j) {
    float v = t[k16 + j][n];
    short hi = f2bf(v);
    th[j] = hi;
    tl[j] = f2bf(v - bf2f(hi));
  }
  size_t oo = obase + (size_t)(n0 + n) * Kd + k0 + k16;
  ((int4*)(Wth + oo))[0] = ((int4*)th)[0];
  ((int4*)(Wth + oo + 8))[0] = ((int4*)th)[1];
  if (Wtl) {
    ((int4*)(Wtl + oo))[0] = ((int4*)tl)[0];
    ((int4*)(Wtl + oo + 8))[0] = ((int4*)tl)[1];
  }
}

// Four DxD transposes (wq,wk,wv,wo) in one launch, z selects.
struct TPtrs {
  const float* w[4];
  short* hh[4];
  short* ll[4];
};
__global__ __launch_bounds__(256) void transpose4_kernel(TPtrs p) {
  int z = blockIdx.z;
  const float* Wb = p.w[z];
  short* Wth = p.hh[z];
  short* Wtl = p.ll[z];
  int n0 = blockIdx.x * 64, k0 = blockIdx.y * 64;
  __shared__ float t[64][65];
  int tid = threadIdx.x;
#pragma unroll
  for (int i = 0; i < 4; ++i) {
    int idx = i * 256 + tid;
    int r = idx >> 4, c4 = (idx & 15) * 4;
    float4 v = *(const float4*)(Wb + (size_t)(k0 + r) * CD + n0 + c4);
    t[r][c4] = v.x; t[r][c4 + 1] = v.y; t[r][c4 + 2] = v.z; t[r][c4 + 3] = v.w;
  }
  __syncthreads();
  int n = tid >> 2, k16 = (tid & 3) * 16;
  short th[16], tl[16];
#pragma unroll
  for (int j = 0; j < 16; ++j) {
    float v = t[k16 + j][n];
    short hi = f2bf(v);
    th[j] = hi;
    tl[j] = f2bf(v - bf2f(hi));
  }
  size_t oo = (size_t)(n0 + n) * CD + k0 + k16;
  ((int4*)(Wth + oo))[0] = ((int4*)th)[0];
  ((int4*)(Wth + oo + 8))[0] = ((int4*)th)[1];
  ((int4*)(Wtl + oo))[0] = ((int4*)tl)[0];
  ((int4*)(Wtl + oo + 8))[0] = ((int4*)tl)[1];
}

__global__ void pack_bias_kernel(const float* __restrict__ bq,
                                 const float* __restrict__ bk,
                                 const float* __restrict__ bv,
                                 float* __restrict__ out) {
  int i = blockIdx.x * 256 + threadIdx.x;
  if (i < QKVP)
    out[i] = (i < 1024) ? bq[i] : (i < 2048 ? bk[i - 1024] : bv[i - 2048]);
}

// ---------------------------------------------------------------------------
// MoE grouped GEMM: BM=128, BN=256, BK=64, 8 waves.
template <int SILU, int OUTBF>
__global__ __launch_bounds__(512) void moe_gemm_kernel(
    const short* __restrict__ A, const short* __restrict__ Bt,
    const float* __restrict__ bias, void* __restrict__ Cout,
    float* __restrict__ part, int partM, int N, int K,
    const int* __restrict__ tile_e, const int* __restrict__ total_rows) {
  __shared__ __align__(16) short A0[128 * 64], A1[128 * 64];
  __shared__ __align__(16) short B0[256 * 64], B1[256 * 64];
  int tid = threadIdx.x;
  int m0 = blockIdx.y * 128, n0 = blockIdx.x * 256;
  if (m0 >= *total_rows) return;
  int e = tile_e[blockIdx.y];
  const short* Bb = Bt + (size_t)e * N * K;
  const float* biasb = bias ? bias + (size_t)e * N : nullptr;
  int kz = blockIdx.z;
  int kchunk = K / gridDim.z;
  int kbeg = kz * kchunk;
  int nsteps = kchunk >> 6;
  int lane = tid & 63, w = tid >> 6;
  int wr = w >> 2, wc = w & 3;
  int l15 = lane & 15, l4 = lane >> 4;
  f32x4 acc[4][4] = {};

#define STAGE(AS_, BS_, KK)                                                   \
  {                                                                           \
    _Pragma("unroll") for (int i = 0; i < 2; ++i) {                           \
      int c = i * 512 + tid;                                                  \
      int r = c >> 3, gs = c & 7;                                             \
      int g = gs ^ (r & 7);                                                   \
      gload_lds16(A + (size_t)(m0 + r) * K + (KK) + g * 8, &AS_[c * 8]);      \
    }                                                                         \
    _Pragma("unroll") for (int i = 0; i < 4; ++i) {                           \
      int c = i * 512 + tid;                                                  \
      int r = c >> 3, gs = c & 7;                                             \
      int g = gs ^ (r & 7);                                                   \
      gload_lds16(Bb + (size_t)(n0 + r) * K + (KK) + g * 8, &BS_[c * 8]);     \
    }                                                                         \
  }

#define COMPUTE(AS_, BS_)                                                     \
  {                                                                           \
    _Pragma("unroll") for (int ks = 0; ks < 2; ++ks) {                        \
      bf16x8 a[4], b[4];                                                      \
      _Pragma("unroll") for (int m = 0; m < 4; ++m) {                         \
        int row = wr * 64 + m * 16 + l15;                                     \
        int slot = (ks * 4 + l4) ^ (row & 7);                                 \
        a[m] = *(const bf16x8*)&AS_[(row * 8 + slot) * 8];                    \
      }                                                                       \
      _Pragma("unroll") for (int n = 0; n < 4; ++n) {                         \
        int row = wc * 64 + n * 16 + l15;                                     \
        int slot = (ks * 4 + l4) ^ (row & 7);                                 \
        b[n] = *(const bf16x8*)&BS_[(row * 8 + slot) * 8];                    \
      }                                                                       \
      _Pragma("unroll") for (int m = 0; m < 4; ++m)                           \
      _Pragma("unroll") for (int n = 0; n < 4; ++n)                           \
        acc[m][n] = __builtin_amdgcn_mfma_f32_16x16x32_bf16(a[m], b[n],       \
                                                            acc[m][n], 0, 0, 0); \
    }                                                                         \
  }

  STAGE(A0, B0, kbeg);
  __syncthreads();
  for (int s = 0; s < nsteps; s += 2) {
    int k0 = kbeg + (s << 6);
    bool has1 = (s + 1 < nsteps), has2 = (s + 2 < nsteps);
    if (has1) STAGE(A1, B1, k0 + 64);
    COMPUTE(A0, B0);
    __syncthreads();
    if (has1) {
      if (has2) STAGE(A0, B0, k0 + 128);
      COMPUTE(A1, B1);
      __syncthreads();
    }
  }
#undef STAGE
#undef COMPUTE

  if (gridDim.z > 1) {
#pragma unroll
    for (int m = 0; m < 4; ++m) {
      int row = m0 + wr * 64 + m * 16 + l4 * 4;
#pragma unroll
      for (int n = 0; n < 4; ++n) {
        int col = n0 + wc * 64 + n * 16 + l15;
#pragma unroll
        for (int q = 0; q < 4; ++q)
          part[((size_t)kz * partM + row + q) * N + col] = acc[m][n][q];
      }
    }
    return;
  }
  float* outf = (float*)Cout;
  short* outb = (short*)Cout;
#pragma unroll
  for (int m = 0; m < 4; ++m) {
    int row = m0 + wr * 64 + m * 16 + l4 * 4;
#pragma unroll
    for (int n = 0; n < 4; ++n) {
      int col = n0 + wc * 64 + n * 16 + l15;
      float bv = biasb[col];
#pragma unroll
      for (int q = 0; q < 4; ++q) {
        float v = acc[m][n][q] + bv;
        if (SILU) v = v / (1.f + __expf(-v));
        if (OUTBF) outb[(size_t)(row + q) * N + col] = f2bf(v);
        else outf[(size_t)(row + q) * N + col] = v;
      }
    }
  }
}

// ---------------------------------------------------------------------------
// Attention MFMA GEMM: 128x128, BK=32, 4 waves, hi/lo reg-staged, split-K.
template <int LO>
__global__ __launch_bounds__(256) void mfma_gemm_kernel(
    const short* __restrict__ Ah, const short* __restrict__ Al,
    const short* __restrict__ Bh, const short* __restrict__ Bl,
    float* __restrict__ part, int partM, int N, int K) {
  __shared__ short As0[4096], Bs0[4096], As1[4096], Bs1[4096];
  __shared__ short Als0[LO ? 4096 : 64], Bls0[LO ? 4096 : 64];
  __shared__ short Als1[LO ? 4096 : 64], Bls1[LO ? 4096 : 64];
  int tid = threadIdx.x;
  int m0 = blockIdx.y * 128, n0 = blockIdx.x * 128;
  int kz = blockIdx.z;
  int kchunk = K / gridDim.z;
  int kbeg = kz * kchunk;
  int nsteps = kchunk >> 5;
  int lane = tid & 63, w = tid >> 6;
  int wr = w >> 1, wc = w & 1;
  int l15 = lane & 15, l4 = lane >> 4;
  int xorl = (l15 & 3) ^ ((l15 >> 2) & 3);
  f32x4 acc[4][4] = {};
  bf16x8 vA0[2], vB0[2], vAl0[2], vBl0[2];
  bf16x8 vA1[2], vB1[2], vAl1[2], vBl1[2];

#define LOAD_SET(VA, VB, VAL, VBL, KK)                                        \
  {                                                                           \
    _Pragma("unroll") for (int ic = 0; ic < 2; ++ic) {                        \
      int c = ic * 256 + tid;                                                 \
      int r = c >> 2, g = c & 3;                                              \
      size_t ao = (size_t)(m0 + r) * K + (KK) + g * 8;                        \
      size_t bo = (size_t)(n0 + r) * K + (KK) + g * 8;                        \
      VA[ic] = *(const bf16x8*)(Ah + ao);                                     \
      VB[ic] = *(const bf16x8*)(Bh + bo);                                     \
      if (LO) {                                                               \
        VAL[ic] = *(const bf16x8*)(Al + ao);                                  \
        VBL[ic] = *(const bf16x8*)(Bl + bo);                                  \
      }                                                                       \
    }                                                                         \
  }

#define WRITE_SET(AS_, BS_, ALS_, BLS_, VA, VB, VAL, VBL)                     \
  {                                                                           \
    _Pragma("unroll") for (int ic = 0; ic < 2; ++ic) {                        \
      int c = ic * 256 + tid;                                                 \
      int r = c >> 2, g = c & 3;                                              \
      int ch = (r * 4 + (g ^ (r & 3) ^ ((r >> 2) & 3))) * 8;                  \
      *(bf16x8*)&AS_[ch] = VA[ic];                                            \
      *(bf16x8*)&BS_[ch] = VB[ic];                                            \
      if (LO) {                                                               \
        *(bf16x8*)&ALS_[ch] = VAL[ic];                                        \
        *(bf16x8*)&BLS_[ch] = VBL[ic];                                        \
      }                                                                       \
    }                                                                         \
  }

#define COMPUTE_SET(AS_, BS_, ALS_, BLS_)                                     \
  {                                                                           \
    bf16x8 ah[4], al[4];                                                      \
    _Pragma("unroll") for (int m = 0; m < 4; ++m) {                           \
      int row = wr * 64 + m * 16 + l15;                                       \
      int idx = (row * 4 + (l4 ^ xorl)) * 8;                                  \
      ah[m] = *(const bf16x8*)&AS_[idx];                                      \
      if (LO) al[m] = *(const bf16x8*)&ALS_[idx];                             \
    }                                                                         \
    _Pragma("unroll") for (int n = 0; n < 4; ++n) {                           \
      int row = wc * 64 + n * 16 + l15;                                       \
      int idx = (row * 4 + (l4 ^ xorl)) * 8;                                  \
      bf16x8 bhn = *(const bf16x8*)&BS_[idx];                                 \
      bf16x8 bln;                                                             \
      if (LO) bln = *(const bf16x8*)&BLS_[idx];                               \
      _Pragma("unroll") for (int m = 0; m < 4; ++m) {                         \
        acc[m][n] = __builtin_amdgcn_mfma_f32_16x16x32_bf16(ah[m], bhn,       \
                                                            acc[m][n], 0, 0, 0); \
        if (LO) {                                                             \
          acc[m][n] = __builtin_amdgcn_mfma_f32_16x16x32_bf16(al[m], bhn,     \
                                                              acc[m][n], 0, 0, 0); \
          acc[m][n] = __builtin_amdgcn_mfma_f32_16x16x32_bf16(ah[m], bln,     \
                                                              acc[m][n], 0, 0, 0); \
        }                                                                     \
      }                                                                       \
    }                                                                         \
  }

  LOAD_SET(vA0, vB0, vAl0, vBl0, kbeg);
  WRITE_SET(As0, Bs0, Als0, Bls0, vA0, vB0, vAl0, vBl0);
  __syncthreads();
  for (int s = 0; s < nsteps; s += 2) {
    int k0 = kbeg + (s << 5);
    bool has1 = (s + 1 < nsteps), has2 = (s + 2 < nsteps);
    if (has1) LOAD_SET(vA1, vB1, vAl1, vBl1, k0 + 32);
    COMPUTE_SET(As0, Bs0, Als0, Bls0);
    if (has1) WRITE_SET(As1, Bs1, Als1, Bls1, vA1, vB1, vAl1, vBl1);
    __syncthreads();
    if (has1) {
      if (has2) LOAD_SET(vA0, vB0, vAl0, vBl0, k0 + 64);
      COMPUTE_SET(As1, Bs1, Als1, Bls1);
      if (has2) WRITE_SET(As0, Bs0, Als0, Bls0, vA0, vB0, vAl0, vBl0);
      __syncthreads();
    }
  }
#undef LOAD_SET
#undef WRITE_SET
#undef COMPUTE_SET

#pragma unroll
  for (int m = 0; m < 4; ++m) {
    int row = m0 + wr * 64 + m * 16 + l4 * 4;
#pragma unroll
    for (int n = 0; n < 4; ++n) {
      int col = n0 + wc * 64 + n * 16 + l15;
#pragma unroll
      for (int q = 0; q < 4; ++q)
        part[((size_t)kz * partM + row + q) * N + col] = acc[m][n][q];
    }
  }
}

// split-K reduce (QKV): out[row][c] = sum_z part[z][row][c] + bias. fp32 out.
__global__ __launch_bounds__(256) void reduce_splitk_kernel(
    const float* __restrict__ part, int partM, int nz,
    const float* __restrict__ bias, float* __restrict__ outp, int N) {
  int row = blockIdx.x;
  for (int c = threadIdx.x * 4; c < N; c += 1024) {
    float4 s = *(const float4*)(part + (size_t)row * N + c);
    for (int z = 1; z < nz; ++z) {
      float4 p = *(const float4*)(part + ((size_t)z * partM + row) * N + c);
      s.x += p.x; s.y += p.y; s.z += p.z; s.w += p.w;
    }
    s.x += bias[c]; s.y += bias[c + 1]; s.z += bias[c + 2]; s.w += bias[c + 3];
    *(float4*)(outp + (size_t)row * N + c) = s;
  }
}

// ---------------------------------------------------------------------------
// Attention epilogue (fused): WO split-K reduce + residual + rmsnorm2 + router.
__global__ __launch_bounds__(256) void attn_epilogue_kernel(
    const float* __restrict__ part, const float* __restrict__ bo,
    const float* __restrict__ x, const float* __restrict__ n2w,
    const float* __restrict__ wr, const float* __restrict__ br,
    float* __restrict__ x1, float* __restrict__ h2, int* __restrict__ top_i,
    float* __restrict__ top_p, float* __restrict__ probs_out) {
  int t = blockIdx.x;
  int tid = threadIdx.x;
  int c = tid * 4;
  float4 s = *(const float4*)(part + (size_t)t * CD + c);
#pragma unroll
  for (int z = 1; z < 4; ++z) {
    float4 p = *(const float4*)(part + ((size_t)z * CT + t) * CD + c);
    s.x += p.x; s.y += p.y; s.z += p.z; s.w += p.w;
  }
  float4 bv = *(const float4*)(bo + c);
  float4 xv = *(const float4*)(x + (size_t)t * CD + c);
  s.x += bv.x + xv.x; s.y += bv.y + xv.y;
  s.z += bv.z + xv.z; s.w += bv.w + xv.w;
  *(float4*)(x1 + (size_t)t * CD + c) = s;
  float ss = s.x*s.x + s.y*s.y + s.z*s.z + s.w*s.w;
  for (int off = 32; off > 0; off >>= 1) ss += __shfl_down(ss, off);
  __shared__ float red[4];
  __shared__ float s_scale;
  int lane = tid & 63, wid = tid >> 6;
  if (lane == 0) red[wid] = ss;
  __syncthreads();
  if (tid == 0) {
    float tot = red[0] + red[1] + red[2] + red[3];
    s_scale = rsqrtf(tot / (float)CD + CEPS);
  }
  __syncthreads();
  float sc = s_scale;
  float4 wv = *(const float4*)(n2w + c);
  float hv[4] = {s.x * sc * wv.x, s.y * sc * wv.y,
                 s.z * sc * wv.z, s.w * sc * wv.w};
  *(float4*)(h2 + (size_t)t * CD + c) =
      make_float4(hv[0], hv[1], hv[2], hv[3]);
  float a[CE] = {};
#pragma unroll
  for (int j = 0; j < 4; ++j) {
    const float* wrow = wr + (size_t)(c + j) * CE;
#pragma unroll
    for (int e = 0; e < CE; ++e) a[e] += hv[j] * wrow[e];
  }
  __shared__ float red8[256][CE];
#pragma unroll
  for (int e = 0; e < CE; ++e) red8[tid][e] = a[e];
  __syncthreads();
  for (int st = 128; st > 0; st >>= 1) {
    if (tid < st) {
#pragma unroll
      for (int e = 0; e < CE; ++e) red8[tid][e] += red8[tid + st][e];
    }
    __syncthreads();
  }
  if (tid == 0) {
    float probs[CE];
    float mx = -1e30f;
#pragma unroll
    for (int e = 0; e < CE; ++e) {
      probs[e] = red8[0][e] + br[e];
      mx = fmaxf(mx, probs[e]);
    }
    float sum = 0.f;
#pragma unroll
    for (int e = 0; e < CE; ++e) { probs[e] = __expf(probs[e] - mx); sum += probs[e]; }
    float inv = 1.0f / sum;
#pragma unroll
    for (int e = 0; e < CE; ++e) {
      probs[e] *= inv;
      probs_out[t * CE + e] = probs[e];
    }
    int i1 = 0;
#pragma unroll
    for (int e = 1; e < CE; ++e) if (probs[e] > probs[i1]) i1 = e;
    int i2 = (i1 == 0) ? 1 : 0;
#pragma unroll
    for (int e = 0; e < CE; ++e)
      if (e != i1 && probs[e] > probs[i2]) i2 = e;
    float p1 = probs[i1], p2 = probs[i2];
    float s12 = p1 + p2;
    top_i[t * 2 + 0] = i1;
    top_i[t * 2 + 1] = i2;
    top_p[t * 2 + 0] = p1 / s12;
    top_p[t * 2 + 1] = p2 / s12;
  }
}

// ---------------------------------------------------------------------------
// Fused attention v4 (flash-style): 32 q-rows x one (b,h) per block,
// 128 threads, per-thread 4 rows x 4 cols (2x fewer LDS reads per FMA than
// v3's 4x2). Wave = 4 rg x 16 cg; row-reduce via __shfl_xor<=8 stays in the
// 16-lane cg group. V/Pt accessed as float4 (2-way = free); K stride 65.
// fp32 throughout; numerics identical to v3.
__global__ __launch_bounds__(128) void fused_attn_kernel(
    const float* __restrict__ qkv, short* __restrict__ ctxh,
    short* __restrict__ ctxl) {
  __shared__ float Qs[32][68];   // Q tile
  __shared__ float Ks[64 * 65];  // K row-major, stride 65
  __shared__ float Vs[64][68];   // V row-major
  __shared__ float Pt[32][68];   // per-tile P (float4-aligned cols)
  int qt = blockIdx.x, bh = blockIdx.y;
  int b = bh / CH, h = bh % CH;
  int qrow0 = qt * 32;
  int ktmax = (qrow0 + 31) >> 6;
  int tid = threadIdx.x;
  int cg = tid & 15, rg = tid >> 4;  // 16 col-groups x 8 row-groups
  int r0 = rg * 4;
  int c0 = cg * 4;

  // stage Q [32][64]: 512 float4 over 128 threads
#pragma unroll
  for (int it = 0; it < 4; ++it) {
    int idx = it * 128 + tid;
    int r = idx >> 4, c4 = (idx & 15) * 4;
    *(float4*)&Qs[r][c4] = *(const float4*)(
        qkv + (size_t)(b * CS + qrow0 + r) * QKVP + h * CHD + c4);
  }

  float m_i[4], l_i[4];
  float O[4][4] = {};
#pragma unroll
  for (int i = 0; i < 4; ++i) {
    m_i[i] = -1e30f;
    l_i[i] = 0.f;
  }

  for (int kt = 0; kt <= ktmax; ++kt) {
    __syncthreads();  // prev tile's Pt/Vs reads done before overwrite
    // stage K (scalar, stride 65) and V (float4, stride 68): 1024 float4 each
#pragma unroll
    for (int it = 0; it < 8; ++it) {
      int idx = it * 128 + tid;
      int r = idx >> 4, c4 = (idx & 15) * 4;
      const float* src =
          qkv + (size_t)(b * CS + kt * 64 + r) * QKVP + h * CHD;
      float4 kv = *(const float4*)(src + 1024 + c4);
      Ks[r * 65 + c4 + 0] = kv.x;
      Ks[r * 65 + c4 + 1] = kv.y;
      Ks[r * 65 + c4 + 2] = kv.z;
      Ks[r * 65 + c4 + 3] = kv.w;
      *(float4*)&Vs[r][c4] = *(const float4*)(src + 2048 + c4);
    }
    __syncthreads();

    // scores: s[4 rows][4 cols]
    float s[4][4] = {};
#pragma unroll 4
    for (int d = 0; d < 64; ++d) {
      float q0 = Qs[r0 + 0][d];
      float q1 = Qs[r0 + 1][d];
      float q2 = Qs[r0 + 2][d];
      float q3 = Qs[r0 + 3][d];
      float k0 = Ks[(c0 + 0) * 65 + d];
      float k1 = Ks[(c0 + 1) * 65 + d];
      float k2 = Ks[(c0 + 2) * 65 + d];
      float k3 = Ks[(c0 + 3) * 65 + d];
      s[0][0] += q0 * k0; s[0][1] += q0 * k1; s[0][2] += q0 * k2; s[0][3] += q0 * k3;
      s[1][0] += q1 * k0; s[1][1] += q1 * k1; s[1][2] += q1 * k2; s[1][3] += q1 * k3;
      s[2][0] += q2 * k0; s[2][1] += q2 * k1; s[2][2] += q2 * k2; s[2][3] += q2 * k3;
      s[3][0] += q3 * k0; s[3][1] += q3 * k1; s[3][2] += q3 * k2; s[3][3] += q3 * k3;
    }

    // online softmax update (per row, reduce over 16-lane cg group)
#pragma unroll
    for (int i = 0; i < 4; ++i) {
      int gr = qrow0 + r0 + i;
      int gc0 = kt * 64 + c0;
      float sv[4];
#pragma unroll
      for (int j = 0; j < 4; ++j)
        sv[j] = (gc0 + j > gr) ? -1e30f : s[i][j] * 0.125f;
      float tmax = fmaxf(fmaxf(sv[0], sv[1]), fmaxf(sv[2], sv[3]));
#pragma unroll
      for (int off = 8; off > 0; off >>= 1)
        tmax = fmaxf(tmax, __shfl_xor(tmax, off));
      float newm = fmaxf(m_i[i], tmax);
      float p[4];
      float tsum = 0.f;
#pragma unroll
      for (int j = 0; j < 4; ++j) {
        p[j] = __expf(sv[j] - newm);
        tsum += p[j];
      }
#pragma unroll
      for (int off = 8; off > 0; off >>= 1) tsum += __shfl_xor(tsum, off);
      float scale = __expf(m_i[i] - newm);
      l_i[i] = l_i[i] * scale + tsum;
      m_i[i] = newm;
#pragma unroll
      for (int j = 0; j < 4; ++j) O[i][j] *= scale;
      *(float4*)&Pt[r0 + i][c0] = make_float4(p[0], p[1], p[2], p[3]);
    }
    __syncthreads();

    // PV: O[i][j] += sum_c Pt[row][c] * V[c][c0+j]
#pragma unroll 4
    for (int c = 0; c < 64; ++c) {
      float p0 = Pt[r0 + 0][c];
      float p1 = Pt[r0 + 1][c];
      float p2 = Pt[r0 + 2][c];
      float p3 = Pt[r0 + 3][c];
      float4 v4 = *(const float4*)&Vs[c][c0];
      float v[4] = {v4.x, v4.y, v4.z, v4.w};
#pragma unroll
      for (int j = 0; j < 4; ++j) {
        O[0][j] += p0 * v[j];
        O[1][j] += p1 * v[j];
        O[2][j] += p2 * v[j];
        O[3][j] += p3 * v[j];
      }
    }
  }

  // epilogue: normalize by l, write hi/lo bf16 planes
#pragma unroll
  for (int i = 0; i < 4; ++i) {
    float inv = 1.0f / l_i[i];
#pragma unroll
    for (int j = 0; j < 4; ++j) {
      int dv = c0 + j;
      size_t oi = (size_t)(b * CS + qrow0 + r0 + i) * CD + h * CHD + dv;
      float v = O[i][j] * inv;
      short hi = f2bf(v);
      ctxh[oi] = hi;
      ctxl[oi] = f2bf(v - bf2f(hi));
    }
  }
}

// ---------------------------------------------------------------------------
// Finalize (1 block): counts/psum, offsets, tile map, aux loss, cursor clear.
__global__ __launch_bounds__(256) void finalize_kernel(
    const int* __restrict__ top_i, const float* __restrict__ probs,
    int* __restrict__ offs, int* __restrict__ tile_e,
    int* __restrict__ total_padded, int* __restrict__ row_map,
    int* __restrict__ cursor, float* __restrict__ aux_out) {
  int tid = threadIdx.x;
  __shared__ float redp[256][CE];
  __shared__ int redc[256][CE];
  float lp[CE] = {};
  int lc[CE] = {};
  for (int t = tid; t < CT; t += 256) {
    lc[top_i[t * 2 + 0]]++;
    lc[top_i[t * 2 + 1]]++;
#pragma unroll
    for (int e = 0; e < CE; ++e) lp[e] += probs[t * CE + e];
  }
#pragma unroll
  for (int e = 0; e < CE; ++e) { redp[tid][e] = lp[e]; redc[tid][e] = lc[e]; }
  __syncthreads();
  for (int s = 128; s > 0; s >>= 1) {
    if (tid < s) {
#pragma unroll
      for (int e = 0; e < CE; ++e) {
        redp[tid][e] += redp[tid + s][e];
        redc[tid][e] += redc[tid + s][e];
      }
    }
    __syncthreads();
  }
  __shared__ int s_off[CE + 1];
  if (tid == 0) {
    int o = 0;
    for (int e = 0; e < CE; ++e) {
      s_off[e] = o;
      offs[e] = o;
      o += ((redc[0][e] + 127) >> 7) << 7;
    }
    s_off[CE] = o;
    offs[CE] = o;
    *total_padded = o;
    int nt = o >> 7;
    for (int i = 0; i < nt; ++i) {
      int e = 0;
      while (e < CE - 1 && i * 128 >= s_off[e + 1]) e++;
      tile_e[i] = e;
    }
    float aux = 0.f;
    for (int e = 0; e < CE; ++e)
      aux += ((float)redc[0][e] / (float)(CT * CK)) * (redp[0][e] / (float)CT);
    aux_out[0] = aux * (float)CE;
  }
  if (tid < CE) cursor[tid] = 0;
  __syncthreads();
  for (int i = tid; i < MAXROWS; i += blockDim.x) row_map[i] = -1;
}

__global__ void gather_kernel(const int* __restrict__ top_i,
                              const int* __restrict__ offs,
                              int* __restrict__ cursor, int* __restrict__ row_map,
                              int* __restrict__ row_of) {
  int idx = blockIdx.x * blockDim.x + threadIdx.x;
  if (idx >= CT * CK) return;
  int e = top_i[idx];
  int pos = offs[e] + atomicAdd(&cursor[e], 1);
  row_map[pos] = idx >> 1;
  row_of[idx] = pos;
}

// Xg[row] = bf16(h2[row_map[row]]) or zeros for pad rows.
__global__ __launch_bounds__(256) void gatherx_kernel(
    const float* __restrict__ h2, const int* __restrict__ row_map,
    short* __restrict__ Xg) {
  int row = blockIdx.x;
  int tid = threadIdx.x;
  int tok = row_map[row];
  short4 o;
  if (tok < 0) {
    o = make_short4(0, 0, 0, 0);
  } else {
    float4 v = ((const float4*)(h2 + (size_t)tok * CD))[tid];
    o = make_short4(f2bf(v.x), f2bf(v.y), f2bf(v.z), f2bf(v.w));
  }
  ((short4*)(Xg + (size_t)row * CD))[tid] = o;
}

// Fused GEMM2-reduce + combine: per token, read only its 2 routed rows'
// partials, add b2[e], weight, residual.
__global__ __launch_bounds__(256) void combine_g2_kernel(
    const float* __restrict__ part, int partM, int nz,
    const float* __restrict__ b2, const int* __restrict__ tile_e,
    const int* __restrict__ row_of, const float* __restrict__ top_p,
    const float* __restrict__ x1, float* __restrict__ out) {
  int t = blockIdx.x;
  int c = threadIdx.x * 4;
  float4 r = *(const float4*)(x1 + (size_t)t * CD + c);
#pragma unroll
  for (int s = 0; s < CK; ++s) {
    int row = row_of[t * 2 + s];
    int e = tile_e[row >> 7];
    float w = top_p[t * 2 + s];
    float4 acc = *(const float4*)(part + (size_t)row * CD + c);
    for (int z = 1; z < nz; ++z) {
      float4 p = *(const float4*)(part + ((size_t)z * partM + row) * CD + c);
      acc.x += p.x; acc.y += p.y; acc.z += p.z; acc.w += p.w;
    }
    float4 bv = *(const float4*)(b2 + (size_t)e * CD + c);
    r.x += w * (acc.x + bv.x);
    r.y += w * (acc.y + bv.y);
    r.z += w * (acc.z + bv.z);
    r.w += w * (acc.w + bv.w);
  }
  *(float4*)(out + (size_t)t * CD + c) = r;
}

// ---------------------------------------------------------------------------
extern "C" void kernel_launch(void* const* d_in, const int* in_sizes, int n_in,
                              void* d_out, int out_size, void* d_ws,
                              size_t ws_size, hipStream_t stream) {
  const float* x   = (const float*)d_in[0];
  const float* n1w = (const float*)d_in[1];
  const float* n2w = (const float*)d_in[2];
  const float* wq  = (const float*)d_in[3];
  const float* bq  = (const float*)d_in[4];
  const float* wk  = (const float*)d_in[5];
  const float* bk  = (const float*)d_in[6];
  const float* wv  = (const float*)d_in[7];
  const float* bv  = (const float*)d_in[8];
  const float* wo  = (const float*)d_in[9];
  const float* bo  = (const float*)d_in[10];
  const float* wr  = (const float*)d_in[11];
  const float* br  = (const float*)d_in[12];
  const float* w1  = (const float*)d_in[13];
  const float* b1  = (const float*)d_in[14];
  const float* w2  = (const float*)d_in[15];
  const float* b2  = (const float*)d_in[16];
  float* out = (float*)d_out;

  char* base = (char*)d_ws;
  size_t off = 0;
  auto alloc = [&](size_t bytes) -> void* {
    void* p = base + off;
    off += (bytes + 255) & ~(size_t)255;
    return p;
  };
  float* f_x1   = (float*)alloc((size_t)CT * CD * 4);
  float* f_h2   = (float*)alloc((size_t)CT * CD * 4);
  short* f_xg   = (short*)alloc((size_t)MAXROWS * CD * 2);
  short* f_hid  = (short*)alloc((size_t)MAXROWS * CF * 2);
  short* f_hh   = (short*)alloc((size_t)CT * CD * 2);
  short* f_hl   = (short*)alloc((size_t)CT * CD * 2);
  short* f_wqkvh = (short*)alloc((size_t)QKVP * CD * 2);
  short* f_wqkvl = (short*)alloc((size_t)QKVP * CD * 2);
  float* f_qkv  = (float*)alloc((size_t)CT * QKVP * 4);
  short* f_ctxh = (short*)alloc((size_t)CT * CD * 2);
  short* f_ctxl = (short*)alloc((size_t)CT * CD * 2);
  short* f_woth = (short*)alloc((size_t)CD * CD * 2);
  short* f_wotl = (short*)alloc((size_t)CD * CD * 2);
  float* f_bqkv = (float*)alloc(QKVP * 4);
  float* f_topp = (float*)alloc(CT * CK * 4);
  float* f_probs = (float*)alloc(CT * CE * 4);
  int* i_topi   = (int*)alloc(CT * CK * 4);
  int* i_rowof  = (int*)alloc(CT * CK * 4);
  int* i_rowmap = (int*)alloc(MAXROWS * 4);
  int* i_cursor = (int*)alloc(CE * 4);
  int* i_offs   = (int*)alloc((CE + 1) * 4);
  int* i_tile   = (int*)alloc(MAXTILES * 4);
  int* i_total  = (int*)alloc(4);
  // G (64MB): w1t -> w2t (sequential reuse)
  short* f_wG = (short*)alloc((size_t)CE * CD * CF * 2);
  short* f_w1t = f_wG;
  short* f_w2t = f_wG;
  // Rs (48MB): QKV partials -> WO partials -> GEMM2 partials (disjoint)
  void* Rs = alloc((size_t)4 * MAXROWS * CD * 4);
  float* f_partqkv = (float*)Rs;
  float* f_partwo = (float*)Rs;
  float* f_partg2 = (float*)Rs;

  dim3 b256(256);

  pack_bias_kernel<<<QKVP / 256, b256, 0, stream>>>(bq, bk, bv, f_bqkv);
  TPtrs tp;
  tp.w[0] = wq; tp.w[1] = wk; tp.w[2] = wv; tp.w[3] = wo;
  tp.hh[0] = f_wqkvh + 0 * (size_t)CD * CD;
  tp.hh[1] = f_wqkvh + 1 * (size_t)CD * CD;
  tp.hh[2] = f_wqkvh + 2 * (size_t)CD * CD;
  tp.hh[3] = f_woth;
  tp.ll[0] = f_wqkvl + 0 * (size_t)CD * CD;
  tp.ll[1] = f_wqkvl + 1 * (size_t)CD * CD;
  tp.ll[2] = f_wqkvl + 2 * (size_t)CD * CD;
  tp.ll[3] = f_wotl;
  transpose4_kernel<<<dim3(16, 16, 4), b256, 0, stream>>>(tp);
  transpose_convert_kernel<<<dim3(CF / 64, CD / 64, CE), b256, 0, stream>>>(
      w1, f_w1t, nullptr, CD, CF);

  // ---- attention ----
  rmsnorm_hl_kernel<<<CT, b256, 0, stream>>>(x, n1w, f_hh, f_hl);
  mfma_gemm_kernel<1><<<dim3(QKVP / 128, CT / 128, 2), b256, 0, stream>>>(
      f_hh, f_hl, f_wqkvh, f_wqkvl, f_partqkv, CT, QKVP, CD);
  reduce_splitk_kernel<<<CT, b256, 0, stream>>>(f_partqkv, CT, 2, f_bqkv,
                                                f_qkv, QKVP);
  fused_attn_kernel<<<dim3(CS / 32, CBH), dim3(128), 0, stream>>>(
      f_qkv, f_ctxh, f_ctxl);
  mfma_gemm_kernel<1><<<dim3(CD / 128, CT / 128, 4), b256, 0, stream>>>(
      f_ctxh, f_ctxl, f_woth, f_wotl, f_partwo, CT, CD, CD);
  attn_epilogue_kernel<<<CT, b256, 0, stream>>>(f_partwo, bo, x, n2w, wr, br,
                                                f_x1, f_h2, i_topi, f_topp,
                                                f_probs);

  // ---- MoE ----
  finalize_kernel<<<1, 256, 0, stream>>>(i_topi, f_probs, i_offs, i_tile,
                                         i_total, i_rowmap, i_cursor,
                                         out + (size_t)CT * CD);
  gather_kernel<<<(CT * CK + 255) / 256, b256, 0, stream>>>(i_topi, i_offs,
                                                            i_cursor, i_rowmap,
                                                            i_rowof);
  gatherx_kernel<<<MAXROWS, b256, 0, stream>>>(f_h2, i_rowmap, f_xg);

  moe_gemm_kernel<1, 1><<<dim3(CF / 256, MAXTILES, 1), dim3(512), 0, stream>>>(
      f_xg, f_w1t, b1, f_hid, nullptr, 0, CF, CD, i_tile, i_total);
  transpose_convert_kernel<<<dim3(CD / 64, CF / 64, CE), b256, 0, stream>>>(
      w2, f_w2t, nullptr, CF, CD);
  moe_gemm_kernel<0, 0><<<dim3(CD / 256, MAXTILES, 4), dim3(512), 0, stream>>>(
      f_hid, f_w2t, nullptr, nullptr, f_partg2, MAXROWS, CD, CF, i_tile,
      i_total);
  combine_g2_kernel<<<CT, b256, 0, stream>>>(f_partg2, MAXROWS, 4, b2, i_tile,
                                             i_rowof, f_topp, f_x1, out);
}

// Round 14
// 351.608 us; speedup vs baseline: 1.0487x; 1.0487x over previous
//
#include <hip/hip_runtime.h>
#include <math.h>

// Problem constants
#define CB 2
#define CS 512
#define CD 1024
#define CH 16
#define CHD 64
#define CF 4096
#define CE 8
#define CK 2
#define CT (CB*CS)      // 1024 tokens
#define CBH (CB*CH)     // 32 (batch*heads)
#define CEPS 1e-6f
#define QKVP 3072       // packed q|k|v row pitch
#define MAXROWS 3072    // 2048 + 8*127 padded to 128
#define MAXTILES (MAXROWS/128)

typedef __attribute__((ext_vector_type(8))) short bf16x8;
typedef __attribute__((ext_vector_type(4))) float f32x4;

__device__ __forceinline__ short f2bf(float f) {
  unsigned u = __float_as_uint(f);
  unsigned r = (u + 0x7FFF + ((u >> 16) & 1)) >> 16;
  return (short)r;
}
__device__ __forceinline__ float bf2f(short h) {
  return __uint_as_float(((unsigned)(unsigned short)h) << 16);
}

__device__ __forceinline__ void gload_lds16(const void* g, void* l) {
  __builtin_amdgcn_global_load_lds(
      (const __attribute__((address_space(1))) unsigned int*)g,
      (__attribute__((address_space(3))) unsigned int*)l, 16, 0, 0);
}

// ---------------------------------------------------------------------------
// RMSNorm, hi/lo bf16 planes out.
__global__ __launch_bounds__(256) void rmsnorm_hl_kernel(
    const float* __restrict__ x, const float* __restrict__ w,
    short* __restrict__ outH, short* __restrict__ outL) {
  int t = blockIdx.x;
  int tid = threadIdx.x;
  float4 xv = ((const float4*)(x + (size_t)t * CD))[tid];
  float ss = xv.x*xv.x + xv.y*xv.y + xv.z*xv.z + xv.w*xv.w;
  for (int off = 32; off > 0; off >>= 1) ss += __shfl_down(ss, off);
  __shared__ float red[4];
  __shared__ float s_scale;
  int lane = tid & 63, wid = tid >> 6;
  if (lane == 0) red[wid] = ss;
  __syncthreads();
  if (tid == 0) {
    float tot = red[0] + red[1] + red[2] + red[3];
    s_scale = rsqrtf(tot / (float)CD + CEPS);
  }
  __syncthreads();
  float sc = s_scale;
  float4 wv = ((const float4*)w)[tid];
  float o[4] = {xv.x * sc * wv.x, xv.y * sc * wv.y,
                xv.z * sc * wv.z, xv.w * sc * wv.w};
  short4 hi, lo;
  short* hp = (short*)&hi; short* lp = (short*)&lo;
#pragma unroll
  for (int i = 0; i < 4; ++i) {
    short h = f2bf(o[i]);
    hp[i] = h;
    lp[i] = f2bf(o[i] - bf2f(h));
  }
  ((short4*)(outH + (size_t)t * CD))[tid] = hi;
  ((short4*)(outL + (size_t)t * CD))[tid] = lo;
}

// ---------------------------------------------------------------------------
// Tiled transpose+convert, 64x64 tile, 16B short8 stores:
// W[e][Kd][Nd] f32 -> Wth[e][Nd][Kd] bf16 (+ optional lo plane).
__global__ __launch_bounds__(256) void transpose_convert_kernel(
    const float* __restrict__ W, short* __restrict__ Wth,
    short* __restrict__ Wtl, int Kd, int Nd) {
  int e = blockIdx.z;
  const float* Wb = W + (size_t)e * Kd * Nd;
  size_t obase = (size_t)e * Kd * Nd;
  int n0 = blockIdx.x * 64, k0 = blockIdx.y * 64;
  __shared__ float t[64][65];
  int tid = threadIdx.x;
#pragma unroll
  for (int i = 0; i < 4; ++i) {
    int idx = i * 256 + tid;
    int r = idx >> 4, c4 = (idx & 15) * 4;
    float4 v = *(const float4*)(Wb + (size_t)(k0 + r) * Nd + n0 + c4);
    t[r][c4] = v.x; t[r][c4 + 1] = v.y; t[r][c4 + 2] = v.z; t[r][c4 + 3] = v.w;
  }
  __syncthreads();
  int n = tid >> 2, k16 = (tid & 3) * 16;
  short th[16], tl[16];
#pragma unroll
  for (int j = 0; j < 16; ++j) {
    float v = t[k16 + j][n];
    short hi = f2bf(v);
    th[j] = hi;
    tl[j] = f2bf(v - bf2f(hi));
  }
  size_t oo = obase + (size_t)(n0 + n) * Kd + k0 + k16;
  ((int4*)(Wth + oo))[0] = ((int4*)th)[0];
  ((int4*)(Wth + oo + 8))[0] = ((int4*)th)[1];
  if (Wtl) {
    ((int4*)(Wtl + oo))[0] = ((int4*)tl)[0];
    ((int4*)(Wtl + oo + 8))[0] = ((int4*)tl)[1];
  }
}

// Four DxD transposes (wq,wk,wv,wo) in one launch, z selects.
struct TPtrs {
  const float* w[4];
  short* hh[4];
  short* ll[4];
};
__global__ __launch_bounds__(256) void transpose4_kernel(TPtrs p) {
  int z = blockIdx.z;
  const float* Wb = p.w[z];
  short* Wth = p.hh[z];
  short* Wtl = p.ll[z];
  int n0 = blockIdx.x * 64, k0 = blockIdx.y * 64;
  __shared__ float t[64][65];
  int tid = threadIdx.x;
#pragma unroll
  for (int i = 0; i < 4; ++i) {
    int idx = i * 256 + tid;
    int r = idx >> 4, c4 = (idx & 15) * 4;
    float4 v = *(const float4*)(Wb + (size_t)(k0 + r) * CD + n0 + c4);
    t[r][c4] = v.x; t[r][c4 + 1] = v.y; t[r][c4 + 2] = v.z; t[r][c4 + 3] = v.w;
  }
  __syncthreads();
  int n = tid >> 2, k16 = (tid & 3) * 16;
  short th[16], tl[16];
#pragma unroll
  for (int j = 0; j < 16; ++j) {
    float v = t[k16 + j][n];
    short hi = f2bf(v);
    th[j] = hi;
    tl[j] = f2bf(v - bf2f(hi));
  }
  size_t oo = (size_t)(n0 + n) * CD + k0 + k16;
  ((int4*)(Wth + oo))[0] = ((int4*)th)[0];
  ((int4*)(Wth + oo + 8))[0] = ((int4*)th)[1];
  ((int4*)(Wtl + oo))[0] = ((int4*)tl)[0];
  ((int4*)(Wtl + oo + 8))[0] = ((int4*)tl)[1];
}

__global__ void pack_bias_kernel(const float* __restrict__ bq,
                                 const float* __restrict__ bk,
                                 const float* __restrict__ bv,
                                 float* __restrict__ out) {
  int i = blockIdx.x * 256 + threadIdx.x;
  if (i < QKVP)
    out[i] = (i < 1024) ? bq[i] : (i < 2048 ? bk[i - 1024] : bv[i - 2048]);
}

// ---------------------------------------------------------------------------
// MoE grouped GEMM: BM=128, BN=256, BK=64, 8 waves.
template <int SILU, int OUTBF>
__global__ __launch_bounds__(512) void moe_gemm_kernel(
    const short* __restrict__ A, const short* __restrict__ Bt,
    const float* __restrict__ bias, void* __restrict__ Cout,
    float* __restrict__ part, int partM, int N, int K,
    const int* __restrict__ tile_e, const int* __restrict__ total_rows) {
  __shared__ __align__(16) short A0[128 * 64], A1[128 * 64];
  __shared__ __align__(16) short B0[256 * 64], B1[256 * 64];
  int tid = threadIdx.x;
  int m0 = blockIdx.y * 128, n0 = blockIdx.x * 256;
  if (m0 >= *total_rows) return;
  int e = tile_e[blockIdx.y];
  const short* Bb = Bt + (size_t)e * N * K;
  const float* biasb = bias ? bias + (size_t)e * N : nullptr;
  int kz = blockIdx.z;
  int kchunk = K / gridDim.z;
  int kbeg = kz * kchunk;
  int nsteps = kchunk >> 6;
  int lane = tid & 63, w = tid >> 6;
  int wr = w >> 2, wc = w & 3;
  int l15 = lane & 15, l4 = lane >> 4;
  f32x4 acc[4][4] = {};

#define STAGE(AS_, BS_, KK)                                                   \
  {                                                                           \
    _Pragma("unroll") for (int i = 0; i < 2; ++i) {                           \
      int c = i * 512 + tid;                                                  \
      int r = c >> 3, gs = c & 7;                                             \
      int g = gs ^ (r & 7);                                                   \
      gload_lds16(A + (size_t)(m0 + r) * K + (KK) + g * 8, &AS_[c * 8]);      \
    }                                                                         \
    _Pragma("unroll") for (int i = 0; i < 4; ++i) {                           \
      int c = i * 512 + tid;                                                  \
      int r = c >> 3, gs = c & 7;                                             \
      int g = gs ^ (r & 7);                                                   \
      gload_lds16(Bb + (size_t)(n0 + r) * K + (KK) + g * 8, &BS_[c * 8]);     \
    }                                                                         \
  }

#define COMPUTE(AS_, BS_)                                                     \
  {                                                                           \
    _Pragma("unroll") for (int ks = 0; ks < 2; ++ks) {                        \
      bf16x8 a[4], b[4];                                                      \
      _Pragma("unroll") for (int m = 0; m < 4; ++m) {                         \
        int row = wr * 64 + m * 16 + l15;                                     \
        int slot = (ks * 4 + l4) ^ (row & 7);                                 \
        a[m] = *(const bf16x8*)&AS_[(row * 8 + slot) * 8];                    \
      }                                                                       \
      _Pragma("unroll") for (int n = 0; n < 4; ++n) {                         \
        int row = wc * 64 + n * 16 + l15;                                     \
        int slot = (ks * 4 + l4) ^ (row & 7);                                 \
        b[n] = *(const bf16x8*)&BS_[(row * 8 + slot) * 8];                    \
      }                                                                       \
      _Pragma("unroll") for (int m = 0; m < 4; ++m)                           \
      _Pragma("unroll") for (int n = 0; n < 4; ++n)                           \
        acc[m][n] = __builtin_amdgcn_mfma_f32_16x16x32_bf16(a[m], b[n],       \
                                                            acc[m][n], 0, 0, 0); \
    }                                                                         \
  }

  STAGE(A0, B0, kbeg);
  __syncthreads();
  for (int s = 0; s < nsteps; s += 2) {
    int k0 = kbeg + (s << 6);
    bool has1 = (s + 1 < nsteps), has2 = (s + 2 < nsteps);
    if (has1) STAGE(A1, B1, k0 + 64);
    COMPUTE(A0, B0);
    __syncthreads();
    if (has1) {
      if (has2) STAGE(A0, B0, k0 + 128);
      COMPUTE(A1, B1);
      __syncthreads();
    }
  }
#undef STAGE
#undef COMPUTE

  if (gridDim.z > 1) {
#pragma unroll
    for (int m = 0; m < 4; ++m) {
      int row = m0 + wr * 64 + m * 16 + l4 * 4;
#pragma unroll
      for (int n = 0; n < 4; ++n) {
        int col = n0 + wc * 64 + n * 16 + l15;
#pragma unroll
        for (int q = 0; q < 4; ++q)
          part[((size_t)kz * partM + row + q) * N + col] = acc[m][n][q];
      }
    }
    return;
  }
  float* outf = (float*)Cout;
  short* outb = (short*)Cout;
#pragma unroll
  for (int m = 0; m < 4; ++m) {
    int row = m0 + wr * 64 + m * 16 + l4 * 4;
#pragma unroll
    for (int n = 0; n < 4; ++n) {
      int col = n0 + wc * 64 + n * 16 + l15;
      float bv = biasb[col];
#pragma unroll
      for (int q = 0; q < 4; ++q) {
        float v = acc[m][n][q] + bv;
        if (SILU) v = v / (1.f + __expf(-v));
        if (OUTBF) outb[(size_t)(row + q) * N + col] = f2bf(v);
        else outf[(size_t)(row + q) * N + col] = v;
      }
    }
  }
}

// ---------------------------------------------------------------------------
// Attention MFMA GEMM: 128x128, BK=32, 4 waves, hi/lo reg-staged, split-K.
template <int LO>
__global__ __launch_bounds__(256) void mfma_gemm_kernel(
    const short* __restrict__ Ah, const short* __restrict__ Al,
    const short* __restrict__ Bh, const short* __restrict__ Bl,
    float* __restrict__ part, int partM, int N, int K) {
  __shared__ short As0[4096], Bs0[4096], As1[4096], Bs1[4096];
  __shared__ short Als0[LO ? 4096 : 64], Bls0[LO ? 4096 : 64];
  __shared__ short Als1[LO ? 4096 : 64], Bls1[LO ? 4096 : 64];
  int tid = threadIdx.x;
  int m0 = blockIdx.y * 128, n0 = blockIdx.x * 128;
  int kz = blockIdx.z;
  int kchunk = K / gridDim.z;
  int kbeg = kz * kchunk;
  int nsteps = kchunk >> 5;
  int lane = tid & 63, w = tid >> 6;
  int wr = w >> 1, wc = w & 1;
  int l15 = lane & 15, l4 = lane >> 4;
  int xorl = (l15 & 3) ^ ((l15 >> 2) & 3);
  f32x4 acc[4][4] = {};
  bf16x8 vA0[2], vB0[2], vAl0[2], vBl0[2];
  bf16x8 vA1[2], vB1[2], vAl1[2], vBl1[2];

#define LOAD_SET(VA, VB, VAL, VBL, KK)                                        \
  {                                                                           \
    _Pragma("unroll") for (int ic = 0; ic < 2; ++ic) {                        \
      int c = ic * 256 + tid;                                                 \
      int r = c >> 2, g = c & 3;                                              \
      size_t ao = (size_t)(m0 + r) * K + (KK) + g * 8;                        \
      size_t bo = (size_t)(n0 + r) * K + (KK) + g * 8;                        \
      VA[ic] = *(const bf16x8*)(Ah + ao);                                     \
      VB[ic] = *(const bf16x8*)(Bh + bo);                                     \
      if (LO) {                                                               \
        VAL[ic] = *(const bf16x8*)(Al + ao);                                  \
        VBL[ic] = *(const bf16x8*)(Bl + bo);                                  \
      }                                                                       \
    }                                                                         \
  }

#define WRITE_SET(AS_, BS_, ALS_, BLS_, VA, VB, VAL, VBL)                     \
  {                                                                           \
    _Pragma("unroll") for (int ic = 0; ic < 2; ++ic) {                        \
      int c = ic * 256 + tid;                                                 \
      int r = c >> 2, g = c & 3;                                              \
      int ch = (r * 4 + (g ^ (r & 3) ^ ((r >> 2) & 3))) * 8;                  \
      *(bf16x8*)&AS_[ch] = VA[ic];                                            \
      *(bf16x8*)&BS_[ch] = VB[ic];                                            \
      if (LO) {                                                               \
        *(bf16x8*)&ALS_[ch] = VAL[ic];                                        \
        *(bf16x8*)&BLS_[ch] = VBL[ic];                                        \
      }                                                                       \
    }                                                                         \
  }

#define COMPUTE_SET(AS_, BS_, ALS_, BLS_)                                     \
  {                                                                           \
    bf16x8 ah[4], al[4];                                                      \
    _Pragma("unroll") for (int m = 0; m < 4; ++m) {                           \
      int row = wr * 64 + m * 16 + l15;                                       \
      int idx = (row * 4 + (l4 ^ xorl)) * 8;                                  \
      ah[m] = *(const bf16x8*)&AS_[idx];                                      \
      if (LO) al[m] = *(const bf16x8*)&ALS_[idx];                             \
    }                                                                         \
    _Pragma("unroll") for (int n = 0; n < 4; ++n) {                           \
      int row = wc * 64 + n * 16 + l15;                                       \
      int idx = (row * 4 + (l4 ^ xorl)) * 8;                                  \
      bf16x8 bhn = *(const bf16x8*)&BS_[idx];                                 \
      bf16x8 bln;                                                             \
      if (LO) bln = *(const bf16x8*)&BLS_[idx];                               \
      _Pragma("unroll") for (int m = 0; m < 4; ++m) {                         \
        acc[m][n] = __builtin_amdgcn_mfma_f32_16x16x32_bf16(ah[m], bhn,       \
                                                            acc[m][n], 0, 0, 0); \
        if (LO) {                                                             \
          acc[m][n] = __builtin_amdgcn_mfma_f32_16x16x32_bf16(al[m], bhn,     \
                                                              acc[m][n], 0, 0, 0); \
          acc[m][n] = __builtin_amdgcn_mfma_f32_16x16x32_bf16(ah[m], bln,     \
                                                              acc[m][n], 0, 0, 0); \
        }                                                                     \
      }                                                                       \
    }                                                                         \
  }

  LOAD_SET(vA0, vB0, vAl0, vBl0, kbeg);
  WRITE_SET(As0, Bs0, Als0, Bls0, vA0, vB0, vAl0, vBl0);
  __syncthreads();
  for (int s = 0; s < nsteps; s += 2) {
    int k0 = kbeg + (s << 5);
    bool has1 = (s + 1 < nsteps), has2 = (s + 2 < nsteps);
    if (has1) LOAD_SET(vA1, vB1, vAl1, vBl1, k0 + 32);
    COMPUTE_SET(As0, Bs0, Als0, Bls0);
    if (has1) WRITE_SET(As1, Bs1, Als1, Bls1, vA1, vB1, vAl1, vBl1);
    __syncthreads();
    if (has1) {
      if (has2) LOAD_SET(vA0, vB0, vAl0, vBl0, k0 + 64);
      COMPUTE_SET(As1, Bs1, Als1, Bls1);
      if (has2) WRITE_SET(As0, Bs0, Als0, Bls0, vA0, vB0, vAl0, vBl0);
      __syncthreads();
    }
  }
#undef LOAD_SET
#undef WRITE_SET
#undef COMPUTE_SET

#pragma unroll
  for (int m = 0; m < 4; ++m) {
    int row = m0 + wr * 64 + m * 16 + l4 * 4;
#pragma unroll
    for (int n = 0; n < 4; ++n) {
      int col = n0 + wc * 64 + n * 16 + l15;
#pragma unroll
      for (int q = 0; q < 4; ++q)
        part[((size_t)kz * partM + row + q) * N + col] = acc[m][n][q];
    }
  }
}

// split-K reduce (QKV): out[row][c] = sum_z part[z][row][c] + bias. fp32 out.
__global__ __launch_bounds__(256) void reduce_splitk_kernel(
    const float* __restrict__ part, int partM, int nz,
    const float* __restrict__ bias, float* __restrict__ outp, int N) {
  int row = blockIdx.x;
  for (int c = threadIdx.x * 4; c < N; c += 1024) {
    float4 s = *(const float4*)(part + (size_t)row * N + c);
    for (int z = 1; z < nz; ++z) {
      float4 p = *(const float4*)(part + ((size_t)z * partM + row) * N + c);
      s.x += p.x; s.y += p.y; s.z += p.z; s.w += p.w;
    }
    s.x += bias[c]; s.y += bias[c + 1]; s.z += bias[c + 2]; s.w += bias[c + 3];
    *(float4*)(outp + (size_t)row * N + c) = s;
  }
}

// ---------------------------------------------------------------------------
// Attention epilogue (fused): WO split-K reduce + residual + rmsnorm2 + router.
__global__ __launch_bounds__(256) void attn_epilogue_kernel(
    const float* __restrict__ part, const float* __restrict__ bo,
    const float* __restrict__ x, const float* __restrict__ n2w,
    const float* __restrict__ wr, const float* __restrict__ br,
    float* __restrict__ x1, float* __restrict__ h2, int* __restrict__ top_i,
    float* __restrict__ top_p, float* __restrict__ probs_out) {
  int t = blockIdx.x;
  int tid = threadIdx.x;
  int c = tid * 4;
  float4 s = *(const float4*)(part + (size_t)t * CD + c);
#pragma unroll
  for (int z = 1; z < 4; ++z) {
    float4 p = *(const float4*)(part + ((size_t)z * CT + t) * CD + c);
    s.x += p.x; s.y += p.y; s.z += p.z; s.w += p.w;
  }
  float4 bv = *(const float4*)(bo + c);
  float4 xv = *(const float4*)(x + (size_t)t * CD + c);
  s.x += bv.x + xv.x; s.y += bv.y + xv.y;
  s.z += bv.z + xv.z; s.w += bv.w + xv.w;
  *(float4*)(x1 + (size_t)t * CD + c) = s;
  float ss = s.x*s.x + s.y*s.y + s.z*s.z + s.w*s.w;
  for (int off = 32; off > 0; off >>= 1) ss += __shfl_down(ss, off);
  __shared__ float red[4];
  __shared__ float s_scale;
  int lane = tid & 63, wid = tid >> 6;
  if (lane == 0) red[wid] = ss;
  __syncthreads();
  if (tid == 0) {
    float tot = red[0] + red[1] + red[2] + red[3];
    s_scale = rsqrtf(tot / (float)CD + CEPS);
  }
  __syncthreads();
  float sc = s_scale;
  float4 wv = *(const float4*)(n2w + c);
  float hv[4] = {s.x * sc * wv.x, s.y * sc * wv.y,
                 s.z * sc * wv.z, s.w * sc * wv.w};
  *(float4*)(h2 + (size_t)t * CD + c) =
      make_float4(hv[0], hv[1], hv[2], hv[3]);
  float a[CE] = {};
#pragma unroll
  for (int j = 0; j < 4; ++j) {
    const float* wrow = wr + (size_t)(c + j) * CE;
#pragma unroll
    for (int e = 0; e < CE; ++e) a[e] += hv[j] * wrow[e];
  }
  __shared__ float red8[256][CE];
#pragma unroll
  for (int e = 0; e < CE; ++e) red8[tid][e] = a[e];
  __syncthreads();
  for (int st = 128; st > 0; st >>= 1) {
    if (tid < st) {
#pragma unroll
      for (int e = 0; e < CE; ++e) red8[tid][e] += red8[tid + st][e];
    }
    __syncthreads();
  }
  if (tid == 0) {
    float probs[CE];
    float mx = -1e30f;
#pragma unroll
    for (int e = 0; e < CE; ++e) {
      probs[e] = red8[0][e] + br[e];
      mx = fmaxf(mx, probs[e]);
    }
    float sum = 0.f;
#pragma unroll
    for (int e = 0; e < CE; ++e) { probs[e] = __expf(probs[e] - mx); sum += probs[e]; }
    float inv = 1.0f / sum;
#pragma unroll
    for (int e = 0; e < CE; ++e) {
      probs[e] *= inv;
      probs_out[t * CE + e] = probs[e];
    }
    int i1 = 0;
#pragma unroll
    for (int e = 1; e < CE; ++e) if (probs[e] > probs[i1]) i1 = e;
    int i2 = (i1 == 0) ? 1 : 0;
#pragma unroll
    for (int e = 0; e < CE; ++e)
      if (e != i1 && probs[e] > probs[i2]) i2 = e;
    float p1 = probs[i1], p2 = probs[i2];
    float s12 = p1 + p2;
    top_i[t * 2 + 0] = i1;
    top_i[t * 2 + 1] = i2;
    top_p[t * 2 + 0] = p1 / s12;
    top_p[t * 2 + 1] = p2 / s12;
  }
}

// ---------------------------------------------------------------------------
// Fused attention v5: v3 structure (256 threads, 4 rows x 2 cols/thread,
// flash-style online softmax) with K/V TIME-SHARING one LDS buffer (K only
// read in scores phase, V only in PV phase) -> LDS 34.6KB -> 4 blocks/CU
// (16 waves, +33% vs v3/v4). K at stride 65 (scalar writes/reads 2-way);
// V at stride 68 (float4 writes, scalar col reads conflict-free).
// fp32 throughout; numerics identical to v3 (same op order).
__global__ __launch_bounds__(256) void fused_attn_kernel(
    const float* __restrict__ qkv, short* __restrict__ ctxh,
    short* __restrict__ ctxl) {
  __shared__ float Qs[32][68];    // Q tile
  __shared__ float KVs[64 * 68];  // K (stride 65) then V (stride 68)
  __shared__ float Pt[32][66];    // per-tile P
  int qt = blockIdx.x, bh = blockIdx.y;
  int b = bh / CH, h = bh % CH;
  int qrow0 = qt * 32;
  int ktmax = (qrow0 + 31) >> 6;
  int tid = threadIdx.x;
  int cg = tid & 31, rg = tid >> 5;
  int r0 = rg * 4;

  // stage Q [32][64]
#pragma unroll
  for (int it = 0; it < 2; ++it) {
    int idx = it * 256 + tid;
    int r = idx >> 4, c4 = (idx & 15) * 4;
    *(float4*)&Qs[r][c4] = *(const float4*)(
        qkv + (size_t)(b * CS + qrow0 + r) * QKVP + h * CHD + c4);
  }

  float m_i[4], l_i[4], O[4][2];
#pragma unroll
  for (int i = 0; i < 4; ++i) {
    m_i[i] = -1e30f;
    l_i[i] = 0.f;
    O[i][0] = 0.f;
    O[i][1] = 0.f;
  }

  for (int kt = 0; kt <= ktmax; ++kt) {
    __syncthreads();  // prev tile's PV reads of KVs(V)/Pt done
    // stage K (scalar, stride 65)
#pragma unroll
    for (int it = 0; it < 4; ++it) {
      int idx = it * 256 + tid;
      int r = idx >> 4, c4 = (idx & 15) * 4;
      const float* src =
          qkv + (size_t)(b * CS + kt * 64 + r) * QKVP + h * CHD;
      float4 kv = *(const float4*)(src + 1024 + c4);
      KVs[r * 65 + c4 + 0] = kv.x;
      KVs[r * 65 + c4 + 1] = kv.y;
      KVs[r * 65 + c4 + 2] = kv.z;
      KVs[r * 65 + c4 + 3] = kv.w;
    }
    __syncthreads();

    // scores: s[4 rows][2 cols]
    float s[4][2] = {};
#pragma unroll 4
    for (int d = 0; d < 64; ++d) {
      float q0 = Qs[r0 + 0][d];
      float q1 = Qs[r0 + 1][d];
      float q2 = Qs[r0 + 2][d];
      float q3 = Qs[r0 + 3][d];
      float k0 = KVs[(cg * 2 + 0) * 65 + d];
      float k1 = KVs[(cg * 2 + 1) * 65 + d];
      s[0][0] += q0 * k0; s[0][1] += q0 * k1;
      s[1][0] += q1 * k0; s[1][1] += q1 * k1;
      s[2][0] += q2 * k0; s[2][1] += q2 * k1;
      s[3][0] += q3 * k0; s[3][1] += q3 * k1;
    }

    // online softmax update (per row, reduce over 32-lane col group)
#pragma unroll
    for (int i = 0; i < 4; ++i) {
      int gr = qrow0 + r0 + i;
      int gc0 = kt * 64 + cg * 2;
      float s0 = (gc0 + 0 > gr) ? -1e30f : s[i][0] * 0.125f;
      float s1 = (gc0 + 1 > gr) ? -1e30f : s[i][1] * 0.125f;
      float tmax = fmaxf(s0, s1);
#pragma unroll
      for (int off = 16; off > 0; off >>= 1)
        tmax = fmaxf(tmax, __shfl_xor(tmax, off));
      float newm = fmaxf(m_i[i], tmax);
      float p0 = __expf(s0 - newm);
      float p1 = __expf(s1 - newm);
      float tsum = p0 + p1;
#pragma unroll
      for (int off = 16; off > 0; off >>= 1) tsum += __shfl_xor(tsum, off);
      float scale = __expf(m_i[i] - newm);
      l_i[i] = l_i[i] * scale + tsum;
      m_i[i] = newm;
      O[i][0] *= scale;
      O[i][1] *= scale;
      Pt[r0 + i][cg * 2 + 0] = p0;
      Pt[r0 + i][cg * 2 + 1] = p1;
    }
    __syncthreads();  // all K reads + Pt writes done

    // stage V into the same buffer (float4, stride 68)
#pragma unroll
    for (int it = 0; it < 4; ++it) {
      int idx = it * 256 + tid;
      int r = idx >> 4, c4 = (idx & 15) * 4;
      *(float4*)&KVs[r * 68 + c4] = *(const float4*)(
          qkv + (size_t)(b * CS + kt * 64 + r) * QKVP + 2048 + h * CHD + c4);
    }
    __syncthreads();

    // PV: O[i][jd] += sum_c Pt[row][c] * V[c][cg + 32*jd]
#pragma unroll 4
    for (int c = 0; c < 64; ++c) {
      float p0 = Pt[r0 + 0][c];
      float p1 = Pt[r0 + 1][c];
      float p2 = Pt[r0 + 2][c];
      float p3 = Pt[r0 + 3][c];
      float v0 = KVs[c * 68 + cg];
      float v1 = KVs[c * 68 + cg + 32];
      O[0][0] += p0 * v0; O[0][1] += p0 * v1;
      O[1][0] += p1 * v0; O[1][1] += p1 * v1;
      O[2][0] += p2 * v0; O[2][1] += p2 * v1;
      O[3][0] += p3 * v0; O[3][1] += p3 * v1;
    }
  }

  // epilogue: normalize by l, write hi/lo bf16 planes
#pragma unroll
  for (int i = 0; i < 4; ++i) {
    float inv = 1.0f / l_i[i];
#pragma unroll
    for (int jd = 0; jd < 2; ++jd) {
      int dv = cg + 32 * jd;
      size_t oi = (size_t)(b * CS + qrow0 + r0 + i) * CD + h * CHD + dv;
      float v = O[i][jd] * inv;
      short hi = f2bf(v);
      ctxh[oi] = hi;
      ctxl[oi] = f2bf(v - bf2f(hi));
    }
  }
}

// ---------------------------------------------------------------------------
// Finalize (1 block): counts/psum, offsets, tile map, aux loss, cursor clear.
__global__ __launch_bounds__(256) void finalize_kernel(
    const int* __restrict__ top_i, const float* __restrict__ probs,
    int* __restrict__ offs, int* __restrict__ tile_e,
    int* __restrict__ total_padded, int* __restrict__ row_map,
    int* __restrict__ cursor, float* __restrict__ aux_out) {
  int tid = threadIdx.x;
  __shared__ float redp[256][CE];
  __shared__ int redc[256][CE];
  float lp[CE] = {};
  int lc[CE] = {};
  for (int t = tid; t < CT; t += 256) {
    lc[top_i[t * 2 + 0]]++;
    lc[top_i[t * 2 + 1]]++;
#pragma unroll
    for (int e = 0; e < CE; ++e) lp[e] += probs[t * CE + e];
  }
#pragma unroll
  for (int e = 0; e < CE; ++e) { redp[tid][e] = lp[e]; redc[tid][e] = lc[e]; }
  __syncthreads();
  for (int s = 128; s > 0; s >>= 1) {
    if (tid < s) {
#pragma unroll
      for (int e = 0; e < CE; ++e) {
        redp[tid][e] += redp[tid + s][e];
        redc[tid][e] += redc[tid + s][e];
      }
    }
    __syncthreads();
  }
  __shared__ int s_off[CE + 1];
  if (tid == 0) {
    int o = 0;
    for (int e = 0; e < CE; ++e) {
      s_off[e] = o;
      offs[e] = o;
      o += ((redc[0][e] + 127) >> 7) << 7;
    }
    s_off[CE] = o;
    offs[CE] = o;
    *total_padded = o;
    int nt = o >> 7;
    for (int i = 0; i < nt; ++i) {
      int e = 0;
      while (e < CE - 1 && i * 128 >= s_off[e + 1]) e++;
      tile_e[i] = e;
    }
    float aux = 0.f;
    for (int e = 0; e < CE; ++e)
      aux += ((float)redc[0][e] / (float)(CT * CK)) * (redp[0][e] / (float)CT);
    aux_out[0] = aux * (float)CE;
  }
  if (tid < CE) cursor[tid] = 0;
  __syncthreads();
  for (int i = tid; i < MAXROWS; i += blockDim.x) row_map[i] = -1;
}

__global__ void gather_kernel(const int* __restrict__ top_i,
                              const int* __restrict__ offs,
                              int* __restrict__ cursor, int* __restrict__ row_map,
                              int* __restrict__ row_of) {
  int idx = blockIdx.x * blockDim.x + threadIdx.x;
  if (idx >= CT * CK) return;
  int e = top_i[idx];
  int pos = offs[e] + atomicAdd(&cursor[e], 1);
  row_map[pos] = idx >> 1;
  row_of[idx] = pos;
}

// Xg[row] = bf16(h2[row_map[row]]) or zeros for pad rows.
__global__ __launch_bounds__(256) void gatherx_kernel(
    const float* __restrict__ h2, const int* __restrict__ row_map,
    short* __restrict__ Xg) {
  int row = blockIdx.x;
  int tid = threadIdx.x;
  int tok = row_map[row];
  short4 o;
  if (tok < 0) {
    o = make_short4(0, 0, 0, 0);
  } else {
    float4 v = ((const float4*)(h2 + (size_t)tok * CD))[tid];
    o = make_short4(f2bf(v.x), f2bf(v.y), f2bf(v.z), f2bf(v.w));
  }
  ((short4*)(Xg + (size_t)row * CD))[tid] = o;
}

// Fused GEMM2-reduce + combine: per token, read only its 2 routed rows'
// partials, add b2[e], weight, residual.
__global__ __launch_bounds__(256) void combine_g2_kernel(
    const float* __restrict__ part, int partM, int nz,
    const float* __restrict__ b2, const int* __restrict__ tile_e,
    const int* __restrict__ row_of, const float* __restrict__ top_p,
    const float* __restrict__ x1, float* __restrict__ out) {
  int t = blockIdx.x;
  int c = threadIdx.x * 4;
  float4 r = *(const float4*)(x1 + (size_t)t * CD + c);
#pragma unroll
  for (int s = 0; s < CK; ++s) {
    int row = row_of[t * 2 + s];
    int e = tile_e[row >> 7];
    float w = top_p[t * 2 + s];
    float4 acc = *(const float4*)(part + (size_t)row * CD + c);
    for (int z = 1; z < nz; ++z) {
      float4 p = *(const float4*)(part + ((size_t)z * partM + row) * CD + c);
      acc.x += p.x; acc.y += p.y; acc.z += p.z; acc.w += p.w;
    }
    float4 bv = *(const float4*)(b2 + (size_t)e * CD + c);
    r.x += w * (acc.x + bv.x);
    r.y += w * (acc.y + bv.y);
    r.z += w * (acc.z + bv.z);
    r.w += w * (acc.w + bv.w);
  }
  *(float4*)(out + (size_t)t * CD + c) = r;
}

// ---------------------------------------------------------------------------
extern "C" void kernel_launch(void* const* d_in, const int* in_sizes, int n_in,
                              void* d_out, int out_size, void* d_ws,
                              size_t ws_size, hipStream_t stream) {
  const float* x   = (const float*)d_in[0];
  const float* n1w = (const float*)d_in[1];
  const float* n2w = (const float*)d_in[2];
  const float* wq  = (const float*)d_in[3];
  const float* bq  = (const float*)d_in[4];
  const float* wk  = (const float*)d_in[5];
  const float* bk  = (const float*)d_in[6];
  const float* wv  = (const float*)d_in[7];
  const float* bv  = (const float*)d_in[8];
  const float* wo  = (const float*)d_in[9];
  const float* bo  = (const float*)d_in[10];
  const float* wr  = (const float*)d_in[11];
  const float* br  = (const float*)d_in[12];
  const float* w1  = (const float*)d_in[13];
  const float* b1  = (const float*)d_in[14];
  const float* w2  = (const float*)d_in[15];
  const float* b2  = (const float*)d_in[16];
  float* out = (float*)d_out;

  char* base = (char*)d_ws;
  size_t off = 0;
  auto alloc = [&](size_t bytes) -> void* {
    void* p = base + off;
    off += (bytes + 255) & ~(size_t)255;
    return p;
  };
  float* f_x1   = (float*)alloc((size_t)CT * CD * 4);
  float* f_h2   = (float*)alloc((size_t)CT * CD * 4);
  short* f_xg   = (short*)alloc((size_t)MAXROWS * CD * 2);
  short* f_hid  = (short*)alloc((size_t)MAXROWS * CF * 2);
  short* f_hh   = (short*)alloc((size_t)CT * CD * 2);
  short* f_hl   = (short*)alloc((size_t)CT * CD * 2);
  short* f_wqkvh = (short*)alloc((size_t)QKVP * CD * 2);
  short* f_wqkvl = (short*)alloc((size_t)QKVP * CD * 2);
  float* f_qkv  = (float*)alloc((size_t)CT * QKVP * 4);
  short* f_ctxh = (short*)alloc((size_t)CT * CD * 2);
  short* f_ctxl = (short*)alloc((size_t)CT * CD * 2);
  short* f_woth = (short*)alloc((size_t)CD * CD * 2);
  short* f_wotl = (short*)alloc((size_t)CD * CD * 2);
  float* f_bqkv = (float*)alloc(QKVP * 4);
  float* f_topp = (float*)alloc(CT * CK * 4);
  float* f_probs = (float*)alloc(CT * CE * 4);
  int* i_topi   = (int*)alloc(CT * CK * 4);
  int* i_rowof  = (int*)alloc(CT * CK * 4);
  int* i_rowmap = (int*)alloc(MAXROWS * 4);
  int* i_cursor = (int*)alloc(CE * 4);
  int* i_offs   = (int*)alloc((CE + 1) * 4);
  int* i_tile   = (int*)alloc(MAXTILES * 4);
  int* i_total  = (int*)alloc(4);
  // G (64MB): w1t -> w2t (sequential reuse)
  short* f_wG = (short*)alloc((size_t)CE * CD * CF * 2);
  short* f_w1t = f_wG;
  short* f_w2t = f_wG;
  // Rs (48MB): QKV partials -> WO partials -> GEMM2 partials (disjoint)
  void* Rs = alloc((size_t)4 * MAXROWS * CD * 4);
  float* f_partqkv = (float*)Rs;
  float* f_partwo = (float*)Rs;
  float* f_partg2 = (float*)Rs;

  dim3 b256(256);

  pack_bias_kernel<<<QKVP / 256, b256, 0, stream>>>(bq, bk, bv, f_bqkv);
  TPtrs tp;
  tp.w[0] = wq; tp.w[1] = wk; tp.w[2] = wv; tp.w[3] = wo;
  tp.hh[0] = f_wqkvh + 0 * (size_t)CD * CD;
  tp.hh[1] = f_wqkvh + 1 * (size_t)CD * CD;
  tp.hh[2] = f_wqkvh + 2 * (size_t)CD * CD;
  tp.hh[3] = f_woth;
  tp.ll[0] = f_wqkvl + 0 * (size_t)CD * CD;
  tp.ll[1] = f_wqkvl + 1 * (size_t)CD * CD;
  tp.ll[2] = f_wqkvl + 2 * (size_t)CD * CD;
  tp.ll[3] = f_wotl;
  transpose4_kernel<<<dim3(16, 16, 4), b256, 0, stream>>>(tp);
  transpose_convert_kernel<<<dim3(CF / 64, CD / 64, CE), b256, 0, stream>>>(
      w1, f_w1t, nullptr, CD, CF);

  // ---- attention ----
  rmsnorm_hl_kernel<<<CT, b256, 0, stream>>>(x, n1w, f_hh, f_hl);
  mfma_gemm_kernel<1><<<dim3(QKVP / 128, CT / 128, 2), b256, 0, stream>>>(
      f_hh, f_hl, f_wqkvh, f_wqkvl, f_partqkv, CT, QKVP, CD);
  reduce_splitk_kernel<<<CT, b256, 0, stream>>>(f_partqkv, CT, 2, f_bqkv,
                                                f_qkv, QKVP);
  fused_attn_kernel<<<dim3(CS / 32, CBH), b256, 0, stream>>>(f_qkv, f_ctxh,
                                                             f_ctxl);
  mfma_gemm_kernel<1><<<dim3(CD / 128, CT / 128, 4), b256, 0, stream>>>(
      f_ctxh, f_ctxl, f_woth, f_wotl, f_partwo, CT, CD, CD);
  attn_epilogue_kernel<<<CT, b256, 0, stream>>>(f_partwo, bo, x, n2w, wr, br,
                                                f_x1, f_h2, i_topi, f_topp,
                                                f_probs);

  // ---- MoE ----
  finalize_kernel<<<1, 256, 0, stream>>>(i_topi, f_probs, i_offs, i_tile,
                                         i_total, i_rowmap, i_cursor,
                                         out + (size_t)CT * CD);
  gather_kernel<<<(CT * CK + 255) / 256, b256, 0, stream>>>(i_topi, i_offs,
                                                            i_cursor, i_rowmap,
                                                            i_rowof);
  gatherx_kernel<<<MAXROWS, b256, 0, stream>>>(f_h2, i_rowmap, f_xg);

  moe_gemm_kernel<1, 1><<<dim3(CF / 256, MAXTILES, 1), dim3(512), 0, stream>>>(
      f_xg, f_w1t, b1, f_hid, nullptr, 0, CF, CD, i_tile, i_total);
  transpose_convert_kernel<<<dim3(CD / 64, CF / 64, CE), b256, 0, stream>>>(
      w2, f_w2t, nullptr, CF, CD);
  moe_gemm_kernel<0, 0><<<dim3(CD / 256, MAXTILES, 4), dim3(512), 0, stream>>>(
      f_hid, f_w2t, nullptr, nullptr, f_partg2, MAXROWS, CD, CF, i_tile,
      i_total);
  combine_g2_kernel<<<CT, b256, 0, stream>>>(f_partg2, MAXROWS, 4, b2, i_tile,
                                             i_rowof, f_topp, f_x1, out);
}

// Round 15
// 343.598 us; speedup vs baseline: 1.0732x; 1.0233x over previous
//
#include <hip/hip_runtime.h>
#include <math.h>

// Problem constants
#define CB 2
#define CS 512
#define CD 1024
#define CH 16
#define CHD 64
#define CF 4096
#define CE 8
#define CK 2
#define CT (CB*CS)      // 1024 tokens
#define CBH (CB*CH)     // 32 (batch*heads)
#define CEPS 1e-6f
#define QKVP 3072       // packed q|k|v row pitch
#define MAXROWS 3072    // 2048 + 8*127 padded to 128
#define MAXTILES (MAXROWS/128)

typedef __attribute__((ext_vector_type(8))) short bf16x8;
typedef __attribute__((ext_vector_type(4))) float f32x4;

__device__ __forceinline__ short f2bf(float f) {
  unsigned u = __float_as_uint(f);
  unsigned r = (u + 0x7FFF + ((u >> 16) & 1)) >> 16;
  return (short)r;
}
__device__ __forceinline__ float bf2f(short h) {
  return __uint_as_float(((unsigned)(unsigned short)h) << 16);
}

__device__ __forceinline__ void gload_lds16(const void* g, void* l) {
  __builtin_amdgcn_global_load_lds(
      (const __attribute__((address_space(1))) unsigned int*)g,
      (__attribute__((address_space(3))) unsigned int*)l, 16, 0, 0);
}

// ---------------------------------------------------------------------------
// RMSNorm, hi/lo bf16 planes out.
__global__ __launch_bounds__(256) void rmsnorm_hl_kernel(
    const float* __restrict__ x, const float* __restrict__ w,
    short* __restrict__ outH, short* __restrict__ outL) {
  int t = blockIdx.x;
  int tid = threadIdx.x;
  float4 xv = ((const float4*)(x + (size_t)t * CD))[tid];
  float ss = xv.x*xv.x + xv.y*xv.y + xv.z*xv.z + xv.w*xv.w;
  for (int off = 32; off > 0; off >>= 1) ss += __shfl_down(ss, off);
  __shared__ float red[4];
  __shared__ float s_scale;
  int lane = tid & 63, wid = tid >> 6;
  if (lane == 0) red[wid] = ss;
  __syncthreads();
  if (tid == 0) {
    float tot = red[0] + red[1] + red[2] + red[3];
    s_scale = rsqrtf(tot / (float)CD + CEPS);
  }
  __syncthreads();
  float sc = s_scale;
  float4 wv = ((const float4*)w)[tid];
  float o[4] = {xv.x * sc * wv.x, xv.y * sc * wv.y,
                xv.z * sc * wv.z, xv.w * sc * wv.w};
  short4 hi, lo;
  short* hp = (short*)&hi; short* lp = (short*)&lo;
#pragma unroll
  for (int i = 0; i < 4; ++i) {
    short h = f2bf(o[i]);
    hp[i] = h;
    lp[i] = f2bf(o[i] - bf2f(h));
  }
  ((short4*)(outH + (size_t)t * CD))[tid] = hi;
  ((short4*)(outL + (size_t)t * CD))[tid] = lo;
}

// ---------------------------------------------------------------------------
// Tiled transpose+convert, 64x64 tile, 16B short8 stores:
// W[e][Kd][Nd] f32 -> Wth[e][Nd][Kd] bf16 (+ optional lo plane).
__global__ __launch_bounds__(256) void transpose_convert_kernel(
    const float* __restrict__ W, short* __restrict__ Wth,
    short* __restrict__ Wtl, int Kd, int Nd) {
  int e = blockIdx.z;
  const float* Wb = W + (size_t)e * Kd * Nd;
  size_t obase = (size_t)e * Kd * Nd;
  int n0 = blockIdx.x * 64, k0 = blockIdx.y * 64;
  __shared__ float t[64][65];
  int tid = threadIdx.x;
#pragma unroll
  for (int i = 0; i < 4; ++i) {
    int idx = i * 256 + tid;
    int r = idx >> 4, c4 = (idx & 15) * 4;
    float4 v = *(const float4*)(Wb + (size_t)(k0 + r) * Nd + n0 + c4);
    t[r][c4] = v.x; t[r][c4 + 1] = v.y; t[r][c4 + 2] = v.z; t[r][c4 + 3] = v.w;
  }
  __syncthreads();
  int n = tid >> 2, k16 = (tid & 3) * 16;
  short th[16], tl[16];
#pragma unroll
  for (int j = 0; j < 16; ++j) {
    float v = t[k16 + j][n];
    short hi = f2bf(v);
    th[j] = hi;
    tl[j] = f2bf(v - bf2f(hi));
  }
  size_t oo = obase + (size_t)(n0 + n) * Kd + k0 + k16;
  ((int4*)(Wth + oo))[0] = ((int4*)th)[0];
  ((int4*)(Wth + oo + 8))[0] = ((int4*)th)[1];
  if (Wtl) {
    ((int4*)(Wtl + oo))[0] = ((int4*)tl)[0];
    ((int4*)(Wtl + oo + 8))[0] = ((int4*)tl)[1];
  }
}

// Four DxD transposes (wq,wk,wv,wo) in one launch, z selects.
struct TPtrs {
  const float* w[4];
  short* hh[4];
  short* ll[4];
};
__global__ __launch_bounds__(256) void transpose4_kernel(TPtrs p) {
  int z = blockIdx.z;
  const float* Wb = p.w[z];
  short* Wth = p.hh[z];
  short* Wtl = p.ll[z];
  int n0 = blockIdx.x * 64, k0 = blockIdx.y * 64;
  __shared__ float t[64][65];
  int tid = threadIdx.x;
#pragma unroll
  for (int i = 0; i < 4; ++i) {
    int idx = i * 256 + tid;
    int r = idx >> 4, c4 = (idx & 15) * 4;
    float4 v = *(const float4*)(Wb + (size_t)(k0 + r) * CD + n0 + c4);
    t[r][c4] = v.x; t[r][c4 + 1] = v.y; t[r][c4 + 2] = v.z; t[r][c4 + 3] = v.w;
  }
  __syncthreads();
  int n = tid >> 2, k16 = (tid & 3) * 16;
  short th[16], tl[16];
#pragma unroll
  for (int j = 0; j < 16; ++j) {
    float v = t[k16 + j][n];
    short hi = f2bf(v);
    th[j] = hi;
    tl[j] = f2bf(v - bf2f(hi));
  }
  size_t oo = (size_t)(n0 + n) * CD + k0 + k16;
  ((int4*)(Wth + oo))[0] = ((int4*)th)[0];
  ((int4*)(Wth + oo + 8))[0] = ((int4*)th)[1];
  ((int4*)(Wtl + oo))[0] = ((int4*)tl)[0];
  ((int4*)(Wtl + oo + 8))[0] = ((int4*)tl)[1];
}

__global__ void pack_bias_kernel(const float* __restrict__ bq,
                                 const float* __restrict__ bk,
                                 const float* __restrict__ bv,
                                 float* __restrict__ out) {
  int i = blockIdx.x * 256 + threadIdx.x;
  if (i < QKVP)
    out[i] = (i < 1024) ? bq[i] : (i < 2048 ? bk[i - 1024] : bv[i - 2048]);
}

// ---------------------------------------------------------------------------
// MoE grouped GEMM: BM=128, BN=256, BK=64, 8 waves.
template <int SILU, int OUTBF>
__global__ __launch_bounds__(512) void moe_gemm_kernel(
    const short* __restrict__ A, const short* __restrict__ Bt,
    const float* __restrict__ bias, void* __restrict__ Cout,
    float* __restrict__ part, int partM, int N, int K,
    const int* __restrict__ tile_e, const int* __restrict__ total_rows) {
  __shared__ __align__(16) short A0[128 * 64], A1[128 * 64];
  __shared__ __align__(16) short B0[256 * 64], B1[256 * 64];
  int tid = threadIdx.x;
  int m0 = blockIdx.y * 128, n0 = blockIdx.x * 256;
  if (m0 >= *total_rows) return;
  int e = tile_e[blockIdx.y];
  const short* Bb = Bt + (size_t)e * N * K;
  const float* biasb = bias ? bias + (size_t)e * N : nullptr;
  int kz = blockIdx.z;
  int kchunk = K / gridDim.z;
  int kbeg = kz * kchunk;
  int nsteps = kchunk >> 6;
  int lane = tid & 63, w = tid >> 6;
  int wr = w >> 2, wc = w & 3;
  int l15 = lane & 15, l4 = lane >> 4;
  f32x4 acc[4][4] = {};

#define STAGE(AS_, BS_, KK)                                                   \
  {                                                                           \
    _Pragma("unroll") for (int i = 0; i < 2; ++i) {                           \
      int c = i * 512 + tid;                                                  \
      int r = c >> 3, gs = c & 7;                                             \
      int g = gs ^ (r & 7);                                                   \
      gload_lds16(A + (size_t)(m0 + r) * K + (KK) + g * 8, &AS_[c * 8]);      \
    }                                                                         \
    _Pragma("unroll") for (int i = 0; i < 4; ++i) {                           \
      int c = i * 512 + tid;                                                  \
      int r = c >> 3, gs = c & 7;                                             \
      int g = gs ^ (r & 7);                                                   \
      gload_lds16(Bb + (size_t)(n0 + r) * K + (KK) + g * 8, &BS_[c * 8]);     \
    }                                                                         \
  }

#define COMPUTE(AS_, BS_)                                                     \
  {                                                                           \
    _Pragma("unroll") for (int ks = 0; ks < 2; ++ks) {                        \
      bf16x8 a[4], b[4];                                                      \
      _Pragma("unroll") for (int m = 0; m < 4; ++m) {                         \
        int row = wr * 64 + m * 16 + l15;                                     \
        int slot = (ks * 4 + l4) ^ (row & 7);                                 \
        a[m] = *(const bf16x8*)&AS_[(row * 8 + slot) * 8];                    \
      }                                                                       \
      _Pragma("unroll") for (int n = 0; n < 4; ++n) {                         \
        int row = wc * 64 + n * 16 + l15;                                     \
        int slot = (ks * 4 + l4) ^ (row & 7);                                 \
        b[n] = *(const bf16x8*)&BS_[(row * 8 + slot) * 8];                    \
      }                                                                       \
      _Pragma("unroll") for (int m = 0; m < 4; ++m)                           \
      _Pragma("unroll") for (int n = 0; n < 4; ++n)                           \
        acc[m][n] = __builtin_amdgcn_mfma_f32_16x16x32_bf16(a[m], b[n],       \
                                                            acc[m][n], 0, 0, 0); \
    }                                                                         \
  }

  STAGE(A0, B0, kbeg);
  __syncthreads();
  for (int s = 0; s < nsteps; s += 2) {
    int k0 = kbeg + (s << 6);
    bool has1 = (s + 1 < nsteps), has2 = (s + 2 < nsteps);
    if (has1) STAGE(A1, B1, k0 + 64);
    COMPUTE(A0, B0);
    __syncthreads();
    if (has1) {
      if (has2) STAGE(A0, B0, k0 + 128);
      COMPUTE(A1, B1);
      __syncthreads();
    }
  }
#undef STAGE
#undef COMPUTE

  if (gridDim.z > 1) {
#pragma unroll
    for (int m = 0; m < 4; ++m) {
      int row = m0 + wr * 64 + m * 16 + l4 * 4;
#pragma unroll
      for (int n = 0; n < 4; ++n) {
        int col = n0 + wc * 64 + n * 16 + l15;
#pragma unroll
        for (int q = 0; q < 4; ++q)
          part[((size_t)kz * partM + row + q) * N + col] = acc[m][n][q];
      }
    }
    return;
  }
  float* outf = (float*)Cout;
  short* outb = (short*)Cout;
#pragma unroll
  for (int m = 0; m < 4; ++m) {
    int row = m0 + wr * 64 + m * 16 + l4 * 4;
#pragma unroll
    for (int n = 0; n < 4; ++n) {
      int col = n0 + wc * 64 + n * 16 + l15;
      float bv = biasb[col];
#pragma unroll
      for (int q = 0; q < 4; ++q) {
        float v = acc[m][n][q] + bv;
        if (SILU) v = v / (1.f + __expf(-v));
        if (OUTBF) outb[(size_t)(row + q) * N + col] = f2bf(v);
        else outf[(size_t)(row + q) * N + col] = v;
      }
    }
  }
}

// ---------------------------------------------------------------------------
// Attention MFMA GEMM: 128x128, BK=32, 4 waves, hi/lo reg-staged.
// gridDim.z>1: split-K partials. gridDim.z==1: direct fp32 out + bias.
template <int LO>
__global__ __launch_bounds__(256) void mfma_gemm_kernel(
    const short* __restrict__ Ah, const short* __restrict__ Al,
    const short* __restrict__ Bh, const short* __restrict__ Bl,
    const float* __restrict__ bias, float* __restrict__ dout,
    float* __restrict__ part, int partM, int N, int K) {
  __shared__ short As0[4096], Bs0[4096], As1[4096], Bs1[4096];
  __shared__ short Als0[LO ? 4096 : 64], Bls0[LO ? 4096 : 64];
  __shared__ short Als1[LO ? 4096 : 64], Bls1[LO ? 4096 : 64];
  int tid = threadIdx.x;
  int m0 = blockIdx.y * 128, n0 = blockIdx.x * 128;
  int kz = blockIdx.z;
  int kchunk = K / gridDim.z;
  int kbeg = kz * kchunk;
  int nsteps = kchunk >> 5;
  int lane = tid & 63, w = tid >> 6;
  int wr = w >> 1, wc = w & 1;
  int l15 = lane & 15, l4 = lane >> 4;
  int xorl = (l15 & 3) ^ ((l15 >> 2) & 3);
  f32x4 acc[4][4] = {};
  bf16x8 vA0[2], vB0[2], vAl0[2], vBl0[2];
  bf16x8 vA1[2], vB1[2], vAl1[2], vBl1[2];

#define LOAD_SET(VA, VB, VAL, VBL, KK)                                        \
  {                                                                           \
    _Pragma("unroll") for (int ic = 0; ic < 2; ++ic) {                        \
      int c = ic * 256 + tid;                                                 \
      int r = c >> 2, g = c & 3;                                              \
      size_t ao = (size_t)(m0 + r) * K + (KK) + g * 8;                        \
      size_t bo = (size_t)(n0 + r) * K + (KK) + g * 8;                        \
      VA[ic] = *(const bf16x8*)(Ah + ao);                                     \
      VB[ic] = *(const bf16x8*)(Bh + bo);                                     \
      if (LO) {                                                               \
        VAL[ic] = *(const bf16x8*)(Al + ao);                                  \
        VBL[ic] = *(const bf16x8*)(Bl + bo);                                  \
      }                                                                       \
    }                                                                         \
  }

#define WRITE_SET(AS_, BS_, ALS_, BLS_, VA, VB, VAL, VBL)                     \
  {                                                                           \
    _Pragma("unroll") for (int ic = 0; ic < 2; ++ic) {                        \
      int c = ic * 256 + tid;                                                 \
      int r = c >> 2, g = c & 3;                                              \
      int ch = (r * 4 + (g ^ (r & 3) ^ ((r >> 2) & 3))) * 8;                  \
      *(bf16x8*)&AS_[ch] = VA[ic];                                            \
      *(bf16x8*)&BS_[ch] = VB[ic];                                            \
      if (LO) {                                                               \
        *(bf16x8*)&ALS_[ch] = VAL[ic];                                        \
        *(bf16x8*)&BLS_[ch] = VBL[ic];                                        \
      }                                                                       \
    }                                                                         \
  }

#define COMPUTE_SET(AS_, BS_, ALS_, BLS_)                                     \
  {                                                                           \
    bf16x8 ah[4], al[4];                                                      \
    _Pragma("unroll") for (int m = 0; m < 4; ++m) {                           \
      int row = wr * 64 + m * 16 + l15;                                       \
      int idx = (row * 4 + (l4 ^ xorl)) * 8;                                  \
      ah[m] = *(const bf16x8*)&AS_[idx];                                      \
      if (LO) al[m] = *(const bf16x8*)&ALS_[idx];                             \
    }                                                                         \
    _Pragma("unroll") for (int n = 0; n < 4; ++n) {                           \
      int row = wc * 64 + n * 16 + l15;                                       \
      int idx = (row * 4 + (l4 ^ xorl)) * 8;                                  \
      bf16x8 bhn = *(const bf16x8*)&BS_[idx];                                 \
      bf16x8 bln;                                                             \
      if (LO) bln = *(const bf16x8*)&BLS_[idx];                               \
      _Pragma("unroll") for (int m = 0; m < 4; ++m) {                         \
        acc[m][n] = __builtin_amdgcn_mfma_f32_16x16x32_bf16(ah[m], bhn,       \
                                                            acc[m][n], 0, 0, 0); \
        if (LO) {                                                             \
          acc[m][n] = __builtin_amdgcn_mfma_f32_16x16x32_bf16(al[m], bhn,     \
                                                              acc[m][n], 0, 0, 0); \
          acc[m][n] = __builtin_amdgcn_mfma_f32_16x16x32_bf16(ah[m], bln,     \
                                                              acc[m][n], 0, 0, 0); \
        }                                                                     \
      }                                                                       \
    }                                                                         \
  }

  LOAD_SET(vA0, vB0, vAl0, vBl0, kbeg);
  WRITE_SET(As0, Bs0, Als0, Bls0, vA0, vB0, vAl0, vBl0);
  __syncthreads();
  for (int s = 0; s < nsteps; s += 2) {
    int k0 = kbeg + (s << 5);
    bool has1 = (s + 1 < nsteps), has2 = (s + 2 < nsteps);
    if (has1) LOAD_SET(vA1, vB1, vAl1, vBl1, k0 + 32);
    COMPUTE_SET(As0, Bs0, Als0, Bls0);
    if (has1) WRITE_SET(As1, Bs1, Als1, Bls1, vA1, vB1, vAl1, vBl1);
    __syncthreads();
    if (has1) {
      if (has2) LOAD_SET(vA0, vB0, vAl0, vBl0, k0 + 64);
      COMPUTE_SET(As1, Bs1, Als1, Bls1);
      if (has2) WRITE_SET(As0, Bs0, Als0, Bls0, vA0, vB0, vAl0, vBl0);
      __syncthreads();
    }
  }
#undef LOAD_SET
#undef WRITE_SET
#undef COMPUTE_SET

  if (gridDim.z > 1) {
#pragma unroll
    for (int m = 0; m < 4; ++m) {
      int row = m0 + wr * 64 + m * 16 + l4 * 4;
#pragma unroll
      for (int n = 0; n < 4; ++n) {
        int col = n0 + wc * 64 + n * 16 + l15;
#pragma unroll
        for (int q = 0; q < 4; ++q)
          part[((size_t)kz * partM + row + q) * N + col] = acc[m][n][q];
      }
    }
    return;
  }
  // direct out: acc + bias (fp32)
#pragma unroll
  for (int m = 0; m < 4; ++m) {
    int row = m0 + wr * 64 + m * 16 + l4 * 4;
#pragma unroll
    for (int n = 0; n < 4; ++n) {
      int col = n0 + wc * 64 + n * 16 + l15;
      float bv = bias[col];
#pragma unroll
      for (int q = 0; q < 4; ++q)
        dout[(size_t)(row + q) * N + col] = acc[m][n][q] + bv;
    }
  }
}

// ---------------------------------------------------------------------------
// Attention epilogue (fused): WO split-K reduce + residual + rmsnorm2 + router.
__global__ __launch_bounds__(256) void attn_epilogue_kernel(
    const float* __restrict__ part, const float* __restrict__ bo,
    const float* __restrict__ x, const float* __restrict__ n2w,
    const float* __restrict__ wr, const float* __restrict__ br,
    float* __restrict__ x1, float* __restrict__ h2, int* __restrict__ top_i,
    float* __restrict__ top_p, float* __restrict__ probs_out) {
  int t = blockIdx.x;
  int tid = threadIdx.x;
  int c = tid * 4;
  float4 s = *(const float4*)(part + (size_t)t * CD + c);
#pragma unroll
  for (int z = 1; z < 4; ++z) {
    float4 p = *(const float4*)(part + ((size_t)z * CT + t) * CD + c);
    s.x += p.x; s.y += p.y; s.z += p.z; s.w += p.w;
  }
  float4 bv = *(const float4*)(bo + c);
  float4 xv = *(const float4*)(x + (size_t)t * CD + c);
  s.x += bv.x + xv.x; s.y += bv.y + xv.y;
  s.z += bv.z + xv.z; s.w += bv.w + xv.w;
  *(float4*)(x1 + (size_t)t * CD + c) = s;
  float ss = s.x*s.x + s.y*s.y + s.z*s.z + s.w*s.w;
  for (int off = 32; off > 0; off >>= 1) ss += __shfl_down(ss, off);
  __shared__ float red[4];
  __shared__ float s_scale;
  int lane = tid & 63, wid = tid >> 6;
  if (lane == 0) red[wid] = ss;
  __syncthreads();
  if (tid == 0) {
    float tot = red[0] + red[1] + red[2] + red[3];
    s_scale = rsqrtf(tot / (float)CD + CEPS);
  }
  __syncthreads();
  float sc = s_scale;
  float4 wv = *(const float4*)(n2w + c);
  float hv[4] = {s.x * sc * wv.x, s.y * sc * wv.y,
                 s.z * sc * wv.z, s.w * sc * wv.w};
  *(float4*)(h2 + (size_t)t * CD + c) =
      make_float4(hv[0], hv[1], hv[2], hv[3]);
  float a[CE] = {};
#pragma unroll
  for (int j = 0; j < 4; ++j) {
    const float* wrow = wr + (size_t)(c + j) * CE;
#pragma unroll
    for (int e = 0; e < CE; ++e) a[e] += hv[j] * wrow[e];
  }
  __shared__ float red8[256][CE];
#pragma unroll
  for (int e = 0; e < CE; ++e) red8[tid][e] = a[e];
  __syncthreads();
  for (int st = 128; st > 0; st >>= 1) {
    if (tid < st) {
#pragma unroll
      for (int e = 0; e < CE; ++e) red8[tid][e] += red8[tid + st][e];
    }
    __syncthreads();
  }
  if (tid == 0) {
    float probs[CE];
    float mx = -1e30f;
#pragma unroll
    for (int e = 0; e < CE; ++e) {
      probs[e] = red8[0][e] + br[e];
      mx = fmaxf(mx, probs[e]);
    }
    float sum = 0.f;
#pragma unroll
    for (int e = 0; e < CE; ++e) { probs[e] = __expf(probs[e] - mx); sum += probs[e]; }
    float inv = 1.0f / sum;
#pragma unroll
    for (int e = 0; e < CE; ++e) {
      probs[e] *= inv;
      probs_out[t * CE + e] = probs[e];
    }
    int i1 = 0;
#pragma unroll
    for (int e = 1; e < CE; ++e) if (probs[e] > probs[i1]) i1 = e;
    int i2 = (i1 == 0) ? 1 : 0;
#pragma unroll
    for (int e = 0; e < CE; ++e)
      if (e != i1 && probs[e] > probs[i2]) i2 = e;
    float p1 = probs[i1], p2 = probs[i2];
    float s12 = p1 + p2;
    top_i[t * 2 + 0] = i1;
    top_i[t * 2 + 1] = i2;
    top_p[t * 2 + 0] = p1 / s12;
    top_p[t * 2 + 1] = p2 / s12;
  }
}

// ---------------------------------------------------------------------------
// Fused attention v5b: v5 structure (256 thr, 4 rows x 2 cols, K/V LDS
// time-share, flash online softmax) with batched LDS access: Pt stride 68,
// Pt written as float2, PV reads P as float4 per 4-col chunk (same FMA
// order -> bit-identical numerics, ~30% fewer LDS instructions in PV).
__global__ __launch_bounds__(256) void fused_attn_kernel(
    const float* __restrict__ qkv, short* __restrict__ ctxh,
    short* __restrict__ ctxl) {
  __shared__ float Qs[32][68];    // Q tile
  __shared__ float KVs[64 * 68];  // K (stride 65) then V (stride 68)
  __shared__ float Pt[32][68];    // per-tile P (stride 68 for float4 reads)
  int qt = blockIdx.x, bh = blockIdx.y;
  int b = bh / CH, h = bh % CH;
  int qrow0 = qt * 32;
  int ktmax = (qrow0 + 31) >> 6;
  int tid = threadIdx.x;
  int cg = tid & 31, rg = tid >> 5;
  int r0 = rg * 4;

  // stage Q [32][64]
#pragma unroll
  for (int it = 0; it < 2; ++it) {
    int idx = it * 256 + tid;
    int r = idx >> 4, c4 = (idx & 15) * 4;
    *(float4*)&Qs[r][c4] = *(const float4*)(
        qkv + (size_t)(b * CS + qrow0 + r) * QKVP + h * CHD + c4);
  }

  float m_i[4], l_i[4], O[4][2];
#pragma unroll
  for (int i = 0; i < 4; ++i) {
    m_i[i] = -1e30f;
    l_i[i] = 0.f;
    O[i][0] = 0.f;
    O[i][1] = 0.f;
  }

  for (int kt = 0; kt <= ktmax; ++kt) {
    __syncthreads();  // prev tile's PV reads of KVs(V)/Pt done
    // stage K (scalar, stride 65)
#pragma unroll
    for (int it = 0; it < 4; ++it) {
      int idx = it * 256 + tid;
      int r = idx >> 4, c4 = (idx & 15) * 4;
      const float* src =
          qkv + (size_t)(b * CS + kt * 64 + r) * QKVP + h * CHD;
      float4 kv = *(const float4*)(src + 1024 + c4);
      KVs[r * 65 + c4 + 0] = kv.x;
      KVs[r * 65 + c4 + 1] = kv.y;
      KVs[r * 65 + c4 + 2] = kv.z;
      KVs[r * 65 + c4 + 3] = kv.w;
    }
    __syncthreads();

    // scores: s[4 rows][2 cols]
    float s[4][2] = {};
#pragma unroll 4
    for (int d = 0; d < 64; ++d) {
      float q0 = Qs[r0 + 0][d];
      float q1 = Qs[r0 + 1][d];
      float q2 = Qs[r0 + 2][d];
      float q3 = Qs[r0 + 3][d];
      float k0 = KVs[(cg * 2 + 0) * 65 + d];
      float k1 = KVs[(cg * 2 + 1) * 65 + d];
      s[0][0] += q0 * k0; s[0][1] += q0 * k1;
      s[1][0] += q1 * k0; s[1][1] += q1 * k1;
      s[2][0] += q2 * k0; s[2][1] += q2 * k1;
      s[3][0] += q3 * k0; s[3][1] += q3 * k1;
    }

    // online softmax update (per row, reduce over 32-lane col group)
#pragma unroll
    for (int i = 0; i < 4; ++i) {
      int gr = qrow0 + r0 + i;
      int gc0 = kt * 64 + cg * 2;
      float s0 = (gc0 + 0 > gr) ? -1e30f : s[i][0] * 0.125f;
      float s1 = (gc0 + 1 > gr) ? -1e30f : s[i][1] * 0.125f;
      float tmax = fmaxf(s0, s1);
#pragma unroll
      for (int off = 16; off > 0; off >>= 1)
        tmax = fmaxf(tmax, __shfl_xor(tmax, off));
      float newm = fmaxf(m_i[i], tmax);
      float p0 = __expf(s0 - newm);
      float p1 = __expf(s1 - newm);
      float tsum = p0 + p1;
#pragma unroll
      for (int off = 16; off > 0; off >>= 1) tsum += __shfl_xor(tsum, off);
      float scale = __expf(m_i[i] - newm);
      l_i[i] = l_i[i] * scale + tsum;
      m_i[i] = newm;
      O[i][0] *= scale;
      O[i][1] *= scale;
      *(float2*)&Pt[r0 + i][cg * 2] = make_float2(p0, p1);
    }
    __syncthreads();  // all K reads + Pt writes done

    // stage V into the same buffer (float4, stride 68)
#pragma unroll
    for (int it = 0; it < 4; ++it) {
      int idx = it * 256 + tid;
      int r = idx >> 4, c4 = (idx & 15) * 4;
      *(float4*)&KVs[r * 68 + c4] = *(const float4*)(
          qkv + (size_t)(b * CS + kt * 64 + r) * QKVP + 2048 + h * CHD + c4);
    }
    __syncthreads();

    // PV: per 4-c chunk, float4 P reads; same FMA order as scalar version.
#pragma unroll 2
    for (int c4 = 0; c4 < 64; c4 += 4) {
      float4 pr[4];
#pragma unroll
      for (int i = 0; i < 4; ++i) pr[i] = *(const float4*)&Pt[r0 + i][c4];
      float pv[4][4] = {{pr[0].x, pr[0].y, pr[0].z, pr[0].w},
                        {pr[1].x, pr[1].y, pr[1].z, pr[1].w},
                        {pr[2].x, pr[2].y, pr[2].z, pr[2].w},
                        {pr[3].x, pr[3].y, pr[3].z, pr[3].w}};
#pragma unroll
      for (int j = 0; j < 4; ++j) {
        int c = c4 + j;
        float v0 = KVs[c * 68 + cg];
        float v1 = KVs[c * 68 + cg + 32];
        O[0][0] += pv[0][j] * v0; O[0][1] += pv[0][j] * v1;
        O[1][0] += pv[1][j] * v0; O[1][1] += pv[1][j] * v1;
        O[2][0] += pv[2][j] * v0; O[2][1] += pv[2][j] * v1;
        O[3][0] += pv[3][j] * v0; O[3][1] += pv[3][j] * v1;
      }
    }
  }

  // epilogue: normalize by l, write hi/lo bf16 planes
#pragma unroll
  for (int i = 0; i < 4; ++i) {
    float inv = 1.0f / l_i[i];
#pragma unroll
    for (int jd = 0; jd < 2; ++jd) {
      int dv = cg + 32 * jd;
      size_t oi = (size_t)(b * CS + qrow0 + r0 + i) * CD + h * CHD + dv;
      float v = O[i][jd] * inv;
      short hi = f2bf(v);
      ctxh[oi] = hi;
      ctxl[oi] = f2bf(v - bf2f(hi));
    }
  }
}

// ---------------------------------------------------------------------------
// Finalize (1 block): counts/psum, offsets, tile map, aux loss, cursor clear.
__global__ __launch_bounds__(256) void finalize_kernel(
    const int* __restrict__ top_i, const float* __restrict__ probs,
    int* __restrict__ offs, int* __restrict__ tile_e,
    int* __restrict__ total_padded, int* __restrict__ row_map,
    int* __restrict__ cursor, float* __restrict__ aux_out) {
  int tid = threadIdx.x;
  __shared__ float redp[256][CE];
  __shared__ int redc[256][CE];
  float lp[CE] = {};
  int lc[CE] = {};
  for (int t = tid; t < CT; t += 256) {
    lc[top_i[t * 2 + 0]]++;
    lc[top_i[t * 2 + 1]]++;
#pragma unroll
    for (int e = 0; e < CE; ++e) lp[e] += probs[t * CE + e];
  }
#pragma unroll
  for (int e = 0; e < CE; ++e) { redp[tid][e] = lp[e]; redc[tid][e] = lc[e]; }
  __syncthreads();
  for (int s = 128; s > 0; s >>= 1) {
    if (tid < s) {
#pragma unroll
      for (int e = 0; e < CE; ++e) {
        redp[tid][e] += redp[tid + s][e];
        redc[tid][e] += redc[tid + s][e];
      }
    }
    __syncthreads();
  }
  __shared__ int s_off[CE + 1];
  if (tid == 0) {
    int o = 0;
    for (int e = 0; e < CE; ++e) {
      s_off[e] = o;
      offs[e] = o;
      o += ((redc[0][e] + 127) >> 7) << 7;
    }
    s_off[CE] = o;
    offs[CE] = o;
    *total_padded = o;
    int nt = o >> 7;
    for (int i = 0; i < nt; ++i) {
      int e = 0;
      while (e < CE - 1 && i * 128 >= s_off[e + 1]) e++;
      tile_e[i] = e;
    }
    float aux = 0.f;
    for (int e = 0; e < CE; ++e)
      aux += ((float)redc[0][e] / (float)(CT * CK)) * (redp[0][e] / (float)CT);
    aux_out[0] = aux * (float)CE;
  }
  if (tid < CE) cursor[tid] = 0;
  __syncthreads();
  for (int i = tid; i < MAXROWS; i += blockDim.x) row_map[i] = -1;
}

__global__ void gather_kernel(const int* __restrict__ top_i,
                              const int* __restrict__ offs,
                              int* __restrict__ cursor, int* __restrict__ row_map,
                              int* __restrict__ row_of) {
  int idx = blockIdx.x * blockDim.x + threadIdx.x;
  if (idx >= CT * CK) return;
  int e = top_i[idx];
  int pos = offs[e] + atomicAdd(&cursor[e], 1);
  row_map[pos] = idx >> 1;
  row_of[idx] = pos;
}

// Xg[row] = bf16(h2[row_map[row]]) or zeros for pad rows.
__global__ __launch_bounds__(256) void gatherx_kernel(
    const float* __restrict__ h2, const int* __restrict__ row_map,
    short* __restrict__ Xg) {
  int row = blockIdx.x;
  int tid = threadIdx.x;
  int tok = row_map[row];
  short4 o;
  if (tok < 0) {
    o = make_short4(0, 0, 0, 0);
  } else {
    float4 v = ((const float4*)(h2 + (size_t)tok * CD))[tid];
    o = make_short4(f2bf(v.x), f2bf(v.y), f2bf(v.z), f2bf(v.w));
  }
  ((short4*)(Xg + (size_t)row * CD))[tid] = o;
}

// Fused GEMM2-reduce + combine: per token, read only its 2 routed rows'
// partials, add b2[e], weight, residual.
__global__ __launch_bounds__(256) void combine_g2_kernel(
    const float* __restrict__ part, int partM, int nz,
    const float* __restrict__ b2, const int* __restrict__ tile_e,
    const int* __restrict__ row_of, const float* __restrict__ top_p,
    const float* __restrict__ x1, float* __restrict__ out) {
  int t = blockIdx.x;
  int c = threadIdx.x * 4;
  float4 r = *(const float4*)(x1 + (size_t)t * CD + c);
#pragma unroll
  for (int s = 0; s < CK; ++s) {
    int row = row_of[t * 2 + s];
    int e = tile_e[row >> 7];
    float w = top_p[t * 2 + s];
    float4 acc = *(const float4*)(part + (size_t)row * CD + c);
    for (int z = 1; z < nz; ++z) {
      float4 p = *(const float4*)(part + ((size_t)z * partM + row) * CD + c);
      acc.x += p.x; acc.y += p.y; acc.z += p.z; acc.w += p.w;
    }
    float4 bv = *(const float4*)(b2 + (size_t)e * CD + c);
    r.x += w * (acc.x + bv.x);
    r.y += w * (acc.y + bv.y);
    r.z += w * (acc.z + bv.z);
    r.w += w * (acc.w + bv.w);
  }
  *(float4*)(out + (size_t)t * CD + c) = r;
}

// ---------------------------------------------------------------------------
extern "C" void kernel_launch(void* const* d_in, const int* in_sizes, int n_in,
                              void* d_out, int out_size, void* d_ws,
                              size_t ws_size, hipStream_t stream) {
  const float* x   = (const float*)d_in[0];
  const float* n1w = (const float*)d_in[1];
  const float* n2w = (const float*)d_in[2];
  const float* wq  = (const float*)d_in[3];
  const float* bq  = (const float*)d_in[4];
  const float* wk  = (const float*)d_in[5];
  const float* bk  = (const float*)d_in[6];
  const float* wv  = (const float*)d_in[7];
  const float* bv  = (const float*)d_in[8];
  const float* wo  = (const float*)d_in[9];
  const float* bo  = (const float*)d_in[10];
  const float* wr  = (const float*)d_in[11];
  const float* br  = (const float*)d_in[12];
  const float* w1  = (const float*)d_in[13];
  const float* b1  = (const float*)d_in[14];
  const float* w2  = (const float*)d_in[15];
  const float* b2  = (const float*)d_in[16];
  float* out = (float*)d_out;

  char* base = (char*)d_ws;
  size_t off = 0;
  auto alloc = [&](size_t bytes) -> void* {
    void* p = base + off;
    off += (bytes + 255) & ~(size_t)255;
    return p;
  };
  float* f_x1   = (float*)alloc((size_t)CT * CD * 4);
  float* f_h2   = (float*)alloc((size_t)CT * CD * 4);
  short* f_xg   = (short*)alloc((size_t)MAXROWS * CD * 2);
  short* f_hid  = (short*)alloc((size_t)MAXROWS * CF * 2);
  short* f_hh   = (short*)alloc((size_t)CT * CD * 2);
  short* f_hl   = (short*)alloc((size_t)CT * CD * 2);
  short* f_wqkvh = (short*)alloc((size_t)QKVP * CD * 2);
  short* f_wqkvl = (short*)alloc((size_t)QKVP * CD * 2);
  float* f_qkv  = (float*)alloc((size_t)CT * QKVP * 4);
  short* f_ctxh = (short*)alloc((size_t)CT * CD * 2);
  short* f_ctxl = (short*)alloc((size_t)CT * CD * 2);
  short* f_woth = (short*)alloc((size_t)CD * CD * 2);
  short* f_wotl = (short*)alloc((size_t)CD * CD * 2);
  float* f_bqkv = (float*)alloc(QKVP * 4);
  float* f_topp = (float*)alloc(CT * CK * 4);
  float* f_probs = (float*)alloc(CT * CE * 4);
  int* i_topi   = (int*)alloc(CT * CK * 4);
  int* i_rowof  = (int*)alloc(CT * CK * 4);
  int* i_rowmap = (int*)alloc(MAXROWS * 4);
  int* i_cursor = (int*)alloc(CE * 4);
  int* i_offs   = (int*)alloc((CE + 1) * 4);
  int* i_tile   = (int*)alloc(MAXTILES * 4);
  int* i_total  = (int*)alloc(4);
  // G (64MB): w1t -> w2t (sequential reuse)
  short* f_wG = (short*)alloc((size_t)CE * CD * CF * 2);
  short* f_w1t = f_wG;
  short* f_w2t = f_wG;
  // Rs (48MB): WO partials -> GEMM2 partials (disjoint)
  void* Rs = alloc((size_t)4 * MAXROWS * CD * 4);
  float* f_partwo = (float*)Rs;
  float* f_partg2 = (float*)Rs;

  dim3 b256(256);

  pack_bias_kernel<<<QKVP / 256, b256, 0, stream>>>(bq, bk, bv, f_bqkv);
  TPtrs tp;
  tp.w[0] = wq; tp.w[1] = wk; tp.w[2] = wv; tp.w[3] = wo;
  tp.hh[0] = f_wqkvh + 0 * (size_t)CD * CD;
  tp.hh[1] = f_wqkvh + 1 * (size_t)CD * CD;
  tp.hh[2] = f_wqkvh + 2 * (size_t)CD * CD;
  tp.hh[3] = f_woth;
  tp.ll[0] = f_wqkvl + 0 * (size_t)CD * CD;
  tp.ll[1] = f_wqkvl + 1 * (size_t)CD * CD;
  tp.ll[2] = f_wqkvl + 2 * (size_t)CD * CD;
  tp.ll[3] = f_wotl;
  transpose4_kernel<<<dim3(16, 16, 4), b256, 0, stream>>>(tp);
  transpose_convert_kernel<<<dim3(CF / 64, CD / 64, CE), b256, 0, stream>>>(
      w1, f_w1t, nullptr, CD, CF);

  // ---- attention ----
  rmsnorm_hl_kernel<<<CT, b256, 0, stream>>>(x, n1w, f_hh, f_hl);
  // QKV: split-K=1, bias fused, direct fp32 out (no reduce pass)
  mfma_gemm_kernel<1><<<dim3(QKVP / 128, CT / 128, 1), b256, 0, stream>>>(
      f_hh, f_hl, f_wqkvh, f_wqkvl, f_bqkv, f_qkv, nullptr, CT, QKVP, CD);
  fused_attn_kernel<<<dim3(CS / 32, CBH), b256, 0, stream>>>(f_qkv, f_ctxh,
                                                             f_ctxl);
  mfma_gemm_kernel<1><<<dim3(CD / 128, CT / 128, 4), b256, 0, stream>>>(
      f_ctxh, f_ctxl, f_woth, f_wotl, nullptr, nullptr, f_partwo, CT, CD, CD);
  attn_epilogue_kernel<<<CT, b256, 0, stream>>>(f_partwo, bo, x, n2w, wr, br,
                                                f_x1, f_h2, i_topi, f_topp,
                                                f_probs);

  // ---- MoE ----
  finalize_kernel<<<1, 256, 0, stream>>>(i_topi, f_probs, i_offs, i_tile,
                                         i_total, i_rowmap, i_cursor,
                                         out + (size_t)CT * CD);
  gather_kernel<<<(CT * CK + 255) / 256, b256, 0, stream>>>(i_topi, i_offs,
                                                            i_cursor, i_rowmap,
                                                            i_rowof);
  gatherx_kernel<<<MAXROWS, b256, 0, stream>>>(f_h2, i_rowmap, f_xg);

  moe_gemm_kernel<1, 1><<<dim3(CF / 256, MAXTILES, 1), dim3(512), 0, stream>>>(
      f_xg, f_w1t, b1, f_hid, nullptr, 0, CF, CD, i_tile, i_total);
  transpose_convert_kernel<<<dim3(CD / 64, CF / 64, CE), b256, 0, stream>>>(
      w2, f_w2t, nullptr, CF, CD);
  moe_gemm_kernel<0, 0><<<dim3(CD / 256, MAXTILES, 4), dim3(512), 0, stream>>>(
      f_hid, f_w2t, nullptr, nullptr, f_partg2, MAXROWS, CD, CF, i_tile,
      i_total);
  combine_g2_kernel<<<CT, b256, 0, stream>>>(f_partg2, MAXROWS, 4, b2, i_tile,
                                             i_rowof, f_topp, f_x1, out);
}

// Round 16
// 328.796 us; speedup vs baseline: 1.1215x; 1.0450x over previous
//
#include <hip/hip_runtime.h>
#include <math.h>

// Problem constants
#define CB 2
#define CS 512
#define CD 1024
#define CH 16
#define CHD 64
#define CF 4096
#define CE 8
#define CK 2
#define CT (CB*CS)      // 1024 tokens
#define CBH (CB*CH)     // 32 (batch*heads)
#define CEPS 1e-6f
#define QKVP 3072       // packed q|k|v row pitch
#define MAXROWS 3072    // 2048 + 8*127 padded to 128
#define MAXTILES (MAXROWS/128)

typedef __attribute__((ext_vector_type(8))) short bf16x8;
typedef __attribute__((ext_vector_type(4))) float f32x4;

__device__ __forceinline__ short f2bf(float f) {
  unsigned u = __float_as_uint(f);
  unsigned r = (u + 0x7FFF + ((u >> 16) & 1)) >> 16;
  return (short)r;
}
__device__ __forceinline__ float bf2f(short h) {
  return __uint_as_float(((unsigned)(unsigned short)h) << 16);
}

__device__ __forceinline__ void gload_lds16(const void* g, void* l) {
  __builtin_amdgcn_global_load_lds(
      (const __attribute__((address_space(1))) unsigned int*)g,
      (__attribute__((address_space(3))) unsigned int*)l, 16, 0, 0);
}

// ---------------------------------------------------------------------------
// RMSNorm, hi/lo bf16 planes out.
__global__ __launch_bounds__(256) void rmsnorm_hl_kernel(
    const float* __restrict__ x, const float* __restrict__ w,
    short* __restrict__ outH, short* __restrict__ outL) {
  int t = blockIdx.x;
  int tid = threadIdx.x;
  float4 xv = ((const float4*)(x + (size_t)t * CD))[tid];
  float ss = xv.x*xv.x + xv.y*xv.y + xv.z*xv.z + xv.w*xv.w;
  for (int off = 32; off > 0; off >>= 1) ss += __shfl_down(ss, off);
  __shared__ float red[4];
  __shared__ float s_scale;
  int lane = tid & 63, wid = tid >> 6;
  if (lane == 0) red[wid] = ss;
  __syncthreads();
  if (tid == 0) {
    float tot = red[0] + red[1] + red[2] + red[3];
    s_scale = rsqrtf(tot / (float)CD + CEPS);
  }
  __syncthreads();
  float sc = s_scale;
  float4 wv = ((const float4*)w)[tid];
  float o[4] = {xv.x * sc * wv.x, xv.y * sc * wv.y,
                xv.z * sc * wv.z, xv.w * sc * wv.w};
  short4 hi, lo;
  short* hp = (short*)&hi; short* lp = (short*)&lo;
#pragma unroll
  for (int i = 0; i < 4; ++i) {
    short h = f2bf(o[i]);
    hp[i] = h;
    lp[i] = f2bf(o[i] - bf2f(h));
  }
  ((short4*)(outH + (size_t)t * CD))[tid] = hi;
  ((short4*)(outL + (size_t)t * CD))[tid] = lo;
}

// ---------------------------------------------------------------------------
// Tiled transpose+convert, 64x64 tile, 16B short8 stores:
// W[e][Kd][Nd] f32 -> Wth[e][Nd][Kd] bf16 (+ optional lo plane).
__global__ __launch_bounds__(256) void transpose_convert_kernel(
    const float* __restrict__ W, short* __restrict__ Wth,
    short* __restrict__ Wtl, int Kd, int Nd) {
  int e = blockIdx.z;
  const float* Wb = W + (size_t)e * Kd * Nd;
  size_t obase = (size_t)e * Kd * Nd;
  int n0 = blockIdx.x * 64, k0 = blockIdx.y * 64;
  __shared__ float t[64][65];
  int tid = threadIdx.x;
#pragma unroll
  for (int i = 0; i < 4; ++i) {
    int idx = i * 256 + tid;
    int r = idx >> 4, c4 = (idx & 15) * 4;
    float4 v = *(const float4*)(Wb + (size_t)(k0 + r) * Nd + n0 + c4);
    t[r][c4] = v.x; t[r][c4 + 1] = v.y; t[r][c4 + 2] = v.z; t[r][c4 + 3] = v.w;
  }
  __syncthreads();
  int n = tid >> 2, k16 = (tid & 3) * 16;
  short th[16], tl[16];
#pragma unroll
  for (int j = 0; j < 16; ++j) {
    float v = t[k16 + j][n];
    short hi = f2bf(v);
    th[j] = hi;
    tl[j] = f2bf(v - bf2f(hi));
  }
  size_t oo = obase + (size_t)(n0 + n) * Kd + k0 + k16;
  ((int4*)(Wth + oo))[0] = ((int4*)th)[0];
  ((int4*)(Wth + oo + 8))[0] = ((int4*)th)[1];
  if (Wtl) {
    ((int4*)(Wtl + oo))[0] = ((int4*)tl)[0];
    ((int4*)(Wtl + oo + 8))[0] = ((int4*)tl)[1];
  }
}

// Four DxD transposes (wq,wk,wv,wo) in one launch, z selects.
struct TPtrs {
  const float* w[4];
  short* hh[4];
  short* ll[4];
};
__global__ __launch_bounds__(256) void transpose4_kernel(TPtrs p) {
  int z = blockIdx.z;
  const float* Wb = p.w[z];
  short* Wth = p.hh[z];
  short* Wtl = p.ll[z];
  int n0 = blockIdx.x * 64, k0 = blockIdx.y * 64;
  __shared__ float t[64][65];
  int tid = threadIdx.x;
#pragma unroll
  for (int i = 0; i < 4; ++i) {
    int idx = i * 256 + tid;
    int r = idx >> 4, c4 = (idx & 15) * 4;
    float4 v = *(const float4*)(Wb + (size_t)(k0 + r) * CD + n0 + c4);
    t[r][c4] = v.x; t[r][c4 + 1] = v.y; t[r][c4 + 2] = v.z; t[r][c4 + 3] = v.w;
  }
  __syncthreads();
  int n = tid >> 2, k16 = (tid & 3) * 16;
  short th[16], tl[16];
#pragma unroll
  for (int j = 0; j < 16; ++j) {
    float v = t[k16 + j][n];
    short hi = f2bf(v);
    th[j] = hi;
    tl[j] = f2bf(v - bf2f(hi));
  }
  size_t oo = (size_t)(n0 + n) * CD + k0 + k16;
  ((int4*)(Wth + oo))[0] = ((int4*)th)[0];
  ((int4*)(Wth + oo + 8))[0] = ((int4*)th)[1];
  ((int4*)(Wtl + oo))[0] = ((int4*)tl)[0];
  ((int4*)(Wtl + oo + 8))[0] = ((int4*)tl)[1];
}

__global__ void pack_bias_kernel(const float* __restrict__ bq,
                                 const float* __restrict__ bk,
                                 const float* __restrict__ bv,
                                 float* __restrict__ out) {
  int i = blockIdx.x * 256 + threadIdx.x;
  if (i < QKVP)
    out[i] = (i < 1024) ? bq[i] : (i < 2048 ? bk[i - 1024] : bv[i - 2048]);
}

// ---------------------------------------------------------------------------
// MoE grouped GEMM: BM=128, BN=128, BK=64, 8 waves (2x4; wave out 64x32).
// LDS 64KB -> 2 blocks/CU (was BN=256/96KB/1 block). Same staging/swizzle.
template <int SILU, int OUTBF>
__global__ __launch_bounds__(512) void moe_gemm_kernel(
    const short* __restrict__ A, const short* __restrict__ Bt,
    const float* __restrict__ bias, void* __restrict__ Cout,
    float* __restrict__ part, int partM, int N, int K,
    const int* __restrict__ tile_e, const int* __restrict__ total_rows) {
  __shared__ __align__(16) short A0[128 * 64], A1[128 * 64];
  __shared__ __align__(16) short B0[128 * 64], B1[128 * 64];
  int tid = threadIdx.x;
  int m0 = blockIdx.y * 128, n0 = blockIdx.x * 128;
  if (m0 >= *total_rows) return;
  int e = tile_e[blockIdx.y];
  const short* Bb = Bt + (size_t)e * N * K;
  const float* biasb = bias ? bias + (size_t)e * N : nullptr;
  int kz = blockIdx.z;
  int kchunk = K / gridDim.z;
  int kbeg = kz * kchunk;
  int nsteps = kchunk >> 6;
  int lane = tid & 63, w = tid >> 6;
  int wr = w >> 2, wc = w & 3;  // wave out: rows 64*wr.., cols 32*wc..
  int l15 = lane & 15, l4 = lane >> 4;
  f32x4 acc[4][2] = {};

  // A/B: 128 rows x 8 slots = 1024 chunks each; 2 insts/thread each.
#define STAGE(AS_, BS_, KK)                                                   \
  {                                                                           \
    _Pragma("unroll") for (int i = 0; i < 2; ++i) {                           \
      int c = i * 512 + tid;                                                  \
      int r = c >> 3, gs = c & 7;                                             \
      int g = gs ^ (r & 7);                                                   \
      gload_lds16(A + (size_t)(m0 + r) * K + (KK) + g * 8, &AS_[c * 8]);      \
    }                                                                         \
    _Pragma("unroll") for (int i = 0; i < 2; ++i) {                           \
      int c = i * 512 + tid;                                                  \
      int r = c >> 3, gs = c & 7;                                             \
      int g = gs ^ (r & 7);                                                   \
      gload_lds16(Bb + (size_t)(n0 + r) * K + (KK) + g * 8, &BS_[c * 8]);     \
    }                                                                         \
  }

#define COMPUTE(AS_, BS_)                                                     \
  {                                                                           \
    _Pragma("unroll") for (int ks = 0; ks < 2; ++ks) {                        \
      bf16x8 a[4], b[2];                                                      \
      _Pragma("unroll") for (int m = 0; m < 4; ++m) {                         \
        int row = wr * 64 + m * 16 + l15;                                     \
        int slot = (ks * 4 + l4) ^ (row & 7);                                 \
        a[m] = *(const bf16x8*)&AS_[(row * 8 + slot) * 8];                    \
      }                                                                       \
      _Pragma("unroll") for (int n = 0; n < 2; ++n) {                         \
        int row = wc * 32 + n * 16 + l15;                                     \
        int slot = (ks * 4 + l4) ^ (row & 7);                                 \
        b[n] = *(const bf16x8*)&BS_[(row * 8 + slot) * 8];                    \
      }                                                                       \
      _Pragma("unroll") for (int m = 0; m < 4; ++m)                           \
      _Pragma("unroll") for (int n = 0; n < 2; ++n)                           \
        acc[m][n] = __builtin_amdgcn_mfma_f32_16x16x32_bf16(a[m], b[n],       \
                                                            acc[m][n], 0, 0, 0); \
    }                                                                         \
  }

  STAGE(A0, B0, kbeg);
  __syncthreads();
  for (int s = 0; s < nsteps; s += 2) {
    int k0 = kbeg + (s << 6);
    bool has1 = (s + 1 < nsteps), has2 = (s + 2 < nsteps);
    if (has1) STAGE(A1, B1, k0 + 64);
    COMPUTE(A0, B0);
    __syncthreads();
    if (has1) {
      if (has2) STAGE(A0, B0, k0 + 128);
      COMPUTE(A1, B1);
      __syncthreads();
    }
  }
#undef STAGE
#undef COMPUTE

  if (gridDim.z > 1) {
#pragma unroll
    for (int m = 0; m < 4; ++m) {
      int row = m0 + wr * 64 + m * 16 + l4 * 4;
#pragma unroll
      for (int n = 0; n < 2; ++n) {
        int col = n0 + wc * 32 + n * 16 + l15;
#pragma unroll
        for (int q = 0; q < 4; ++q)
          part[((size_t)kz * partM + row + q) * N + col] = acc[m][n][q];
      }
    }
    return;
  }
  float* outf = (float*)Cout;
  short* outb = (short*)Cout;
#pragma unroll
  for (int m = 0; m < 4; ++m) {
    int row = m0 + wr * 64 + m * 16 + l4 * 4;
#pragma unroll
    for (int n = 0; n < 2; ++n) {
      int col = n0 + wc * 32 + n * 16 + l15;
      float bv = biasb[col];
#pragma unroll
      for (int q = 0; q < 4; ++q) {
        float v = acc[m][n][q] + bv;
        if (SILU) v = v / (1.f + __expf(-v));
        if (OUTBF) outb[(size_t)(row + q) * N + col] = f2bf(v);
        else outf[(size_t)(row + q) * N + col] = v;
      }
    }
  }
}

// ---------------------------------------------------------------------------
// Attention MFMA GEMM: 128x128, BK=32, 4 waves, hi/lo reg-staged.
// gridDim.z>1: split-K partials. gridDim.z==1: direct fp32 out + bias.
template <int LO>
__global__ __launch_bounds__(256) void mfma_gemm_kernel(
    const short* __restrict__ Ah, const short* __restrict__ Al,
    const short* __restrict__ Bh, const short* __restrict__ Bl,
    const float* __restrict__ bias, float* __restrict__ dout,
    float* __restrict__ part, int partM, int N, int K) {
  __shared__ short As0[4096], Bs0[4096], As1[4096], Bs1[4096];
  __shared__ short Als0[LO ? 4096 : 64], Bls0[LO ? 4096 : 64];
  __shared__ short Als1[LO ? 4096 : 64], Bls1[LO ? 4096 : 64];
  int tid = threadIdx.x;
  int m0 = blockIdx.y * 128, n0 = blockIdx.x * 128;
  int kz = blockIdx.z;
  int kchunk = K / gridDim.z;
  int kbeg = kz * kchunk;
  int nsteps = kchunk >> 5;
  int lane = tid & 63, w = tid >> 6;
  int wr = w >> 1, wc = w & 1;
  int l15 = lane & 15, l4 = lane >> 4;
  int xorl = (l15 & 3) ^ ((l15 >> 2) & 3);
  f32x4 acc[4][4] = {};
  bf16x8 vA0[2], vB0[2], vAl0[2], vBl0[2];
  bf16x8 vA1[2], vB1[2], vAl1[2], vBl1[2];

#define LOAD_SET(VA, VB, VAL, VBL, KK)                                        \
  {                                                                           \
    _Pragma("unroll") for (int ic = 0; ic < 2; ++ic) {                        \
      int c = ic * 256 + tid;                                                 \
      int r = c >> 2, g = c & 3;                                              \
      size_t ao = (size_t)(m0 + r) * K + (KK) + g * 8;                        \
      size_t bo = (size_t)(n0 + r) * K + (KK) + g * 8;                        \
      VA[ic] = *(const bf16x8*)(Ah + ao);                                     \
      VB[ic] = *(const bf16x8*)(Bh + bo);                                     \
      if (LO) {                                                               \
        VAL[ic] = *(const bf16x8*)(Al + ao);                                  \
        VBL[ic] = *(const bf16x8*)(Bl + bo);                                  \
      }                                                                       \
    }                                                                         \
  }

#define WRITE_SET(AS_, BS_, ALS_, BLS_, VA, VB, VAL, VBL)                     \
  {                                                                           \
    _Pragma("unroll") for (int ic = 0; ic < 2; ++ic) {                        \
      int c = ic * 256 + tid;                                                 \
      int r = c >> 2, g = c & 3;                                              \
      int ch = (r * 4 + (g ^ (r & 3) ^ ((r >> 2) & 3))) * 8;                  \
      *(bf16x8*)&AS_[ch] = VA[ic];                                            \
      *(bf16x8*)&BS_[ch] = VB[ic];                                            \
      if (LO) {                                                               \
        *(bf16x8*)&ALS_[ch] = VAL[ic];                                        \
        *(bf16x8*)&BLS_[ch] = VBL[ic];                                        \
      }                                                                       \
    }                                                                         \
  }

#define COMPUTE_SET(AS_, BS_, ALS_, BLS_)                                     \
  {                                                                           \
    bf16x8 ah[4], al[4];                                                      \
    _Pragma("unroll") for (int m = 0; m < 4; ++m) {                           \
      int row = wr * 64 + m * 16 + l15;                                       \
      int idx = (row * 4 + (l4 ^ xorl)) * 8;                                  \
      ah[m] = *(const bf16x8*)&AS_[idx];                                      \
      if (LO) al[m] = *(const bf16x8*)&ALS_[idx];                             \
    }                                                                         \
    _Pragma("unroll") for (int n = 0; n < 4; ++n) {                           \
      int row = wc * 64 + n * 16 + l15;                                       \
      int idx = (row * 4 + (l4 ^ xorl)) * 8;                                  \
      bf16x8 bhn = *(const bf16x8*)&BS_[idx];                                 \
      bf16x8 bln;                                                             \
      if (LO) bln = *(const bf16x8*)&BLS_[idx];                               \
      _Pragma("unroll") for (int m = 0; m < 4; ++m) {                         \
        acc[m][n] = __builtin_amdgcn_mfma_f32_16x16x32_bf16(ah[m], bhn,       \
                                                            acc[m][n], 0, 0, 0); \
        if (LO) {                                                             \
          acc[m][n] = __builtin_amdgcn_mfma_f32_16x16x32_bf16(al[m], bhn,     \
                                                              acc[m][n], 0, 0, 0); \
          acc[m][n] = __builtin_amdgcn_mfma_f32_16x16x32_bf16(ah[m], bln,     \
                                                              acc[m][n], 0, 0, 0); \
        }                                                                     \
      }                                                                       \
    }                                                                         \
  }

  LOAD_SET(vA0, vB0, vAl0, vBl0, kbeg);
  WRITE_SET(As0, Bs0, Als0, Bls0, vA0, vB0, vAl0, vBl0);
  __syncthreads();
  for (int s = 0; s < nsteps; s += 2) {
    int k0 = kbeg + (s << 5);
    bool has1 = (s + 1 < nsteps), has2 = (s + 2 < nsteps);
    if (has1) LOAD_SET(vA1, vB1, vAl1, vBl1, k0 + 32);
    COMPUTE_SET(As0, Bs0, Als0, Bls0);
    if (has1) WRITE_SET(As1, Bs1, Als1, Bls1, vA1, vB1, vAl1, vBl1);
    __syncthreads();
    if (has1) {
      if (has2) LOAD_SET(vA0, vB0, vAl0, vBl0, k0 + 64);
      COMPUTE_SET(As1, Bs1, Als1, Bls1);
      if (has2) WRITE_SET(As0, Bs0, Als0, Bls0, vA0, vB0, vAl0, vBl0);
      __syncthreads();
    }
  }
#undef LOAD_SET
#undef WRITE_SET
#undef COMPUTE_SET

  if (gridDim.z > 1) {
#pragma unroll
    for (int m = 0; m < 4; ++m) {
      int row = m0 + wr * 64 + m * 16 + l4 * 4;
#pragma unroll
      for (int n = 0; n < 4; ++n) {
        int col = n0 + wc * 64 + n * 16 + l15;
#pragma unroll
        for (int q = 0; q < 4; ++q)
          part[((size_t)kz * partM + row + q) * N + col] = acc[m][n][q];
      }
    }
    return;
  }
  // direct out: acc + bias (fp32)
#pragma unroll
  for (int m = 0; m < 4; ++m) {
    int row = m0 + wr * 64 + m * 16 + l4 * 4;
#pragma unroll
    for (int n = 0; n < 4; ++n) {
      int col = n0 + wc * 64 + n * 16 + l15;
      float bv = bias[col];
#pragma unroll
      for (int q = 0; q < 4; ++q)
        dout[(size_t)(row + q) * N + col] = acc[m][n][q] + bv;
    }
  }
}

// ---------------------------------------------------------------------------
// Attention epilogue (fused): WO split-K reduce + residual + rmsnorm2 + router.
__global__ __launch_bounds__(256) void attn_epilogue_kernel(
    const float* __restrict__ part, const float* __restrict__ bo,
    const float* __restrict__ x, const float* __restrict__ n2w,
    const float* __restrict__ wr, const float* __restrict__ br,
    float* __restrict__ x1, float* __restrict__ h2, int* __restrict__ top_i,
    float* __restrict__ top_p, float* __restrict__ probs_out) {
  int t = blockIdx.x;
  int tid = threadIdx.x;
  int c = tid * 4;
  float4 s = *(const float4*)(part + (size_t)t * CD + c);
#pragma unroll
  for (int z = 1; z < 4; ++z) {
    float4 p = *(const float4*)(part + ((size_t)z * CT + t) * CD + c);
    s.x += p.x; s.y += p.y; s.z += p.z; s.w += p.w;
  }
  float4 bv = *(const float4*)(bo + c);
  float4 xv = *(const float4*)(x + (size_t)t * CD + c);
  s.x += bv.x + xv.x; s.y += bv.y + xv.y;
  s.z += bv.z + xv.z; s.w += bv.w + xv.w;
  *(float4*)(x1 + (size_t)t * CD + c) = s;
  float ss = s.x*s.x + s.y*s.y + s.z*s.z + s.w*s.w;
  for (int off = 32; off > 0; off >>= 1) ss += __shfl_down(ss, off);
  __shared__ float red[4];
  __shared__ float s_scale;
  int lane = tid & 63, wid = tid >> 6;
  if (lane == 0) red[wid] = ss;
  __syncthreads();
  if (tid == 0) {
    float tot = red[0] + red[1] + red[2] + red[3];
    s_scale = rsqrtf(tot / (float)CD + CEPS);
  }
  __syncthreads();
  float sc = s_scale;
  float4 wv = *(const float4*)(n2w + c);
  float hv[4] = {s.x * sc * wv.x, s.y * sc * wv.y,
                 s.z * sc * wv.z, s.w * sc * wv.w};
  *(float4*)(h2 + (size_t)t * CD + c) =
      make_float4(hv[0], hv[1], hv[2], hv[3]);
  float a[CE] = {};
#pragma unroll
  for (int j = 0; j < 4; ++j) {
    const float* wrow = wr + (size_t)(c + j) * CE;
#pragma unroll
    for (int e = 0; e < CE; ++e) a[e] += hv[j] * wrow[e];
  }
  __shared__ float red8[256][CE];
#pragma unroll
  for (int e = 0; e < CE; ++e) red8[tid][e] = a[e];
  __syncthreads();
  for (int st = 128; st > 0; st >>= 1) {
    if (tid < st) {
#pragma unroll
      for (int e = 0; e < CE; ++e) red8[tid][e] += red8[tid + st][e];
    }
    __syncthreads();
  }
  if (tid == 0) {
    float probs[CE];
    float mx = -1e30f;
#pragma unroll
    for (int e = 0; e < CE; ++e) {
      probs[e] = red8[0][e] + br[e];
      mx = fmaxf(mx, probs[e]);
    }
    float sum = 0.f;
#pragma unroll
    for (int e = 0; e < CE; ++e) { probs[e] = __expf(probs[e] - mx); sum += probs[e]; }
    float inv = 1.0f / sum;
#pragma unroll
    for (int e = 0; e < CE; ++e) {
      probs[e] *= inv;
      probs_out[t * CE + e] = probs[e];
    }
    int i1 = 0;
#pragma unroll
    for (int e = 1; e < CE; ++e) if (probs[e] > probs[i1]) i1 = e;
    int i2 = (i1 == 0) ? 1 : 0;
#pragma unroll
    for (int e = 0; e < CE; ++e)
      if (e != i1 && probs[e] > probs[i2]) i2 = e;
    float p1 = probs[i1], p2 = probs[i2];
    float s12 = p1 + p2;
    top_i[t * 2 + 0] = i1;
    top_i[t * 2 + 1] = i2;
    top_p[t * 2 + 0] = p1 / s12;
    top_p[t * 2 + 1] = p2 / s12;
  }
}

// ---------------------------------------------------------------------------
// Fused attention v5b (unchanged from round 15).
__global__ __launch_bounds__(256) void fused_attn_kernel(
    const float* __restrict__ qkv, short* __restrict__ ctxh,
    short* __restrict__ ctxl) {
  __shared__ float Qs[32][68];    // Q tile
  __shared__ float KVs[64 * 68];  // K (stride 65) then V (stride 68)
  __shared__ float Pt[32][68];    // per-tile P (stride 68 for float4 reads)
  int qt = blockIdx.x, bh = blockIdx.y;
  int b = bh / CH, h = bh % CH;
  int qrow0 = qt * 32;
  int ktmax = (qrow0 + 31) >> 6;
  int tid = threadIdx.x;
  int cg = tid & 31, rg = tid >> 5;
  int r0 = rg * 4;

  // stage Q [32][64]
#pragma unroll
  for (int it = 0; it < 2; ++it) {
    int idx = it * 256 + tid;
    int r = idx >> 4, c4 = (idx & 15) * 4;
    *(float4*)&Qs[r][c4] = *(const float4*)(
        qkv + (size_t)(b * CS + qrow0 + r) * QKVP + h * CHD + c4);
  }

  float m_i[4], l_i[4], O[4][2];
#pragma unroll
  for (int i = 0; i < 4; ++i) {
    m_i[i] = -1e30f;
    l_i[i] = 0.f;
    O[i][0] = 0.f;
    O[i][1] = 0.f;
  }

  for (int kt = 0; kt <= ktmax; ++kt) {
    __syncthreads();  // prev tile's PV reads of KVs(V)/Pt done
    // stage K (scalar, stride 65)
#pragma unroll
    for (int it = 0; it < 4; ++it) {
      int idx = it * 256 + tid;
      int r = idx >> 4, c4 = (idx & 15) * 4;
      const float* src =
          qkv + (size_t)(b * CS + kt * 64 + r) * QKVP + h * CHD;
      float4 kv = *(const float4*)(src + 1024 + c4);
      KVs[r * 65 + c4 + 0] = kv.x;
      KVs[r * 65 + c4 + 1] = kv.y;
      KVs[r * 65 + c4 + 2] = kv.z;
      KVs[r * 65 + c4 + 3] = kv.w;
    }
    __syncthreads();

    // scores: s[4 rows][2 cols]
    float s[4][2] = {};
#pragma unroll 4
    for (int d = 0; d < 64; ++d) {
      float q0 = Qs[r0 + 0][d];
      float q1 = Qs[r0 + 1][d];
      float q2 = Qs[r0 + 2][d];
      float q3 = Qs[r0 + 3][d];
      float k0 = KVs[(cg * 2 + 0) * 65 + d];
      float k1 = KVs[(cg * 2 + 1) * 65 + d];
      s[0][0] += q0 * k0; s[0][1] += q0 * k1;
      s[1][0] += q1 * k0; s[1][1] += q1 * k1;
      s[2][0] += q2 * k0; s[2][1] += q2 * k1;
      s[3][0] += q3 * k0; s[3][1] += q3 * k1;
    }

    // online softmax update (per row, reduce over 32-lane col group)
#pragma unroll
    for (int i = 0; i < 4; ++i) {
      int gr = qrow0 + r0 + i;
      int gc0 = kt * 64 + cg * 2;
      float s0 = (gc0 + 0 > gr) ? -1e30f : s[i][0] * 0.125f;
      float s1 = (gc0 + 1 > gr) ? -1e30f : s[i][1] * 0.125f;
      float tmax = fmaxf(s0, s1);
#pragma unroll
      for (int off = 16; off > 0; off >>= 1)
        tmax = fmaxf(tmax, __shfl_xor(tmax, off));
      float newm = fmaxf(m_i[i], tmax);
      float p0 = __expf(s0 - newm);
      float p1 = __expf(s1 - newm);
      float tsum = p0 + p1;
#pragma unroll
      for (int off = 16; off > 0; off >>= 1) tsum += __shfl_xor(tsum, off);
      float scale = __expf(m_i[i] - newm);
      l_i[i] = l_i[i] * scale + tsum;
      m_i[i] = newm;
      O[i][0] *= scale;
      O[i][1] *= scale;
      *(float2*)&Pt[r0 + i][cg * 2] = make_float2(p0, p1);
    }
    __syncthreads();  // all K reads + Pt writes done

    // stage V into the same buffer (float4, stride 68)
#pragma unroll
    for (int it = 0; it < 4; ++it) {
      int idx = it * 256 + tid;
      int r = idx >> 4, c4 = (idx & 15) * 4;
      *(float4*)&KVs[r * 68 + c4] = *(const float4*)(
          qkv + (size_t)(b * CS + kt * 64 + r) * QKVP + 2048 + h * CHD + c4);
    }
    __syncthreads();

    // PV: per 4-c chunk, float4 P reads; same FMA order as scalar version.
#pragma unroll 2
    for (int c4 = 0; c4 < 64; c4 += 4) {
      float4 pr[4];
#pragma unroll
      for (int i = 0; i < 4; ++i) pr[i] = *(const float4*)&Pt[r0 + i][c4];
      float pv[4][4] = {{pr[0].x, pr[0].y, pr[0].z, pr[0].w},
                        {pr[1].x, pr[1].y, pr[1].z, pr[1].w},
                        {pr[2].x, pr[2].y, pr[2].z, pr[2].w},
                        {pr[3].x, pr[3].y, pr[3].z, pr[3].w}};
#pragma unroll
      for (int j = 0; j < 4; ++j) {
        int c = c4 + j;
        float v0 = KVs[c * 68 + cg];
        float v1 = KVs[c * 68 + cg + 32];
        O[0][0] += pv[0][j] * v0; O[0][1] += pv[0][j] * v1;
        O[1][0] += pv[1][j] * v0; O[1][1] += pv[1][j] * v1;
        O[2][0] += pv[2][j] * v0; O[2][1] += pv[2][j] * v1;
        O[3][0] += pv[3][j] * v0; O[3][1] += pv[3][j] * v1;
      }
    }
  }

  // epilogue: normalize by l, write hi/lo bf16 planes
#pragma unroll
  for (int i = 0; i < 4; ++i) {
    float inv = 1.0f / l_i[i];
#pragma unroll
    for (int jd = 0; jd < 2; ++jd) {
      int dv = cg + 32 * jd;
      size_t oi = (size_t)(b * CS + qrow0 + r0 + i) * CD + h * CHD + dv;
      float v = O[i][jd] * inv;
      short hi = f2bf(v);
      ctxh[oi] = hi;
      ctxl[oi] = f2bf(v - bf2f(hi));
    }
  }
}

// ---------------------------------------------------------------------------
// Finalize (1 block): counts/psum, offsets, tile map, aux loss, cursor clear.
__global__ __launch_bounds__(256) void finalize_kernel(
    const int* __restrict__ top_i, const float* __restrict__ probs,
    int* __restrict__ offs, int* __restrict__ tile_e,
    int* __restrict__ total_padded, int* __restrict__ row_map,
    int* __restrict__ cursor, float* __restrict__ aux_out) {
  int tid = threadIdx.x;
  __shared__ float redp[256][CE];
  __shared__ int redc[256][CE];
  float lp[CE] = {};
  int lc[CE] = {};
  for (int t = tid; t < CT; t += 256) {
    lc[top_i[t * 2 + 0]]++;
    lc[top_i[t * 2 + 1]]++;
#pragma unroll
    for (int e = 0; e < CE; ++e) lp[e] += probs[t * CE + e];
  }
#pragma unroll
  for (int e = 0; e < CE; ++e) { redp[tid][e] = lp[e]; redc[tid][e] = lc[e]; }
  __syncthreads();
  for (int s = 128; s > 0; s >>= 1) {
    if (tid < s) {
#pragma unroll
      for (int e = 0; e < CE; ++e) {
        redp[tid][e] += redp[tid + s][e];
        redc[tid][e] += redc[tid + s][e];
      }
    }
    __syncthreads();
  }
  __shared__ int s_off[CE + 1];
  if (tid == 0) {
    int o = 0;
    for (int e = 0; e < CE; ++e) {
      s_off[e] = o;
      offs[e] = o;
      o += ((redc[0][e] + 127) >> 7) << 7;
    }
    s_off[CE] = o;
    offs[CE] = o;
    *total_padded = o;
    int nt = o >> 7;
    for (int i = 0; i < nt; ++i) {
      int e = 0;
      while (e < CE - 1 && i * 128 >= s_off[e + 1]) e++;
      tile_e[i] = e;
    }
    float aux = 0.f;
    for (int e = 0; e < CE; ++e)
      aux += ((float)redc[0][e] / (float)(CT * CK)) * (redp[0][e] / (float)CT);
    aux_out[0] = aux * (float)CE;
  }
  if (tid < CE) cursor[tid] = 0;
  __syncthreads();
  for (int i = tid; i < MAXROWS; i += blockDim.x) row_map[i] = -1;
}

__global__ void gather_kernel(const int* __restrict__ top_i,
                              const int* __restrict__ offs,
                              int* __restrict__ cursor, int* __restrict__ row_map,
                              int* __restrict__ row_of) {
  int idx = blockIdx.x * blockDim.x + threadIdx.x;
  if (idx >= CT * CK) return;
  int e = top_i[idx];
  int pos = offs[e] + atomicAdd(&cursor[e], 1);
  row_map[pos] = idx >> 1;
  row_of[idx] = pos;
}

// Xg[row] = bf16(h2[row_map[row]]) or zeros for pad rows.
__global__ __launch_bounds__(256) void gatherx_kernel(
    const float* __restrict__ h2, const int* __restrict__ row_map,
    short* __restrict__ Xg) {
  int row = blockIdx.x;
  int tid = threadIdx.x;
  int tok = row_map[row];
  short4 o;
  if (tok < 0) {
    o = make_short4(0, 0, 0, 0);
  } else {
    float4 v = ((const float4*)(h2 + (size_t)tok * CD))[tid];
    o = make_short4(f2bf(v.x), f2bf(v.y), f2bf(v.z), f2bf(v.w));
  }
  ((short4*)(Xg + (size_t)row * CD))[tid] = o;
}

// Fused GEMM2-reduce + combine: per token, read only its 2 routed rows'
// partials, add b2[e], weight, residual.
__global__ __launch_bounds__(256) void combine_g2_kernel(
    const float* __restrict__ part, int partM, int nz,
    const float* __restrict__ b2, const int* __restrict__ tile_e,
    const int* __restrict__ row_of, const float* __restrict__ top_p,
    const float* __restrict__ x1, float* __restrict__ out) {
  int t = blockIdx.x;
  int c = threadIdx.x * 4;
  float4 r = *(const float4*)(x1 + (size_t)t * CD + c);
#pragma unroll
  for (int s = 0; s < CK; ++s) {
    int row = row_of[t * 2 + s];
    int e = tile_e[row >> 7];
    float w = top_p[t * 2 + s];
    float4 acc = *(const float4*)(part + (size_t)row * CD + c);
    for (int z = 1; z < nz; ++z) {
      float4 p = *(const float4*)(part + ((size_t)z * partM + row) * CD + c);
      acc.x += p.x; acc.y += p.y; acc.z += p.z; acc.w += p.w;
    }
    float4 bv = *(const float4*)(b2 + (size_t)e * CD + c);
    r.x += w * (acc.x + bv.x);
    r.y += w * (acc.y + bv.y);
    r.z += w * (acc.z + bv.z);
    r.w += w * (acc.w + bv.w);
  }
  *(float4*)(out + (size_t)t * CD + c) = r;
}

// ---------------------------------------------------------------------------
extern "C" void kernel_launch(void* const* d_in, const int* in_sizes, int n_in,
                              void* d_out, int out_size, void* d_ws,
                              size_t ws_size, hipStream_t stream) {
  const float* x   = (const float*)d_in[0];
  const float* n1w = (const float*)d_in[1];
  const float* n2w = (const float*)d_in[2];
  const float* wq  = (const float*)d_in[3];
  const float* bq  = (const float*)d_in[4];
  const float* wk  = (const float*)d_in[5];
  const float* bk  = (const float*)d_in[6];
  const float* wv  = (const float*)d_in[7];
  const float* bv  = (const float*)d_in[8];
  const float* wo  = (const float*)d_in[9];
  const float* bo  = (const float*)d_in[10];
  const float* wr  = (const float*)d_in[11];
  const float* br  = (const float*)d_in[12];
  const float* w1  = (const float*)d_in[13];
  const float* b1  = (const float*)d_in[14];
  const float* w2  = (const float*)d_in[15];
  const float* b2  = (const float*)d_in[16];
  float* out = (float*)d_out;

  char* base = (char*)d_ws;
  size_t off = 0;
  auto alloc = [&](size_t bytes) -> void* {
    void* p = base + off;
    off += (bytes + 255) & ~(size_t)255;
    return p;
  };
  float* f_x1   = (float*)alloc((size_t)CT * CD * 4);
  float* f_h2   = (float*)alloc((size_t)CT * CD * 4);
  short* f_xg   = (short*)alloc((size_t)MAXROWS * CD * 2);
  short* f_hid  = (short*)alloc((size_t)MAXROWS * CF * 2);
  short* f_hh   = (short*)alloc((size_t)CT * CD * 2);
  short* f_hl   = (short*)alloc((size_t)CT * CD * 2);
  short* f_wqkvh = (short*)alloc((size_t)QKVP * CD * 2);
  short* f_wqkvl = (short*)alloc((size_t)QKVP * CD * 2);
  float* f_qkv  = (float*)alloc((size_t)CT * QKVP * 4);
  short* f_ctxh = (short*)alloc((size_t)CT * CD * 2);
  short* f_ctxl = (short*)alloc((size_t)CT * CD * 2);
  short* f_woth = (short*)alloc((size_t)CD * CD * 2);
  short* f_wotl = (short*)alloc((size_t)CD * CD * 2);
  float* f_bqkv = (float*)alloc(QKVP * 4);
  float* f_topp = (float*)alloc(CT * CK * 4);
  float* f_probs = (float*)alloc(CT * CE * 4);
  int* i_topi   = (int*)alloc(CT * CK * 4);
  int* i_rowof  = (int*)alloc(CT * CK * 4);
  int* i_rowmap = (int*)alloc(MAXROWS * 4);
  int* i_cursor = (int*)alloc(CE * 4);
  int* i_offs   = (int*)alloc((CE + 1) * 4);
  int* i_tile   = (int*)alloc(MAXTILES * 4);
  int* i_total  = (int*)alloc(4);
  // G (64MB): w1t -> w2t (sequential reuse)
  short* f_wG = (short*)alloc((size_t)CE * CD * CF * 2);
  short* f_w1t = f_wG;
  short* f_w2t = f_wG;
  // Rs (48MB): WO partials -> GEMM2 partials (disjoint)
  void* Rs = alloc((size_t)4 * MAXROWS * CD * 4);
  float* f_partwo = (float*)Rs;
  float* f_partg2 = (float*)Rs;

  dim3 b256(256);

  pack_bias_kernel<<<QKVP / 256, b256, 0, stream>>>(bq, bk, bv, f_bqkv);
  TPtrs tp;
  tp.w[0] = wq; tp.w[1] = wk; tp.w[2] = wv; tp.w[3] = wo;
  tp.hh[0] = f_wqkvh + 0 * (size_t)CD * CD;
  tp.hh[1] = f_wqkvh + 1 * (size_t)CD * CD;
  tp.hh[2] = f_wqkvh + 2 * (size_t)CD * CD;
  tp.hh[3] = f_woth;
  tp.ll[0] = f_wqkvl + 0 * (size_t)CD * CD;
  tp.ll[1] = f_wqkvl + 1 * (size_t)CD * CD;
  tp.ll[2] = f_wqkvl + 2 * (size_t)CD * CD;
  tp.ll[3] = f_wotl;
  transpose4_kernel<<<dim3(16, 16, 4), b256, 0, stream>>>(tp);
  transpose_convert_kernel<<<dim3(CF / 64, CD / 64, CE), b256, 0, stream>>>(
      w1, f_w1t, nullptr, CD, CF);

  // ---- attention ----
  rmsnorm_hl_kernel<<<CT, b256, 0, stream>>>(x, n1w, f_hh, f_hl);
  // QKV: split-K=1, bias fused, direct fp32 out (no reduce pass)
  mfma_gemm_kernel<1><<<dim3(QKVP / 128, CT / 128, 1), b256, 0, stream>>>(
      f_hh, f_hl, f_wqkvh, f_wqkvl, f_bqkv, f_qkv, nullptr, CT, QKVP, CD);
  fused_attn_kernel<<<dim3(CS / 32, CBH), b256, 0, stream>>>(f_qkv, f_ctxh,
                                                             f_ctxl);
  mfma_gemm_kernel<1><<<dim3(CD / 128, CT / 128, 4), b256, 0, stream>>>(
      f_ctxh, f_ctxl, f_woth, f_wotl, nullptr, nullptr, f_partwo, CT, CD, CD);
  attn_epilogue_kernel<<<CT, b256, 0, stream>>>(f_partwo, bo, x, n2w, wr, br,
                                                f_x1, f_h2, i_topi, f_topp,
                                                f_probs);

  // ---- MoE ----
  finalize_kernel<<<1, 256, 0, stream>>>(i_topi, f_probs, i_offs, i_tile,
                                         i_total, i_rowmap, i_cursor,
                                         out + (size_t)CT * CD);
  gather_kernel<<<(CT * CK + 255) / 256, b256, 0, stream>>>(i_topi, i_offs,
                                                            i_cursor, i_rowmap,
                                                            i_rowof);
  gatherx_kernel<<<MAXROWS, b256, 0, stream>>>(f_h2, i_rowmap, f_xg);

  // expert GEMM1: BN=128 -> grid (CF/128=32, tiles)
  moe_gemm_kernel<1, 1><<<dim3(CF / 128, MAXTILES, 1), dim3(512), 0, stream>>>(
      f_xg, f_w1t, b1, f_hid, nullptr, 0, CF, CD, i_tile, i_total);
  transpose_convert_kernel<<<dim3(CD / 64, CF / 64, CE), b256, 0, stream>>>(
      w2, f_w2t, nullptr, CF, CD);
  // expert GEMM2: BN=128, split-K=4 -> grid (CD/128=8, tiles, 4)
  moe_gemm_kernel<0, 0><<<dim3(CD / 128, MAXTILES, 4), dim3(512), 0, stream>>>(
      f_hid, f_w2t, nullptr, nullptr, f_partg2, MAXROWS, CD, CF, i_tile,
      i_total);
  combine_g2_kernel<<<CT, b256, 0, stream>>>(f_partg2, MAXROWS, 4, b2, i_tile,
                                             i_rowof, f_topp, f_x1, out);
}

// Round 17
// 316.251 us; speedup vs baseline: 1.1660x; 1.0397x over previous
//
#include <hip/hip_runtime.h>
#include <math.h>

// Problem constants
#define CB 2
#define CS 512
#define CD 1024
#define CH 16
#define CHD 64
#define CF 4096
#define CE 8
#define CK 2
#define CT (CB*CS)      // 1024 tokens
#define CBH (CB*CH)     // 32 (batch*heads)
#define CEPS 1e-6f
#define QKVP 3072       // packed q|k|v row pitch
#define MAXROWS 3072    // 2048 + 8*127 padded to 128
#define MAXTILES (MAXROWS/128)

typedef __attribute__((ext_vector_type(8))) short bf16x8;
typedef __attribute__((ext_vector_type(4))) float f32x4;

__device__ __forceinline__ short f2bf(float f) {
  unsigned u = __float_as_uint(f);
  unsigned r = (u + 0x7FFF + ((u >> 16) & 1)) >> 16;
  return (short)r;
}
__device__ __forceinline__ float bf2f(short h) {
  return __uint_as_float(((unsigned)(unsigned short)h) << 16);
}

__device__ __forceinline__ void gload_lds16(const void* g, void* l) {
  __builtin_amdgcn_global_load_lds(
      (const __attribute__((address_space(1))) unsigned int*)g,
      (__attribute__((address_space(3))) unsigned int*)l, 16, 0, 0);
}

// ---------------------------------------------------------------------------
// RMSNorm, hi/lo bf16 planes out.
__global__ __launch_bounds__(256) void rmsnorm_hl_kernel(
    const float* __restrict__ x, const float* __restrict__ w,
    short* __restrict__ outH, short* __restrict__ outL) {
  int t = blockIdx.x;
  int tid = threadIdx.x;
  float4 xv = ((const float4*)(x + (size_t)t * CD))[tid];
  float ss = xv.x*xv.x + xv.y*xv.y + xv.z*xv.z + xv.w*xv.w;
  for (int off = 32; off > 0; off >>= 1) ss += __shfl_down(ss, off);
  __shared__ float red[4];
  __shared__ float s_scale;
  int lane = tid & 63, wid = tid >> 6;
  if (lane == 0) red[wid] = ss;
  __syncthreads();
  if (tid == 0) {
    float tot = red[0] + red[1] + red[2] + red[3];
    s_scale = rsqrtf(tot / (float)CD + CEPS);
  }
  __syncthreads();
  float sc = s_scale;
  float4 wv = ((const float4*)w)[tid];
  float o[4] = {xv.x * sc * wv.x, xv.y * sc * wv.y,
                xv.z * sc * wv.z, xv.w * sc * wv.w};
  short4 hi, lo;
  short* hp = (short*)&hi; short* lp = (short*)&lo;
#pragma unroll
  for (int i = 0; i < 4; ++i) {
    short h = f2bf(o[i]);
    hp[i] = h;
    lp[i] = f2bf(o[i] - bf2f(h));
  }
  ((short4*)(outH + (size_t)t * CD))[tid] = hi;
  ((short4*)(outL + (size_t)t * CD))[tid] = lo;
}

// ---------------------------------------------------------------------------
// Tiled transpose+convert, 64x64 tile, 16B short8 stores:
// W[e][Kd][Nd] f32 -> Wth[e][Nd][Kd] bf16 (+ optional lo plane).
__global__ __launch_bounds__(256) void transpose_convert_kernel(
    const float* __restrict__ W, short* __restrict__ Wth,
    short* __restrict__ Wtl, int Kd, int Nd) {
  int e = blockIdx.z;
  const float* Wb = W + (size_t)e * Kd * Nd;
  size_t obase = (size_t)e * Kd * Nd;
  int n0 = blockIdx.x * 64, k0 = blockIdx.y * 64;
  __shared__ float t[64][65];
  int tid = threadIdx.x;
#pragma unroll
  for (int i = 0; i < 4; ++i) {
    int idx = i * 256 + tid;
    int r = idx >> 4, c4 = (idx & 15) * 4;
    float4 v = *(const float4*)(Wb + (size_t)(k0 + r) * Nd + n0 + c4);
    t[r][c4] = v.x; t[r][c4 + 1] = v.y; t[r][c4 + 2] = v.z; t[r][c4 + 3] = v.w;
  }
  __syncthreads();
  int n = tid >> 2, k16 = (tid & 3) * 16;
  short th[16], tl[16];
#pragma unroll
  for (int j = 0; j < 16; ++j) {
    float v = t[k16 + j][n];
    short hi = f2bf(v);
    th[j] = hi;
    tl[j] = f2bf(v - bf2f(hi));
  }
  size_t oo = obase + (size_t)(n0 + n) * Kd + k0 + k16;
  ((int4*)(Wth + oo))[0] = ((int4*)th)[0];
  ((int4*)(Wth + oo + 8))[0] = ((int4*)th)[1];
  if (Wtl) {
    ((int4*)(Wtl + oo))[0] = ((int4*)tl)[0];
    ((int4*)(Wtl + oo + 8))[0] = ((int4*)tl)[1];
  }
}

// Four DxD transposes (wq,wk,wv,wo) + bias packing (z==4) in one launch.
struct TPtrs {
  const float* w[4];
  short* hh[4];
  short* ll[4];
  const float* bq;
  const float* bk;
  const float* bv;
  float* bqkv;
};
__global__ __launch_bounds__(256) void transpose4_kernel(TPtrs p) {
  int z = blockIdx.z;
  if (z == 4) {
    // bias packing: 12 blocks x 256 threads cover QKVP=3072
    if (blockIdx.y == 0 && blockIdx.x < 12) {
      int i = blockIdx.x * 256 + threadIdx.x;
      if (i < QKVP)
        p.bqkv[i] =
            (i < 1024) ? p.bq[i] : (i < 2048 ? p.bk[i - 1024] : p.bv[i - 2048]);
    }
    return;
  }
  const float* Wb = p.w[z];
  short* Wth = p.hh[z];
  short* Wtl = p.ll[z];
  int n0 = blockIdx.x * 64, k0 = blockIdx.y * 64;
  __shared__ float t[64][65];
  int tid = threadIdx.x;
#pragma unroll
  for (int i = 0; i < 4; ++i) {
    int idx = i * 256 + tid;
    int r = idx >> 4, c4 = (idx & 15) * 4;
    float4 v = *(const float4*)(Wb + (size_t)(k0 + r) * CD + n0 + c4);
    t[r][c4] = v.x; t[r][c4 + 1] = v.y; t[r][c4 + 2] = v.z; t[r][c4 + 3] = v.w;
  }
  __syncthreads();
  int n = tid >> 2, k16 = (tid & 3) * 16;
  short th[16], tl[16];
#pragma unroll
  for (int j = 0; j < 16; ++j) {
    float v = t[k16 + j][n];
    short hi = f2bf(v);
    th[j] = hi;
    tl[j] = f2bf(v - bf2f(hi));
  }
  size_t oo = (size_t)(n0 + n) * CD + k0 + k16;
  ((int4*)(Wth + oo))[0] = ((int4*)th)[0];
  ((int4*)(Wth + oo + 8))[0] = ((int4*)th)[1];
  ((int4*)(Wtl + oo))[0] = ((int4*)tl)[0];
  ((int4*)(Wtl + oo + 8))[0] = ((int4*)tl)[1];
}

// ---------------------------------------------------------------------------
// MoE grouped GEMM: BM=128, BN=128, BK=64, 8 waves (2x4; wave out 64x32).
// LDS 64KB -> 2 blocks/CU. A source optionally row_map-indirect (gathered
// from h2b per token; pad rows -> zrow). Per-thread A base pointers computed
// once before the K-loop (gload_lds global addr is per-lane).
template <int SILU, int OUTBF>
__global__ __launch_bounds__(512) void moe_gemm_kernel(
    const short* __restrict__ A, const int* __restrict__ row_map,
    const short* __restrict__ zrow, const short* __restrict__ Bt,
    const float* __restrict__ bias, void* __restrict__ Cout,
    float* __restrict__ part, int partM, int N, int K,
    const int* __restrict__ tile_e, const int* __restrict__ total_rows) {
  __shared__ __align__(16) short A0[128 * 64], A1[128 * 64];
  __shared__ __align__(16) short B0[128 * 64], B1[128 * 64];
  int tid = threadIdx.x;
  int m0 = blockIdx.y * 128, n0 = blockIdx.x * 128;
  if (m0 >= *total_rows) return;
  int e = tile_e[blockIdx.y];
  const short* Bb = Bt + (size_t)e * N * K;
  const float* biasb = bias ? bias + (size_t)e * N : nullptr;
  int kz = blockIdx.z;
  int kchunk = K / gridDim.z;
  int kbeg = kz * kchunk;
  int nsteps = kchunk >> 6;
  int lane = tid & 63, w = tid >> 6;
  int wr = w >> 2, wc = w & 3;  // wave out: rows 64*wr.., cols 32*wc..
  int l15 = lane & 15, l4 = lane >> 4;
  f32x4 acc[4][2] = {};

  // per-thread A base pointers (fixed across K-steps)
  const short* aB[2];
#pragma unroll
  for (int i = 0; i < 2; ++i) {
    int r = (i * 512 + tid) >> 3;
    int grow = m0 + r;
    if (row_map) {
      int tok = row_map[grow];
      aB[i] = (tok < 0) ? zrow : A + (size_t)tok * K;
    } else {
      aB[i] = A + (size_t)grow * K;
    }
  }

#define STAGE(AS_, BS_, KK)                                                   \
  {                                                                           \
    _Pragma("unroll") for (int i = 0; i < 2; ++i) {                           \
      int c = i * 512 + tid;                                                  \
      int r = c >> 3, gs = c & 7;                                             \
      int g = gs ^ (r & 7);                                                   \
      gload_lds16(aB[i] + (KK) + g * 8, &AS_[c * 8]);                         \
    }                                                                         \
    _Pragma("unroll") for (int i = 0; i < 2; ++i) {                           \
      int c = i * 512 + tid;                                                  \
      int r = c >> 3, gs = c & 7;                                             \
      int g = gs ^ (r & 7);                                                   \
      gload_lds16(Bb + (size_t)(n0 + r) * K + (KK) + g * 8, &BS_[c * 8]);     \
    }                                                                         \
  }

#define COMPUTE(AS_, BS_)                                                     \
  {                                                                           \
    _Pragma("unroll") for (int ks = 0; ks < 2; ++ks) {                        \
      bf16x8 a[4], b[2];                                                      \
      _Pragma("unroll") for (int m = 0; m < 4; ++m) {                         \
        int row = wr * 64 + m * 16 + l15;                                     \
        int slot = (ks * 4 + l4) ^ (row & 7);                                 \
        a[m] = *(const bf16x8*)&AS_[(row * 8 + slot) * 8];                    \
      }                                                                       \
      _Pragma("unroll") for (int n = 0; n < 2; ++n) {                         \
        int row = wc * 32 + n * 16 + l15;                                     \
        int slot = (ks * 4 + l4) ^ (row & 7);                                 \
        b[n] = *(const bf16x8*)&BS_[(row * 8 + slot) * 8];                    \
      }                                                                       \
      _Pragma("unroll") for (int m = 0; m < 4; ++m)                           \
      _Pragma("unroll") for (int n = 0; n < 2; ++n)                           \
        acc[m][n] = __builtin_amdgcn_mfma_f32_16x16x32_bf16(a[m], b[n],       \
                                                            acc[m][n], 0, 0, 0); \
    }                                                                         \
  }

  STAGE(A0, B0, kbeg);
  __syncthreads();
  for (int s = 0; s < nsteps; s += 2) {
    int k0 = kbeg + (s << 6);
    bool has1 = (s + 1 < nsteps), has2 = (s + 2 < nsteps);
    if (has1) STAGE(A1, B1, k0 + 64);
    COMPUTE(A0, B0);
    __syncthreads();
    if (has1) {
      if (has2) STAGE(A0, B0, k0 + 128);
      COMPUTE(A1, B1);
      __syncthreads();
    }
  }
#undef STAGE
#undef COMPUTE

  if (gridDim.z > 1) {
#pragma unroll
    for (int m = 0; m < 4; ++m) {
      int row = m0 + wr * 64 + m * 16 + l4 * 4;
#pragma unroll
      for (int n = 0; n < 2; ++n) {
        int col = n0 + wc * 32 + n * 16 + l15;
#pragma unroll
        for (int q = 0; q < 4; ++q)
          part[((size_t)kz * partM + row + q) * N + col] = acc[m][n][q];
      }
    }
    return;
  }
  float* outf = (float*)Cout;
  short* outb = (short*)Cout;
#pragma unroll
  for (int m = 0; m < 4; ++m) {
    int row = m0 + wr * 64 + m * 16 + l4 * 4;
#pragma unroll
    for (int n = 0; n < 2; ++n) {
      int col = n0 + wc * 32 + n * 16 + l15;
      float bv = biasb[col];
#pragma unroll
      for (int q = 0; q < 4; ++q) {
        float v = acc[m][n][q] + bv;
        if (SILU) v = v / (1.f + __expf(-v));
        if (OUTBF) outb[(size_t)(row + q) * N + col] = f2bf(v);
        else outf[(size_t)(row + q) * N + col] = v;
      }
    }
  }
}

// ---------------------------------------------------------------------------
// Attention MFMA GEMM: 128x128, BK=32, 4 waves, hi/lo reg-staged.
// gridDim.z>1: split-K partials. gridDim.z==1: direct fp32 out + bias.
template <int LO>
__global__ __launch_bounds__(256) void mfma_gemm_kernel(
    const short* __restrict__ Ah, const short* __restrict__ Al,
    const short* __restrict__ Bh, const short* __restrict__ Bl,
    const float* __restrict__ bias, float* __restrict__ dout,
    float* __restrict__ part, int partM, int N, int K) {
  __shared__ short As0[4096], Bs0[4096], As1[4096], Bs1[4096];
  __shared__ short Als0[LO ? 4096 : 64], Bls0[LO ? 4096 : 64];
  __shared__ short Als1[LO ? 4096 : 64], Bls1[LO ? 4096 : 64];
  int tid = threadIdx.x;
  int m0 = blockIdx.y * 128, n0 = blockIdx.x * 128;
  int kz = blockIdx.z;
  int kchunk = K / gridDim.z;
  int kbeg = kz * kchunk;
  int nsteps = kchunk >> 5;
  int lane = tid & 63, w = tid >> 6;
  int wr = w >> 1, wc = w & 1;
  int l15 = lane & 15, l4 = lane >> 4;
  int xorl = (l15 & 3) ^ ((l15 >> 2) & 3);
  f32x4 acc[4][4] = {};
  bf16x8 vA0[2], vB0[2], vAl0[2], vBl0[2];
  bf16x8 vA1[2], vB1[2], vAl1[2], vBl1[2];

#define LOAD_SET(VA, VB, VAL, VBL, KK)                                        \
  {                                                                           \
    _Pragma("unroll") for (int ic = 0; ic < 2; ++ic) {                        \
      int c = ic * 256 + tid;                                                 \
      int r = c >> 2, g = c & 3;                                              \
      size_t ao = (size_t)(m0 + r) * K + (KK) + g * 8;                        \
      size_t bo = (size_t)(n0 + r) * K + (KK) + g * 8;                        \
      VA[ic] = *(const bf16x8*)(Ah + ao);                                     \
      VB[ic] = *(const bf16x8*)(Bh + bo);                                     \
      if (LO) {                                                               \
        VAL[ic] = *(const bf16x8*)(Al + ao);                                  \
        VBL[ic] = *(const bf16x8*)(Bl + bo);                                  \
      }                                                                       \
    }                                                                         \
  }

#define WRITE_SET(AS_, BS_, ALS_, BLS_, VA, VB, VAL, VBL)                     \
  {                                                                           \
    _Pragma("unroll") for (int ic = 0; ic < 2; ++ic) {                        \
      int c = ic * 256 + tid;                                                 \
      int r = c >> 2, g = c & 3;                                              \
      int ch = (r * 4 + (g ^ (r & 3) ^ ((r >> 2) & 3))) * 8;                  \
      *(bf16x8*)&AS_[ch] = VA[ic];                                            \
      *(bf16x8*)&BS_[ch] = VB[ic];                                            \
      if (LO) {                                                               \
        *(bf16x8*)&ALS_[ch] = VAL[ic];                                        \
        *(bf16x8*)&BLS_[ch] = VBL[ic];                                        \
      }                                                                       \
    }                                                                         \
  }

#define COMPUTE_SET(AS_, BS_, ALS_, BLS_)                                     \
  {                                                                           \
    bf16x8 ah[4], al[4];                                                      \
    _Pragma("unroll") for (int m = 0; m < 4; ++m) {                           \
      int row = wr * 64 + m * 16 + l15;                                       \
      int idx = (row * 4 + (l4 ^ xorl)) * 8;                                  \
      ah[m] = *(const bf16x8*)&AS_[idx];                                      \
      if (LO) al[m] = *(const bf16x8*)&ALS_[idx];                             \
    }                                                                         \
    _Pragma("unroll") for (int n = 0; n < 4; ++n) {                           \
      int row = wc * 64 + n * 16 + l15;                                       \
      int idx = (row * 4 + (l4 ^ xorl)) * 8;                                  \
      bf16x8 bhn = *(const bf16x8*)&BS_[idx];                                 \
      bf16x8 bln;                                                             \
      if (LO) bln = *(const bf16x8*)&BLS_[idx];                               \
      _Pragma("unroll") for (int m = 0; m < 4; ++m) {                         \
        acc[m][n] = __builtin_amdgcn_mfma_f32_16x16x32_bf16(ah[m], bhn,       \
                                                            acc[m][n], 0, 0, 0); \
        if (LO) {                                                             \
          acc[m][n] = __builtin_amdgcn_mfma_f32_16x16x32_bf16(al[m], bhn,     \
                                                              acc[m][n], 0, 0, 0); \
          acc[m][n] = __builtin_amdgcn_mfma_f32_16x16x32_bf16(ah[m], bln,     \
                                                              acc[m][n], 0, 0, 0); \
        }                                                                     \
      }                                                                       \
    }                                                                         \
  }

  LOAD_SET(vA0, vB0, vAl0, vBl0, kbeg);
  WRITE_SET(As0, Bs0, Als0, Bls0, vA0, vB0, vAl0, vBl0);
  __syncthreads();
  for (int s = 0; s < nsteps; s += 2) {
    int k0 = kbeg + (s << 5);
    bool has1 = (s + 1 < nsteps), has2 = (s + 2 < nsteps);
    if (has1) LOAD_SET(vA1, vB1, vAl1, vBl1, k0 + 32);
    COMPUTE_SET(As0, Bs0, Als0, Bls0);
    if (has1) WRITE_SET(As1, Bs1, Als1, Bls1, vA1, vB1, vAl1, vBl1);
    __syncthreads();
    if (has1) {
      if (has2) LOAD_SET(vA0, vB0, vAl0, vBl0, k0 + 64);
      COMPUTE_SET(As1, Bs1, Als1, Bls1);
      if (has2) WRITE_SET(As0, Bs0, Als0, Bls0, vA0, vB0, vAl0, vBl0);
      __syncthreads();
    }
  }
#undef LOAD_SET
#undef WRITE_SET
#undef COMPUTE_SET

  if (gridDim.z > 1) {
#pragma unroll
    for (int m = 0; m < 4; ++m) {
      int row = m0 + wr * 64 + m * 16 + l4 * 4;
#pragma unroll
      for (int n = 0; n < 4; ++n) {
        int col = n0 + wc * 64 + n * 16 + l15;
#pragma unroll
        for (int q = 0; q < 4; ++q)
          part[((size_t)kz * partM + row + q) * N + col] = acc[m][n][q];
      }
    }
    return;
  }
  // direct out: acc + bias (fp32)
#pragma unroll
  for (int m = 0; m < 4; ++m) {
    int row = m0 + wr * 64 + m * 16 + l4 * 4;
#pragma unroll
    for (int n = 0; n < 4; ++n) {
      int col = n0 + wc * 64 + n * 16 + l15;
      float bv = bias[col];
#pragma unroll
      for (int q = 0; q < 4; ++q)
        dout[(size_t)(row + q) * N + col] = acc[m][n][q] + bv;
    }
  }
}

// ---------------------------------------------------------------------------
// Attention epilogue (fused): WO split-K reduce + residual + rmsnorm2 +
// router. h2 written directly as bf16 (feeds MoE GEMM1's gathered A).
__global__ __launch_bounds__(256) void attn_epilogue_kernel(
    const float* __restrict__ part, const float* __restrict__ bo,
    const float* __restrict__ x, const float* __restrict__ n2w,
    const float* __restrict__ wr, const float* __restrict__ br,
    float* __restrict__ x1, short* __restrict__ h2b, int* __restrict__ top_i,
    float* __restrict__ top_p, float* __restrict__ probs_out) {
  int t = blockIdx.x;
  int tid = threadIdx.x;
  int c = tid * 4;
  float4 s = *(const float4*)(part + (size_t)t * CD + c);
#pragma unroll
  for (int z = 1; z < 4; ++z) {
    float4 p = *(const float4*)(part + ((size_t)z * CT + t) * CD + c);
    s.x += p.x; s.y += p.y; s.z += p.z; s.w += p.w;
  }
  float4 bv = *(const float4*)(bo + c);
  float4 xv = *(const float4*)(x + (size_t)t * CD + c);
  s.x += bv.x + xv.x; s.y += bv.y + xv.y;
  s.z += bv.z + xv.z; s.w += bv.w + xv.w;
  *(float4*)(x1 + (size_t)t * CD + c) = s;
  float ss = s.x*s.x + s.y*s.y + s.z*s.z + s.w*s.w;
  for (int off = 32; off > 0; off >>= 1) ss += __shfl_down(ss, off);
  __shared__ float red[4];
  __shared__ float s_scale;
  int lane = tid & 63, wid = tid >> 6;
  if (lane == 0) red[wid] = ss;
  __syncthreads();
  if (tid == 0) {
    float tot = red[0] + red[1] + red[2] + red[3];
    s_scale = rsqrtf(tot / (float)CD + CEPS);
  }
  __syncthreads();
  float sc = s_scale;
  float4 wv = *(const float4*)(n2w + c);
  float hv[4] = {s.x * sc * wv.x, s.y * sc * wv.y,
                 s.z * sc * wv.z, s.w * sc * wv.w};
  short4 hb = make_short4(f2bf(hv[0]), f2bf(hv[1]), f2bf(hv[2]), f2bf(hv[3]));
  ((short4*)(h2b + (size_t)t * CD))[tid] = hb;
  float a[CE] = {};
#pragma unroll
  for (int j = 0; j < 4; ++j) {
    const float* wrow = wr + (size_t)(c + j) * CE;
#pragma unroll
    for (int e = 0; e < CE; ++e) a[e] += hv[j] * wrow[e];
  }
  __shared__ float red8[256][CE];
#pragma unroll
  for (int e = 0; e < CE; ++e) red8[tid][e] = a[e];
  __syncthreads();
  for (int st = 128; st > 0; st >>= 1) {
    if (tid < st) {
#pragma unroll
      for (int e = 0; e < CE; ++e) red8[tid][e] += red8[tid + st][e];
    }
    __syncthreads();
  }
  if (tid == 0) {
    float probs[CE];
    float mx = -1e30f;
#pragma unroll
    for (int e = 0; e < CE; ++e) {
      probs[e] = red8[0][e] + br[e];
      mx = fmaxf(mx, probs[e]);
    }
    float sum = 0.f;
#pragma unroll
    for (int e = 0; e < CE; ++e) { probs[e] = __expf(probs[e] - mx); sum += probs[e]; }
    float inv = 1.0f / sum;
#pragma unroll
    for (int e = 0; e < CE; ++e) {
      probs[e] *= inv;
      probs_out[t * CE + e] = probs[e];
    }
    int i1 = 0;
#pragma unroll
    for (int e = 1; e < CE; ++e) if (probs[e] > probs[i1]) i1 = e;
    int i2 = (i1 == 0) ? 1 : 0;
#pragma unroll
    for (int e = 0; e < CE; ++e)
      if (e != i1 && probs[e] > probs[i2]) i2 = e;
    float p1 = probs[i1], p2 = probs[i2];
    float s12 = p1 + p2;
    top_i[t * 2 + 0] = i1;
    top_i[t * 2 + 1] = i2;
    top_p[t * 2 + 0] = p1 / s12;
    top_p[t * 2 + 1] = p2 / s12;
  }
}

// ---------------------------------------------------------------------------
// Fused attention v5b (unchanged from round 15/16).
__global__ __launch_bounds__(256) void fused_attn_kernel(
    const float* __restrict__ qkv, short* __restrict__ ctxh,
    short* __restrict__ ctxl) {
  __shared__ float Qs[32][68];    // Q tile
  __shared__ float KVs[64 * 68];  // K (stride 65) then V (stride 68)
  __shared__ float Pt[32][68];    // per-tile P (stride 68 for float4 reads)
  int qt = blockIdx.x, bh = blockIdx.y;
  int b = bh / CH, h = bh % CH;
  int qrow0 = qt * 32;
  int ktmax = (qrow0 + 31) >> 6;
  int tid = threadIdx.x;
  int cg = tid & 31, rg = tid >> 5;
  int r0 = rg * 4;

  // stage Q [32][64]
#pragma unroll
  for (int it = 0; it < 2; ++it) {
    int idx = it * 256 + tid;
    int r = idx >> 4, c4 = (idx & 15) * 4;
    *(float4*)&Qs[r][c4] = *(const float4*)(
        qkv + (size_t)(b * CS + qrow0 + r) * QKVP + h * CHD + c4);
  }

  float m_i[4], l_i[4], O[4][2];
#pragma unroll
  for (int i = 0; i < 4; ++i) {
    m_i[i] = -1e30f;
    l_i[i] = 0.f;
    O[i][0] = 0.f;
    O[i][1] = 0.f;
  }

  for (int kt = 0; kt <= ktmax; ++kt) {
    __syncthreads();  // prev tile's PV reads of KVs(V)/Pt done
    // stage K (scalar, stride 65)
#pragma unroll
    for (int it = 0; it < 4; ++it) {
      int idx = it * 256 + tid;
      int r = idx >> 4, c4 = (idx & 15) * 4;
      const float* src =
          qkv + (size_t)(b * CS + kt * 64 + r) * QKVP + h * CHD;
      float4 kv = *(const float4*)(src + 1024 + c4);
      KVs[r * 65 + c4 + 0] = kv.x;
      KVs[r * 65 + c4 + 1] = kv.y;
      KVs[r * 65 + c4 + 2] = kv.z;
      KVs[r * 65 + c4 + 3] = kv.w;
    }
    __syncthreads();

    // scores: s[4 rows][2 cols]
    float s[4][2] = {};
#pragma unroll 4
    for (int d = 0; d < 64; ++d) {
      float q0 = Qs[r0 + 0][d];
      float q1 = Qs[r0 + 1][d];
      float q2 = Qs[r0 + 2][d];
      float q3 = Qs[r0 + 3][d];
      float k0 = KVs[(cg * 2 + 0) * 65 + d];
      float k1 = KVs[(cg * 2 + 1) * 65 + d];
      s[0][0] += q0 * k0; s[0][1] += q0 * k1;
      s[1][0] += q1 * k0; s[1][1] += q1 * k1;
      s[2][0] += q2 * k0; s[2][1] += q2 * k1;
      s[3][0] += q3 * k0; s[3][1] += q3 * k1;
    }

    // online softmax update (per row, reduce over 32-lane col group)
#pragma unroll
    for (int i = 0; i < 4; ++i) {
      int gr = qrow0 + r0 + i;
      int gc0 = kt * 64 + cg * 2;
      float s0 = (gc0 + 0 > gr) ? -1e30f : s[i][0] * 0.125f;
      float s1 = (gc0 + 1 > gr) ? -1e30f : s[i][1] * 0.125f;
      float tmax = fmaxf(s0, s1);
#pragma unroll
      for (int off = 16; off > 0; off >>= 1)
        tmax = fmaxf(tmax, __shfl_xor(tmax, off));
      float newm = fmaxf(m_i[i], tmax);
      float p0 = __expf(s0 - newm);
      float p1 = __expf(s1 - newm);
      float tsum = p0 + p1;
#pragma unroll
      for (int off = 16; off > 0; off >>= 1) tsum += __shfl_xor(tsum, off);
      float scale = __expf(m_i[i] - newm);
      l_i[i] = l_i[i] * scale + tsum;
      m_i[i] = newm;
      O[i][0] *= scale;
      O[i][1] *= scale;
      *(float2*)&Pt[r0 + i][cg * 2] = make_float2(p0, p1);
    }
    __syncthreads();  // all K reads + Pt writes done

    // stage V into the same buffer (float4, stride 68)
#pragma unroll
    for (int it = 0; it < 4; ++it) {
      int idx = it * 256 + tid;
      int r = idx >> 4, c4 = (idx & 15) * 4;
      *(float4*)&KVs[r * 68 + c4] = *(const float4*)(
          qkv + (size_t)(b * CS + kt * 64 + r) * QKVP + 2048 + h * CHD + c4);
    }
    __syncthreads();

    // PV: per 4-c chunk, float4 P reads; same FMA order as scalar version.
#pragma unroll 2
    for (int c4 = 0; c4 < 64; c4 += 4) {
      float4 pr[4];
#pragma unroll
      for (int i = 0; i < 4; ++i) pr[i] = *(const float4*)&Pt[r0 + i][c4];
      float pv[4][4] = {{pr[0].x, pr[0].y, pr[0].z, pr[0].w},
                        {pr[1].x, pr[1].y, pr[1].z, pr[1].w},
                        {pr[2].x, pr[2].y, pr[2].z, pr[2].w},
                        {pr[3].x, pr[3].y, pr[3].z, pr[3].w}};
#pragma unroll
      for (int j = 0; j < 4; ++j) {
        int c = c4 + j;
        float v0 = KVs[c * 68 + cg];
        float v1 = KVs[c * 68 + cg + 32];
        O[0][0] += pv[0][j] * v0; O[0][1] += pv[0][j] * v1;
        O[1][0] += pv[1][j] * v0; O[1][1] += pv[1][j] * v1;
        O[2][0] += pv[2][j] * v0; O[2][1] += pv[2][j] * v1;
        O[3][0] += pv[3][j] * v0; O[3][1] += pv[3][j] * v1;
      }
    }
  }

  // epilogue: normalize by l, write hi/lo bf16 planes
#pragma unroll
  for (int i = 0; i < 4; ++i) {
    float inv = 1.0f / l_i[i];
#pragma unroll
    for (int jd = 0; jd < 2; ++jd) {
      int dv = cg + 32 * jd;
      size_t oi = (size_t)(b * CS + qrow0 + r0 + i) * CD + h * CHD + dv;
      float v = O[i][jd] * inv;
      short hi = f2bf(v);
      ctxh[oi] = hi;
      ctxl[oi] = f2bf(v - bf2f(hi));
    }
  }
}

// ---------------------------------------------------------------------------
// Finalize (1 block): counts/psum, offsets, tile map, aux loss, cursor clear,
// zero-row fill (pad-row A source for MoE GEMM1).
__global__ __launch_bounds__(256) void finalize_kernel(
    const int* __restrict__ top_i, const float* __restrict__ probs,
    int* __restrict__ offs, int* __restrict__ tile_e,
    int* __restrict__ total_padded, int* __restrict__ row_map,
    int* __restrict__ cursor, short* __restrict__ zrow,
    float* __restrict__ aux_out) {
  int tid = threadIdx.x;
  __shared__ float redp[256][CE];
  __shared__ int redc[256][CE];
  float lp[CE] = {};
  int lc[CE] = {};
  for (int t = tid; t < CT; t += 256) {
    lc[top_i[t * 2 + 0]]++;
    lc[top_i[t * 2 + 1]]++;
#pragma unroll
    for (int e = 0; e < CE; ++e) lp[e] += probs[t * CE + e];
  }
#pragma unroll
  for (int e = 0; e < CE; ++e) { redp[tid][e] = lp[e]; redc[tid][e] = lc[e]; }
  __syncthreads();
  for (int s = 128; s > 0; s >>= 1) {
    if (tid < s) {
#pragma unroll
      for (int e = 0; e < CE; ++e) {
        redp[tid][e] += redp[tid + s][e];
        redc[tid][e] += redc[tid + s][e];
      }
    }
    __syncthreads();
  }
  __shared__ int s_off[CE + 1];
  if (tid == 0) {
    int o = 0;
    for (int e = 0; e < CE; ++e) {
      s_off[e] = o;
      offs[e] = o;
      o += ((redc[0][e] + 127) >> 7) << 7;
    }
    s_off[CE] = o;
    offs[CE] = o;
    *total_padded = o;
    int nt = o >> 7;
    for (int i = 0; i < nt; ++i) {
      int e = 0;
      while (e < CE - 1 && i * 128 >= s_off[e + 1]) e++;
      tile_e[i] = e;
    }
    float aux = 0.f;
    for (int e = 0; e < CE; ++e)
      aux += ((float)redc[0][e] / (float)(CT * CK)) * (redp[0][e] / (float)CT);
    aux_out[0] = aux * (float)CE;
  }
  if (tid < CE) cursor[tid] = 0;
  ((short4*)zrow)[tid] = make_short4(0, 0, 0, 0);  // 256*4 = 1024 shorts
  __syncthreads();
  for (int i = tid; i < MAXROWS; i += blockDim.x) row_map[i] = -1;
}

__global__ void gather_kernel(const int* __restrict__ top_i,
                              const int* __restrict__ offs,
                              int* __restrict__ cursor, int* __restrict__ row_map,
                              int* __restrict__ row_of) {
  int idx = blockIdx.x * blockDim.x + threadIdx.x;
  if (idx >= CT * CK) return;
  int e = top_i[idx];
  int pos = offs[e] + atomicAdd(&cursor[e], 1);
  row_map[pos] = idx >> 1;
  row_of[idx] = pos;
}

// Fused GEMM2-reduce + combine: per token, read only its 2 routed rows'
// partials, add b2[e], weight, residual.
__global__ __launch_bounds__(256) void combine_g2_kernel(
    const float* __restrict__ part, int partM, int nz,
    const float* __restrict__ b2, const int* __restrict__ tile_e,
    const int* __restrict__ row_of, const float* __restrict__ top_p,
    const float* __restrict__ x1, float* __restrict__ out) {
  int t = blockIdx.x;
  int c = threadIdx.x * 4;
  float4 r = *(const float4*)(x1 + (size_t)t * CD + c);
#pragma unroll
  for (int s = 0; s < CK; ++s) {
    int row = row_of[t * 2 + s];
    int e = tile_e[row >> 7];
    float w = top_p[t * 2 + s];
    float4 acc = *(const float4*)(part + (size_t)row * CD + c);
    for (int z = 1; z < nz; ++z) {
      float4 p = *(const float4*)(part + ((size_t)z * partM + row) * CD + c);
      acc.x += p.x; acc.y += p.y; acc.z += p.z; acc.w += p.w;
    }
    float4 bv = *(const float4*)(b2 + (size_t)e * CD + c);
    r.x += w * (acc.x + bv.x);
    r.y += w * (acc.y + bv.y);
    r.z += w * (acc.z + bv.z);
    r.w += w * (acc.w + bv.w);
  }
  *(float4*)(out + (size_t)t * CD + c) = r;
}

// ---------------------------------------------------------------------------
extern "C" void kernel_launch(void* const* d_in, const int* in_sizes, int n_in,
                              void* d_out, int out_size, void* d_ws,
                              size_t ws_size, hipStream_t stream) {
  const float* x   = (const float*)d_in[0];
  const float* n1w = (const float*)d_in[1];
  const float* n2w = (const float*)d_in[2];
  const float* wq  = (const float*)d_in[3];
  const float* bq  = (const float*)d_in[4];
  const float* wk  = (const float*)d_in[5];
  const float* bk  = (const float*)d_in[6];
  const float* wv  = (const float*)d_in[7];
  const float* bv  = (const float*)d_in[8];
  const float* wo  = (const float*)d_in[9];
  const float* bo  = (const float*)d_in[10];
  const float* wr  = (const float*)d_in[11];
  const float* br  = (const float*)d_in[12];
  const float* w1  = (const float*)d_in[13];
  const float* b1  = (const float*)d_in[14];
  const float* w2  = (const float*)d_in[15];
  const float* b2  = (const float*)d_in[16];
  float* out = (float*)d_out;

  char* base = (char*)d_ws;
  size_t off = 0;
  auto alloc = [&](size_t bytes) -> void* {
    void* p = base + off;
    off += (bytes + 255) & ~(size_t)255;
    return p;
  };
  float* f_x1   = (float*)alloc((size_t)CT * CD * 4);
  short* f_h2b  = (short*)alloc((size_t)CT * CD * 2);   // bf16 h2 (MoE input)
  short* f_hid  = (short*)alloc((size_t)MAXROWS * CF * 2);
  short* f_hh   = (short*)alloc((size_t)CT * CD * 2);
  short* f_hl   = (short*)alloc((size_t)CT * CD * 2);
  short* f_wqkvh = (short*)alloc((size_t)QKVP * CD * 2);
  short* f_wqkvl = (short*)alloc((size_t)QKVP * CD * 2);
  float* f_qkv  = (float*)alloc((size_t)CT * QKVP * 4);
  short* f_ctxh = (short*)alloc((size_t)CT * CD * 2);
  short* f_ctxl = (short*)alloc((size_t)CT * CD * 2);
  short* f_woth = (short*)alloc((size_t)CD * CD * 2);
  short* f_wotl = (short*)alloc((size_t)CD * CD * 2);
  float* f_bqkv = (float*)alloc(QKVP * 4);
  float* f_topp = (float*)alloc(CT * CK * 4);
  float* f_probs = (float*)alloc(CT * CE * 4);
  short* f_zrow = (short*)alloc(CD * 2);
  int* i_topi   = (int*)alloc(CT * CK * 4);
  int* i_rowof  = (int*)alloc(CT * CK * 4);
  int* i_rowmap = (int*)alloc(MAXROWS * 4);
  int* i_cursor = (int*)alloc(CE * 4);
  int* i_offs   = (int*)alloc((CE + 1) * 4);
  int* i_tile   = (int*)alloc(MAXTILES * 4);
  int* i_total  = (int*)alloc(4);
  // G (64MB): w1t -> w2t (sequential reuse)
  short* f_wG = (short*)alloc((size_t)CE * CD * CF * 2);
  short* f_w1t = f_wG;
  short* f_w2t = f_wG;
  // Rs (48MB): WO partials -> GEMM2 partials (disjoint)
  void* Rs = alloc((size_t)4 * MAXROWS * CD * 4);
  float* f_partwo = (float*)Rs;
  float* f_partg2 = (float*)Rs;

  dim3 b256(256);

  TPtrs tp;
  tp.w[0] = wq; tp.w[1] = wk; tp.w[2] = wv; tp.w[3] = wo;
  tp.hh[0] = f_wqkvh + 0 * (size_t)CD * CD;
  tp.hh[1] = f_wqkvh + 1 * (size_t)CD * CD;
  tp.hh[2] = f_wqkvh + 2 * (size_t)CD * CD;
  tp.hh[3] = f_woth;
  tp.ll[0] = f_wqkvl + 0 * (size_t)CD * CD;
  tp.ll[1] = f_wqkvl + 1 * (size_t)CD * CD;
  tp.ll[2] = f_wqkvl + 2 * (size_t)CD * CD;
  tp.ll[3] = f_wotl;
  tp.bq = bq; tp.bk = bk; tp.bv = bv; tp.bqkv = f_bqkv;
  transpose4_kernel<<<dim3(16, 16, 5), b256, 0, stream>>>(tp);
  transpose_convert_kernel<<<dim3(CF / 64, CD / 64, CE), b256, 0, stream>>>(
      w1, f_w1t, nullptr, CD, CF);

  // ---- attention ----
  rmsnorm_hl_kernel<<<CT, b256, 0, stream>>>(x, n1w, f_hh, f_hl);
  // QKV: split-K=1, bias fused, direct fp32 out (no reduce pass)
  mfma_gemm_kernel<1><<<dim3(QKVP / 128, CT / 128, 1), b256, 0, stream>>>(
      f_hh, f_hl, f_wqkvh, f_wqkvl, f_bqkv, f_qkv, nullptr, CT, QKVP, CD);
  fused_attn_kernel<<<dim3(CS / 32, CBH), b256, 0, stream>>>(f_qkv, f_ctxh,
                                                             f_ctxl);
  mfma_gemm_kernel<1><<<dim3(CD / 128, CT / 128, 4), b256, 0, stream>>>(
      f_ctxh, f_ctxl, f_woth, f_wotl, nullptr, nullptr, f_partwo, CT, CD, CD);
  attn_epilogue_kernel<<<CT, b256, 0, stream>>>(f_partwo, bo, x, n2w, wr, br,
                                                f_x1, f_h2b, i_topi, f_topp,
                                                f_probs);

  // ---- MoE ----
  finalize_kernel<<<1, 256, 0, stream>>>(i_topi, f_probs, i_offs, i_tile,
                                         i_total, i_rowmap, i_cursor, f_zrow,
                                         out + (size_t)CT * CD);
  gather_kernel<<<(CT * CK + 255) / 256, b256, 0, stream>>>(i_topi, i_offs,
                                                            i_cursor, i_rowmap,
                                                            i_rowof);

  // expert GEMM1: A gathered via row_map from bf16 h2 (no Xg materialization)
  moe_gemm_kernel<1, 1><<<dim3(CF / 128, MAXTILES, 1), dim3(512), 0, stream>>>(
      f_h2b, i_rowmap, f_zrow, f_w1t, b1, f_hid, nullptr, 0, CF, CD, i_tile,
      i_total);
  transpose_convert_kernel<<<dim3(CD / 64, CF / 64, CE), b256, 0, stream>>>(
      w2, f_w2t, nullptr, CF, CD);
  // expert GEMM2: BN=128, split-K=4
  moe_gemm_kernel<0, 0><<<dim3(CD / 128, MAXTILES, 4), dim3(512), 0, stream>>>(
      f_hid, nullptr, nullptr, f_w2t, nullptr, nullptr, f_partg2, MAXROWS, CD,
      CF, i_tile, i_total);
  combine_g2_kernel<<<CT, b256, 0, stream>>>(f_partg2, MAXROWS, 4, b2, i_tile,
                                             i_rowof, f_topp, f_x1, out);
}

// Round 18
// 311.044 us; speedup vs baseline: 1.1855x; 1.0167x over previous
//
#include <hip/hip_runtime.h>
#include <math.h>

// Problem constants
#define CB 2
#define CS 512
#define CD 1024
#define CH 16
#define CHD 64
#define CF 4096
#define CE 8
#define CK 2
#define CT (CB*CS)      // 1024 tokens
#define CBH (CB*CH)     // 32 (batch*heads)
#define CEPS 1e-6f
#define QKVP 3072       // packed q|k|v row pitch
#define MAXROWS 3072    // 2048 + 8*127 padded to 128
#define MAXTILES (MAXROWS/128)

typedef __attribute__((ext_vector_type(8))) short bf16x8;
typedef __attribute__((ext_vector_type(4))) float f32x4;

__device__ __forceinline__ short f2bf(float f) {
  unsigned u = __float_as_uint(f);
  unsigned r = (u + 0x7FFF + ((u >> 16) & 1)) >> 16;
  return (short)r;
}
__device__ __forceinline__ float bf2f(short h) {
  return __uint_as_float(((unsigned)(unsigned short)h) << 16);
}

__device__ __forceinline__ void gload_lds16(const void* g, void* l) {
  __builtin_amdgcn_global_load_lds(
      (const __attribute__((address_space(1))) unsigned int*)g,
      (__attribute__((address_space(3))) unsigned int*)l, 16, 0, 0);
}

// ---------------------------------------------------------------------------
// Tiled transpose+convert, 64x64 tile, 16B short8 stores:
// W[e][Kd][Nd] f32 -> Wth[e][Nd][Kd] bf16 (+ optional lo plane).
__global__ __launch_bounds__(256) void transpose_convert_kernel(
    const float* __restrict__ W, short* __restrict__ Wth,
    short* __restrict__ Wtl, int Kd, int Nd) {
  int e = blockIdx.z;
  const float* Wb = W + (size_t)e * Kd * Nd;
  size_t obase = (size_t)e * Kd * Nd;
  int n0 = blockIdx.x * 64, k0 = blockIdx.y * 64;
  __shared__ float t[64][65];
  int tid = threadIdx.x;
#pragma unroll
  for (int i = 0; i < 4; ++i) {
    int idx = i * 256 + tid;
    int r = idx >> 4, c4 = (idx & 15) * 4;
    float4 v = *(const float4*)(Wb + (size_t)(k0 + r) * Nd + n0 + c4);
    t[r][c4] = v.x; t[r][c4 + 1] = v.y; t[r][c4 + 2] = v.z; t[r][c4 + 3] = v.w;
  }
  __syncthreads();
  int n = tid >> 2, k16 = (tid & 3) * 16;
  short th[16], tl[16];
#pragma unroll
  for (int j = 0; j < 16; ++j) {
    float v = t[k16 + j][n];
    short hi = f2bf(v);
    th[j] = hi;
    tl[j] = f2bf(v - bf2f(hi));
  }
  size_t oo = obase + (size_t)(n0 + n) * Kd + k0 + k16;
  ((int4*)(Wth + oo))[0] = ((int4*)th)[0];
  ((int4*)(Wth + oo + 8))[0] = ((int4*)th)[1];
  if (Wtl) {
    ((int4*)(Wtl + oo))[0] = ((int4*)tl)[0];
    ((int4*)(Wtl + oo + 8))[0] = ((int4*)tl)[1];
  }
}

// Four DxD transposes (wq,wk,wv,wo), bias packing (z==4), rmsnorm1 (z==5).
struct TPtrs {
  const float* w[4];
  short* hh[4];
  short* ll[4];
  const float* bq;
  const float* bk;
  const float* bv;
  float* bqkv;
  const float* xin;
  const float* n1w;
  short* hH;
  short* hL;
};
__global__ __launch_bounds__(256) void transpose4_kernel(TPtrs p) {
  int z = blockIdx.z;
  int tid = threadIdx.x;
  if (z == 4) {
    // bias packing: 12 blocks x 256 threads cover QKVP=3072
    if (blockIdx.y == 0 && blockIdx.x < 12) {
      int i = blockIdx.x * 256 + tid;
      if (i < QKVP)
        p.bqkv[i] =
            (i < 1024) ? p.bq[i] : (i < 2048 ? p.bk[i - 1024] : p.bv[i - 2048]);
    }
    return;
  }
  if (z == 5) {
    // rmsnorm1 hi/lo: 256 blocks x 4 tokens each
    __shared__ float red[4];
    __shared__ float s_scale;
    int bid = blockIdx.y * 16 + blockIdx.x;
    int lane = tid & 63, wid = tid >> 6;
    for (int tt = 0; tt < 4; ++tt) {
      int t = bid * 4 + tt;
      float4 xv = ((const float4*)(p.xin + (size_t)t * CD))[tid];
      float ss = xv.x*xv.x + xv.y*xv.y + xv.z*xv.z + xv.w*xv.w;
      for (int off = 32; off > 0; off >>= 1) ss += __shfl_down(ss, off);
      if (lane == 0) red[wid] = ss;
      __syncthreads();
      if (tid == 0) {
        float tot = red[0] + red[1] + red[2] + red[3];
        s_scale = rsqrtf(tot / (float)CD + CEPS);
      }
      __syncthreads();
      float sc = s_scale;
      float4 wv = ((const float4*)p.n1w)[tid];
      float o[4] = {xv.x * sc * wv.x, xv.y * sc * wv.y,
                    xv.z * sc * wv.z, xv.w * sc * wv.w};
      short4 hi, lo;
      short* hp = (short*)&hi; short* lp = (short*)&lo;
#pragma unroll
      for (int i = 0; i < 4; ++i) {
        short h = f2bf(o[i]);
        hp[i] = h;
        lp[i] = f2bf(o[i] - bf2f(h));
      }
      ((short4*)(p.hH + (size_t)t * CD))[tid] = hi;
      ((short4*)(p.hL + (size_t)t * CD))[tid] = lo;
      __syncthreads();
    }
    return;
  }
  const float* Wb = p.w[z];
  short* Wth = p.hh[z];
  short* Wtl = p.ll[z];
  int n0 = blockIdx.x * 64, k0 = blockIdx.y * 64;
  __shared__ float t[64][65];
#pragma unroll
  for (int i = 0; i < 4; ++i) {
    int idx = i * 256 + tid;
    int r = idx >> 4, c4 = (idx & 15) * 4;
    float4 v = *(const float4*)(Wb + (size_t)(k0 + r) * CD + n0 + c4);
    t[r][c4] = v.x; t[r][c4 + 1] = v.y; t[r][c4 + 2] = v.z; t[r][c4 + 3] = v.w;
  }
  __syncthreads();
  int n = tid >> 2, k16 = (tid & 3) * 16;
  short th[16], tl[16];
#pragma unroll
  for (int j = 0; j < 16; ++j) {
    float v = t[k16 + j][n];
    short hi = f2bf(v);
    th[j] = hi;
    tl[j] = f2bf(v - bf2f(hi));
  }
  size_t oo = (size_t)(n0 + n) * CD + k0 + k16;
  ((int4*)(Wth + oo))[0] = ((int4*)th)[0];
  ((int4*)(Wth + oo + 8))[0] = ((int4*)th)[1];
  ((int4*)(Wtl + oo))[0] = ((int4*)tl)[0];
  ((int4*)(Wtl + oo + 8))[0] = ((int4*)tl)[1];
}

// ---------------------------------------------------------------------------
// MoE grouped GEMM: BM=128, BN=128, BK=64, 8 waves (2x4; wave out 64x32).
// LDS 64KB -> 2 blocks/CU. A source optionally row_map-indirect.
template <int SILU, int OUTBF>
__global__ __launch_bounds__(512) void moe_gemm_kernel(
    const short* __restrict__ A, const int* __restrict__ row_map,
    const short* __restrict__ zrow, const short* __restrict__ Bt,
    const float* __restrict__ bias, void* __restrict__ Cout,
    float* __restrict__ part, int partM, int N, int K,
    const int* __restrict__ tile_e, const int* __restrict__ total_rows) {
  __shared__ __align__(16) short A0[128 * 64], A1[128 * 64];
  __shared__ __align__(16) short B0[128 * 64], B1[128 * 64];
  int tid = threadIdx.x;
  int m0 = blockIdx.y * 128, n0 = blockIdx.x * 128;
  if (m0 >= *total_rows) return;
  int e = tile_e[blockIdx.y];
  const short* Bb = Bt + (size_t)e * N * K;
  const float* biasb = bias ? bias + (size_t)e * N : nullptr;
  int kz = blockIdx.z;
  int kchunk = K / gridDim.z;
  int kbeg = kz * kchunk;
  int nsteps = kchunk >> 6;
  int lane = tid & 63, w = tid >> 6;
  int wr = w >> 2, wc = w & 3;
  int l15 = lane & 15, l4 = lane >> 4;
  f32x4 acc[4][2] = {};

  const short* aB[2];
#pragma unroll
  for (int i = 0; i < 2; ++i) {
    int r = (i * 512 + tid) >> 3;
    int grow = m0 + r;
    if (row_map) {
      int tok = row_map[grow];
      aB[i] = (tok < 0) ? zrow : A + (size_t)tok * K;
    } else {
      aB[i] = A + (size_t)grow * K;
    }
  }

#define STAGE(AS_, BS_, KK)                                                   \
  {                                                                           \
    _Pragma("unroll") for (int i = 0; i < 2; ++i) {                           \
      int c = i * 512 + tid;                                                  \
      int r = c >> 3, gs = c & 7;                                             \
      int g = gs ^ (r & 7);                                                   \
      gload_lds16(aB[i] + (KK) + g * 8, &AS_[c * 8]);                         \
    }                                                                         \
    _Pragma("unroll") for (int i = 0; i < 2; ++i) {                           \
      int c = i * 512 + tid;                                                  \
      int r = c >> 3, gs = c & 7;                                             \
      int g = gs ^ (r & 7);                                                   \
      gload_lds16(Bb + (size_t)(n0 + r) * K + (KK) + g * 8, &BS_[c * 8]);     \
    }                                                                         \
  }

#define COMPUTE(AS_, BS_)                                                     \
  {                                                                           \
    _Pragma("unroll") for (int ks = 0; ks < 2; ++ks) {                        \
      bf16x8 a[4], b[2];                                                      \
      _Pragma("unroll") for (int m = 0; m < 4; ++m) {                         \
        int row = wr * 64 + m * 16 + l15;                                     \
        int slot = (ks * 4 + l4) ^ (row & 7);                                 \
        a[m] = *(const bf16x8*)&AS_[(row * 8 + slot) * 8];                    \
      }                                                                       \
      _Pragma("unroll") for (int n = 0; n < 2; ++n) {                         \
        int row = wc * 32 + n * 16 + l15;                                     \
        int slot = (ks * 4 + l4) ^ (row & 7);                                 \
        b[n] = *(const bf16x8*)&BS_[(row * 8 + slot) * 8];                    \
      }                                                                       \
      _Pragma("unroll") for (int m = 0; m < 4; ++m)                           \
      _Pragma("unroll") for (int n = 0; n < 2; ++n)                           \
        acc[m][n] = __builtin_amdgcn_mfma_f32_16x16x32_bf16(a[m], b[n],       \
                                                            acc[m][n], 0, 0, 0); \
    }                                                                         \
  }

  STAGE(A0, B0, kbeg);
  __syncthreads();
  for (int s = 0; s < nsteps; s += 2) {
    int k0 = kbeg + (s << 6);
    bool has1 = (s + 1 < nsteps), has2 = (s + 2 < nsteps);
    if (has1) STAGE(A1, B1, k0 + 64);
    COMPUTE(A0, B0);
    __syncthreads();
    if (has1) {
      if (has2) STAGE(A0, B0, k0 + 128);
      COMPUTE(A1, B1);
      __syncthreads();
    }
  }
#undef STAGE
#undef COMPUTE

  if (gridDim.z > 1) {
#pragma unroll
    for (int m = 0; m < 4; ++m) {
      int row = m0 + wr * 64 + m * 16 + l4 * 4;
#pragma unroll
      for (int n = 0; n < 2; ++n) {
        int col = n0 + wc * 32 + n * 16 + l15;
#pragma unroll
        for (int q = 0; q < 4; ++q)
          part[((size_t)kz * partM + row + q) * N + col] = acc[m][n][q];
      }
    }
    return;
  }
  float* outf = (float*)Cout;
  short* outb = (short*)Cout;
#pragma unroll
  for (int m = 0; m < 4; ++m) {
    int row = m0 + wr * 64 + m * 16 + l4 * 4;
#pragma unroll
    for (int n = 0; n < 2; ++n) {
      int col = n0 + wc * 32 + n * 16 + l15;
      float bv = biasb[col];
#pragma unroll
      for (int q = 0; q < 4; ++q) {
        float v = acc[m][n][q] + bv;
        if (SILU) v = v / (1.f + __expf(-v));
        if (OUTBF) outb[(size_t)(row + q) * N + col] = f2bf(v);
        else outf[(size_t)(row + q) * N + col] = v;
      }
    }
  }
}

// ---------------------------------------------------------------------------
// Attention MFMA GEMM: 128x128, BK=32, 4 waves, hi/lo reg-staged.
// gridDim.z>1: split-K partials. gridDim.z==1: direct fp32 out + bias.
template <int LO>
__global__ __launch_bounds__(256) void mfma_gemm_kernel(
    const short* __restrict__ Ah, const short* __restrict__ Al,
    const short* __restrict__ Bh, const short* __restrict__ Bl,
    const float* __restrict__ bias, float* __restrict__ dout,
    float* __restrict__ part, int partM, int N, int K) {
  __shared__ short As0[4096], Bs0[4096], As1[4096], Bs1[4096];
  __shared__ short Als0[LO ? 4096 : 64], Bls0[LO ? 4096 : 64];
  __shared__ short Als1[LO ? 4096 : 64], Bls1[LO ? 4096 : 64];
  int tid = threadIdx.x;
  int m0 = blockIdx.y * 128, n0 = blockIdx.x * 128;
  int kz = blockIdx.z;
  int kchunk = K / gridDim.z;
  int kbeg = kz * kchunk;
  int nsteps = kchunk >> 5;
  int lane = tid & 63, w = tid >> 6;
  int wr = w >> 1, wc = w & 1;
  int l15 = lane & 15, l4 = lane >> 4;
  int xorl = (l15 & 3) ^ ((l15 >> 2) & 3);
  f32x4 acc[4][4] = {};
  bf16x8 vA0[2], vB0[2], vAl0[2], vBl0[2];
  bf16x8 vA1[2], vB1[2], vAl1[2], vBl1[2];

#define LOAD_SET(VA, VB, VAL, VBL, KK)                                        \
  {                                                                           \
    _Pragma("unroll") for (int ic = 0; ic < 2; ++ic) {                        \
      int c = ic * 256 + tid;                                                 \
      int r = c >> 2, g = c & 3;                                              \
      size_t ao = (size_t)(m0 + r) * K + (KK) + g * 8;                        \
      size_t bo = (size_t)(n0 + r) * K + (KK) + g * 8;                        \
      VA[ic] = *(const bf16x8*)(Ah + ao);                                     \
      VB[ic] = *(const bf16x8*)(Bh + bo);                                     \
      if (LO) {                                                               \
        VAL[ic] = *(const bf16x8*)(Al + ao);                                  \
        VBL[ic] = *(const bf16x8*)(Bl + bo);                                  \
      }                                                                       \
    }                                                                         \
  }

#define WRITE_SET(AS_, BS_, ALS_, BLS_, VA, VB, VAL, VBL)                     \
  {                                                                           \
    _Pragma("unroll") for (int ic = 0; ic < 2; ++ic) {                        \
      int c = ic * 256 + tid;                                                 \
      int r = c >> 2, g = c & 3;                                              \
      int ch = (r * 4 + (g ^ (r & 3) ^ ((r >> 2) & 3))) * 8;                  \
      *(bf16x8*)&AS_[ch] = VA[ic];                                            \
      *(bf16x8*)&BS_[ch] = VB[ic];                                            \
      if (LO) {                                                               \
        *(bf16x8*)&ALS_[ch] = VAL[ic];                                        \
        *(bf16x8*)&BLS_[ch] = VBL[ic];                                        \
      }                                                                       \
    }                                                                         \
  }

#define COMPUTE_SET(AS_, BS_, ALS_, BLS_)                                     \
  {                                                                           \
    bf16x8 ah[4], al[4];                                                      \
    _Pragma("unroll") for (int m = 0; m < 4; ++m) {                           \
      int row = wr * 64 + m * 16 + l15;                                       \
      int idx = (row * 4 + (l4 ^ xorl)) * 8;                                  \
      ah[m] = *(const bf16x8*)&AS_[idx];                                      \
      if (LO) al[m] = *(const bf16x8*)&ALS_[idx];                             \
    }                                                                         \
    _Pragma("unroll") for (int n = 0; n < 4; ++n) {                           \
      int row = wc * 64 + n * 16 + l15;                                       \
      int idx = (row * 4 + (l4 ^ xorl)) * 8;                                  \
      bf16x8 bhn = *(const bf16x8*)&BS_[idx];                                 \
      bf16x8 bln;                                                             \
      if (LO) bln = *(const bf16x8*)&BLS_[idx];                               \
      _Pragma("unroll") for (int m = 0; m < 4; ++m) {                         \
        acc[m][n] = __builtin_amdgcn_mfma_f32_16x16x32_bf16(ah[m], bhn,       \
                                                            acc[m][n], 0, 0, 0); \
        if (LO) {                                                             \
          acc[m][n] = __builtin_amdgcn_mfma_f32_16x16x32_bf16(al[m], bhn,     \
                                                              acc[m][n], 0, 0, 0); \
          acc[m][n] = __builtin_amdgcn_mfma_f32_16x16x32_bf16(ah[m], bln,     \
                                                              acc[m][n], 0, 0, 0); \
        }                                                                     \
      }                                                                       \
    }                                                                         \
  }

  LOAD_SET(vA0, vB0, vAl0, vBl0, kbeg);
  WRITE_SET(As0, Bs0, Als0, Bls0, vA0, vB0, vAl0, vBl0);
  __syncthreads();
  for (int s = 0; s < nsteps; s += 2) {
    int k0 = kbeg + (s << 5);
    bool has1 = (s + 1 < nsteps), has2 = (s + 2 < nsteps);
    if (has1) LOAD_SET(vA1, vB1, vAl1, vBl1, k0 + 32);
    COMPUTE_SET(As0, Bs0, Als0, Bls0);
    if (has1) WRITE_SET(As1, Bs1, Als1, Bls1, vA1, vB1, vAl1, vBl1);
    __syncthreads();
    if (has1) {
      if (has2) LOAD_SET(vA0, vB0, vAl0, vBl0, k0 + 64);
      COMPUTE_SET(As1, Bs1, Als1, Bls1);
      if (has2) WRITE_SET(As0, Bs0, Als0, Bls0, vA0, vB0, vAl0, vBl0);
      __syncthreads();
    }
  }
#undef LOAD_SET
#undef WRITE_SET
#undef COMPUTE_SET

  if (gridDim.z > 1) {
#pragma unroll
    for (int m = 0; m < 4; ++m) {
      int row = m0 + wr * 64 + m * 16 + l4 * 4;
#pragma unroll
      for (int n = 0; n < 4; ++n) {
        int col = n0 + wc * 64 + n * 16 + l15;
#pragma unroll
        for (int q = 0; q < 4; ++q)
          part[((size_t)kz * partM + row + q) * N + col] = acc[m][n][q];
      }
    }
    return;
  }
  // direct out: acc + bias (fp32)
#pragma unroll
  for (int m = 0; m < 4; ++m) {
    int row = m0 + wr * 64 + m * 16 + l4 * 4;
#pragma unroll
    for (int n = 0; n < 4; ++n) {
      int col = n0 + wc * 64 + n * 16 + l15;
      float bv = bias[col];
#pragma unroll
      for (int q = 0; q < 4; ++q)
        dout[(size_t)(row + q) * N + col] = acc[m][n][q] + bv;
    }
  }
}

// ---------------------------------------------------------------------------
// Attention epilogue (fused): WO split-K reduce + residual + rmsnorm2 +
// router. h2 written directly as bf16 (feeds MoE GEMM1's gathered A).
__global__ __launch_bounds__(256) void attn_epilogue_kernel(
    const float* __restrict__ part, const float* __restrict__ bo,
    const float* __restrict__ x, const float* __restrict__ n2w,
    const float* __restrict__ wr, const float* __restrict__ br,
    float* __restrict__ x1, short* __restrict__ h2b, int* __restrict__ top_i,
    float* __restrict__ top_p, float* __restrict__ probs_out) {
  int t = blockIdx.x;
  int tid = threadIdx.x;
  int c = tid * 4;
  float4 s = *(const float4*)(part + (size_t)t * CD + c);
#pragma unroll
  for (int z = 1; z < 4; ++z) {
    float4 p = *(const float4*)(part + ((size_t)z * CT + t) * CD + c);
    s.x += p.x; s.y += p.y; s.z += p.z; s.w += p.w;
  }
  float4 bv = *(const float4*)(bo + c);
  float4 xv = *(const float4*)(x + (size_t)t * CD + c);
  s.x += bv.x + xv.x; s.y += bv.y + xv.y;
  s.z += bv.z + xv.z; s.w += bv.w + xv.w;
  *(float4*)(x1 + (size_t)t * CD + c) = s;
  float ss = s.x*s.x + s.y*s.y + s.z*s.z + s.w*s.w;
  for (int off = 32; off > 0; off >>= 1) ss += __shfl_down(ss, off);
  __shared__ float red[4];
  __shared__ float s_scale;
  int lane = tid & 63, wid = tid >> 6;
  if (lane == 0) red[wid] = ss;
  __syncthreads();
  if (tid == 0) {
    float tot = red[0] + red[1] + red[2] + red[3];
    s_scale = rsqrtf(tot / (float)CD + CEPS);
  }
  __syncthreads();
  float sc = s_scale;
  float4 wv = *(const float4*)(n2w + c);
  float hv[4] = {s.x * sc * wv.x, s.y * sc * wv.y,
                 s.z * sc * wv.z, s.w * sc * wv.w};
  short4 hb = make_short4(f2bf(hv[0]), f2bf(hv[1]), f2bf(hv[2]), f2bf(hv[3]));
  ((short4*)(h2b + (size_t)t * CD))[tid] = hb;
  float a[CE] = {};
#pragma unroll
  for (int j = 0; j < 4; ++j) {
    const float* wrow = wr + (size_t)(c + j) * CE;
#pragma unroll
    for (int e = 0; e < CE; ++e) a[e] += hv[j] * wrow[e];
  }
  __shared__ float red8[256][CE];
#pragma unroll
  for (int e = 0; e < CE; ++e) red8[tid][e] = a[e];
  __syncthreads();
  for (int st = 128; st > 0; st >>= 1) {
    if (tid < st) {
#pragma unroll
      for (int e = 0; e < CE; ++e) red8[tid][e] += red8[tid + st][e];
    }
    __syncthreads();
  }
  if (tid == 0) {
    float probs[CE];
    float mx = -1e30f;
#pragma unroll
    for (int e = 0; e < CE; ++e) {
      probs[e] = red8[0][e] + br[e];
      mx = fmaxf(mx, probs[e]);
    }
    float sum = 0.f;
#pragma unroll
    for (int e = 0; e < CE; ++e) { probs[e] = __expf(probs[e] - mx); sum += probs[e]; }
    float inv = 1.0f / sum;
#pragma unroll
    for (int e = 0; e < CE; ++e) {
      probs[e] *= inv;
      probs_out[t * CE + e] = probs[e];
    }
    int i1 = 0;
#pragma unroll
    for (int e = 1; e < CE; ++e) if (probs[e] > probs[i1]) i1 = e;
    int i2 = (i1 == 0) ? 1 : 0;
#pragma unroll
    for (int e = 0; e < CE; ++e)
      if (e != i1 && probs[e] > probs[i2]) i2 = e;
    float p1 = probs[i1], p2 = probs[i2];
    float s12 = p1 + p2;
    top_i[t * 2 + 0] = i1;
    top_i[t * 2 + 1] = i2;
    top_p[t * 2 + 0] = p1 / s12;
    top_p[t * 2 + 1] = p2 / s12;
  }
}

// ---------------------------------------------------------------------------
// Fused attention v5b (unchanged from rounds 15-17).
__global__ __launch_bounds__(256) void fused_attn_kernel(
    const float* __restrict__ qkv, short* __restrict__ ctxh,
    short* __restrict__ ctxl) {
  __shared__ float Qs[32][68];    // Q tile
  __shared__ float KVs[64 * 68];  // K (stride 65) then V (stride 68)
  __shared__ float Pt[32][68];    // per-tile P (stride 68 for float4 reads)
  int qt = blockIdx.x, bh = blockIdx.y;
  int b = bh / CH, h = bh % CH;
  int qrow0 = qt * 32;
  int ktmax = (qrow0 + 31) >> 6;
  int tid = threadIdx.x;
  int cg = tid & 31, rg = tid >> 5;
  int r0 = rg * 4;

  // stage Q [32][64]
#pragma unroll
  for (int it = 0; it < 2; ++it) {
    int idx = it * 256 + tid;
    int r = idx >> 4, c4 = (idx & 15) * 4;
    *(float4*)&Qs[r][c4] = *(const float4*)(
        qkv + (size_t)(b * CS + qrow0 + r) * QKVP + h * CHD + c4);
  }

  float m_i[4], l_i[4], O[4][2];
#pragma unroll
  for (int i = 0; i < 4; ++i) {
    m_i[i] = -1e30f;
    l_i[i] = 0.f;
    O[i][0] = 0.f;
    O[i][1] = 0.f;
  }

  for (int kt = 0; kt <= ktmax; ++kt) {
    __syncthreads();  // prev tile's PV reads of KVs(V)/Pt done
    // stage K (scalar, stride 65)
#pragma unroll
    for (int it = 0; it < 4; ++it) {
      int idx = it * 256 + tid;
      int r = idx >> 4, c4 = (idx & 15) * 4;
      const float* src =
          qkv + (size_t)(b * CS + kt * 64 + r) * QKVP + h * CHD;
      float4 kv = *(const float4*)(src + 1024 + c4);
      KVs[r * 65 + c4 + 0] = kv.x;
      KVs[r * 65 + c4 + 1] = kv.y;
      KVs[r * 65 + c4 + 2] = kv.z;
      KVs[r * 65 + c4 + 3] = kv.w;
    }
    __syncthreads();

    // scores: s[4 rows][2 cols]
    float s[4][2] = {};
#pragma unroll 4
    for (int d = 0; d < 64; ++d) {
      float q0 = Qs[r0 + 0][d];
      float q1 = Qs[r0 + 1][d];
      float q2 = Qs[r0 + 2][d];
      float q3 = Qs[r0 + 3][d];
      float k0 = KVs[(cg * 2 + 0) * 65 + d];
      float k1 = KVs[(cg * 2 + 1) * 65 + d];
      s[0][0] += q0 * k0; s[0][1] += q0 * k1;
      s[1][0] += q1 * k0; s[1][1] += q1 * k1;
      s[2][0] += q2 * k0; s[2][1] += q2 * k1;
      s[3][0] += q3 * k0; s[3][1] += q3 * k1;
    }

    // online softmax update (per row, reduce over 32-lane col group)
#pragma unroll
    for (int i = 0; i < 4; ++i) {
      int gr = qrow0 + r0 + i;
      int gc0 = kt * 64 + cg * 2;
      float s0 = (gc0 + 0 > gr) ? -1e30f : s[i][0] * 0.125f;
      float s1 = (gc0 + 1 > gr) ? -1e30f : s[i][1] * 0.125f;
      float tmax = fmaxf(s0, s1);
#pragma unroll
      for (int off = 16; off > 0; off >>= 1)
        tmax = fmaxf(tmax, __shfl_xor(tmax, off));
      float newm = fmaxf(m_i[i], tmax);
      float p0 = __expf(s0 - newm);
      float p1 = __expf(s1 - newm);
      float tsum = p0 + p1;
#pragma unroll
      for (int off = 16; off > 0; off >>= 1) tsum += __shfl_xor(tsum, off);
      float scale = __expf(m_i[i] - newm);
      l_i[i] = l_i[i] * scale + tsum;
      m_i[i] = newm;
      O[i][0] *= scale;
      O[i][1] *= scale;
      *(float2*)&Pt[r0 + i][cg * 2] = make_float2(p0, p1);
    }
    __syncthreads();  // all K reads + Pt writes done

    // stage V into the same buffer (float4, stride 68)
#pragma unroll
    for (int it = 0; it < 4; ++it) {
      int idx = it * 256 + tid;
      int r = idx >> 4, c4 = (idx & 15) * 4;
      *(float4*)&KVs[r * 68 + c4] = *(const float4*)(
          qkv + (size_t)(b * CS + kt * 64 + r) * QKVP + 2048 + h * CHD + c4);
    }
    __syncthreads();

    // PV: per 4-c chunk, float4 P reads; same FMA order as scalar version.
#pragma unroll 2
    for (int c4 = 0; c4 < 64; c4 += 4) {
      float4 pr[4];
#pragma unroll
      for (int i = 0; i < 4; ++i) pr[i] = *(const float4*)&Pt[r0 + i][c4];
      float pv[4][4] = {{pr[0].x, pr[0].y, pr[0].z, pr[0].w},
                        {pr[1].x, pr[1].y, pr[1].z, pr[1].w},
                        {pr[2].x, pr[2].y, pr[2].z, pr[2].w},
                        {pr[3].x, pr[3].y, pr[3].z, pr[3].w}};
#pragma unroll
      for (int j = 0; j < 4; ++j) {
        int c = c4 + j;
        float v0 = KVs[c * 68 + cg];
        float v1 = KVs[c * 68 + cg + 32];
        O[0][0] += pv[0][j] * v0; O[0][1] += pv[0][j] * v1;
        O[1][0] += pv[1][j] * v0; O[1][1] += pv[1][j] * v1;
        O[2][0] += pv[2][j] * v0; O[2][1] += pv[2][j] * v1;
        O[3][0] += pv[3][j] * v0; O[3][1] += pv[3][j] * v1;
      }
    }
  }

  // epilogue: normalize by l, write hi/lo bf16 planes
#pragma unroll
  for (int i = 0; i < 4; ++i) {
    float inv = 1.0f / l_i[i];
#pragma unroll
    for (int jd = 0; jd < 2; ++jd) {
      int dv = cg + 32 * jd;
      size_t oi = (size_t)(b * CS + qrow0 + r0 + i) * CD + h * CHD + dv;
      float v = O[i][jd] * inv;
      short hi = f2bf(v);
      ctxh[oi] = hi;
      ctxl[oi] = f2bf(v - bf2f(hi));
    }
  }
}

// ---------------------------------------------------------------------------
// Finalize+gather (1 block): counts/psum, offsets, tile map, aux loss, zrow,
// row_map init, then the gather itself via LDS cursors (order-invariant:
// row content depends only on token, so any within-expert permutation yields
// bitwise-identical output).
__global__ __launch_bounds__(256) void finalize_kernel(
    const int* __restrict__ top_i, const float* __restrict__ probs,
    int* __restrict__ tile_e, int* __restrict__ total_padded,
    int* __restrict__ row_map, int* __restrict__ row_of,
    short* __restrict__ zrow, float* __restrict__ aux_out) {
  int tid = threadIdx.x;
  __shared__ float redp[256][CE];
  __shared__ int redc[256][CE];
  __shared__ int s_off[CE + 1];
  __shared__ int s_cur[CE];
  float lp[CE] = {};
  int lc[CE] = {};
  for (int t = tid; t < CT; t += 256) {
    lc[top_i[t * 2 + 0]]++;
    lc[top_i[t * 2 + 1]]++;
#pragma unroll
    for (int e = 0; e < CE; ++e) lp[e] += probs[t * CE + e];
  }
#pragma unroll
  for (int e = 0; e < CE; ++e) { redp[tid][e] = lp[e]; redc[tid][e] = lc[e]; }
  __syncthreads();
  for (int s = 128; s > 0; s >>= 1) {
    if (tid < s) {
#pragma unroll
      for (int e = 0; e < CE; ++e) {
        redp[tid][e] += redp[tid + s][e];
        redc[tid][e] += redc[tid + s][e];
      }
    }
    __syncthreads();
  }
  if (tid == 0) {
    int o = 0;
    for (int e = 0; e < CE; ++e) {
      s_off[e] = o;
      o += ((redc[0][e] + 127) >> 7) << 7;
    }
    s_off[CE] = o;
    *total_padded = o;
    int nt = o >> 7;
    for (int i = 0; i < nt; ++i) {
      int e = 0;
      while (e < CE - 1 && i * 128 >= s_off[e + 1]) e++;
      tile_e[i] = e;
    }
    float aux = 0.f;
    for (int e = 0; e < CE; ++e)
      aux += ((float)redc[0][e] / (float)(CT * CK)) * (redp[0][e] / (float)CT);
    aux_out[0] = aux * (float)CE;
  }
  if (tid < CE) s_cur[tid] = 0;
  ((short4*)zrow)[tid] = make_short4(0, 0, 0, 0);  // 256*4 = 1024 shorts
  __syncthreads();
  for (int i = tid; i < MAXROWS; i += 256) row_map[i] = -1;
  __syncthreads();
  // gather: assign rows within expert segments (LDS cursors)
  for (int idx = tid; idx < CT * CK; idx += 256) {
    int e = top_i[idx];
    int pos = s_off[e] + atomicAdd(&s_cur[e], 1);
    row_map[pos] = idx >> 1;
    row_of[idx] = pos;
  }
}

// Fused GEMM2-reduce + combine: per token, read only its 2 routed rows'
// partials, add b2[e], weight, residual.
__global__ __launch_bounds__(256) void combine_g2_kernel(
    const float* __restrict__ part, int partM, int nz,
    const float* __restrict__ b2, const int* __restrict__ tile_e,
    const int* __restrict__ row_of, const float* __restrict__ top_p,
    const float* __restrict__ x1, float* __restrict__ out) {
  int t = blockIdx.x;
  int c = threadIdx.x * 4;
  float4 r = *(const float4*)(x1 + (size_t)t * CD + c);
#pragma unroll
  for (int s = 0; s < CK; ++s) {
    int row = row_of[t * 2 + s];
    int e = tile_e[row >> 7];
    float w = top_p[t * 2 + s];
    float4 acc = *(const float4*)(part + (size_t)row * CD + c);
    for (int z = 1; z < nz; ++z) {
      float4 p = *(const float4*)(part + ((size_t)z * partM + row) * CD + c);
      acc.x += p.x; acc.y += p.y; acc.z += p.z; acc.w += p.w;
    }
    float4 bv = *(const float4*)(b2 + (size_t)e * CD + c);
    r.x += w * (acc.x + bv.x);
    r.y += w * (acc.y + bv.y);
    r.z += w * (acc.z + bv.z);
    r.w += w * (acc.w + bv.w);
  }
  *(float4*)(out + (size_t)t * CD + c) = r;
}

// ---------------------------------------------------------------------------
extern "C" void kernel_launch(void* const* d_in, const int* in_sizes, int n_in,
                              void* d_out, int out_size, void* d_ws,
                              size_t ws_size, hipStream_t stream) {
  const float* x   = (const float*)d_in[0];
  const float* n1w = (const float*)d_in[1];
  const float* n2w = (const float*)d_in[2];
  const float* wq  = (const float*)d_in[3];
  const float* bq  = (const float*)d_in[4];
  const float* wk  = (const float*)d_in[5];
  const float* bk  = (const float*)d_in[6];
  const float* wv  = (const float*)d_in[7];
  const float* bv  = (const float*)d_in[8];
  const float* wo  = (const float*)d_in[9];
  const float* bo  = (const float*)d_in[10];
  const float* wr  = (const float*)d_in[11];
  const float* br  = (const float*)d_in[12];
  const float* w1  = (const float*)d_in[13];
  const float* b1  = (const float*)d_in[14];
  const float* w2  = (const float*)d_in[15];
  const float* b2  = (const float*)d_in[16];
  float* out = (float*)d_out;

  char* base = (char*)d_ws;
  size_t off = 0;
  auto alloc = [&](size_t bytes) -> void* {
    void* p = base + off;
    off += (bytes + 255) & ~(size_t)255;
    return p;
  };
  float* f_x1   = (float*)alloc((size_t)CT * CD * 4);
  short* f_h2b  = (short*)alloc((size_t)CT * CD * 2);   // bf16 h2 (MoE input)
  short* f_hid  = (short*)alloc((size_t)MAXROWS * CF * 2);
  short* f_hh   = (short*)alloc((size_t)CT * CD * 2);
  short* f_hl   = (short*)alloc((size_t)CT * CD * 2);
  short* f_wqkvh = (short*)alloc((size_t)QKVP * CD * 2);
  short* f_wqkvl = (short*)alloc((size_t)QKVP * CD * 2);
  float* f_qkv  = (float*)alloc((size_t)CT * QKVP * 4);
  short* f_ctxh = (short*)alloc((size_t)CT * CD * 2);
  short* f_ctxl = (short*)alloc((size_t)CT * CD * 2);
  short* f_woth = (short*)alloc((size_t)CD * CD * 2);
  short* f_wotl = (short*)alloc((size_t)CD * CD * 2);
  float* f_bqkv = (float*)alloc(QKVP * 4);
  float* f_topp = (float*)alloc(CT * CK * 4);
  float* f_probs = (float*)alloc(CT * CE * 4);
  short* f_zrow = (short*)alloc(CD * 2);
  int* i_topi   = (int*)alloc(CT * CK * 4);
  int* i_rowof  = (int*)alloc(CT * CK * 4);
  int* i_rowmap = (int*)alloc(MAXROWS * 4);
  int* i_tile   = (int*)alloc(MAXTILES * 4);
  int* i_total  = (int*)alloc(4);
  // G (64MB): w1t -> w2t (sequential reuse)
  short* f_wG = (short*)alloc((size_t)CE * CD * CF * 2);
  short* f_w1t = f_wG;
  short* f_w2t = f_wG;
  // Rs (48MB): WO partials -> GEMM2 partials (disjoint)
  void* Rs = alloc((size_t)4 * MAXROWS * CD * 4);
  float* f_partwo = (float*)Rs;
  float* f_partg2 = (float*)Rs;

  dim3 b256(256);

  TPtrs tp;
  tp.w[0] = wq; tp.w[1] = wk; tp.w[2] = wv; tp.w[3] = wo;
  tp.hh[0] = f_wqkvh + 0 * (size_t)CD * CD;
  tp.hh[1] = f_wqkvh + 1 * (size_t)CD * CD;
  tp.hh[2] = f_wqkvh + 2 * (size_t)CD * CD;
  tp.hh[3] = f_woth;
  tp.ll[0] = f_wqkvl + 0 * (size_t)CD * CD;
  tp.ll[1] = f_wqkvl + 1 * (size_t)CD * CD;
  tp.ll[2] = f_wqkvl + 2 * (size_t)CD * CD;
  tp.ll[3] = f_wotl;
  tp.bq = bq; tp.bk = bk; tp.bv = bv; tp.bqkv = f_bqkv;
  tp.xin = x; tp.n1w = n1w; tp.hH = f_hh; tp.hL = f_hl;
  // z: 0-3 = wq/wk/wv/wo transposes, 4 = bias pack, 5 = rmsnorm1
  transpose4_kernel<<<dim3(16, 16, 6), b256, 0, stream>>>(tp);
  transpose_convert_kernel<<<dim3(CF / 64, CD / 64, CE), b256, 0, stream>>>(
      w1, f_w1t, nullptr, CD, CF);

  // ---- attention ----
  // QKV: split-K=1, bias fused, direct fp32 out (no reduce pass)
  mfma_gemm_kernel<1><<<dim3(QKVP / 128, CT / 128, 1), b256, 0, stream>>>(
      f_hh, f_hl, f_wqkvh, f_wqkvl, f_bqkv, f_qkv, nullptr, CT, QKVP, CD);
  fused_attn_kernel<<<dim3(CS / 32, CBH), b256, 0, stream>>>(f_qkv, f_ctxh,
                                                             f_ctxl);
  mfma_gemm_kernel<1><<<dim3(CD / 128, CT / 128, 4), b256, 0, stream>>>(
      f_ctxh, f_ctxl, f_woth, f_wotl, nullptr, nullptr, f_partwo, CT, CD, CD);
  attn_epilogue_kernel<<<CT, b256, 0, stream>>>(f_partwo, bo, x, n2w, wr, br,
                                                f_x1, f_h2b, i_topi, f_topp,
                                                f_probs);

  // ---- MoE ----
  finalize_kernel<<<1, 256, 0, stream>>>(i_topi, f_probs, i_tile, i_total,
                                         i_rowmap, i_rowof, f_zrow,
                                         out + (size_t)CT * CD);

  // expert GEMM1: A gathered via row_map from bf16 h2 (no Xg materialization)
  moe_gemm_kernel<1, 1><<<dim3(CF / 128, MAXTILES, 1), dim3(512), 0, stream>>>(
      f_h2b, i_rowmap, f_zrow, f_w1t, b1, f_hid, nullptr, 0, CF, CD, i_tile,
      i_total);
  transpose_convert_kernel<<<dim3(CD / 64, CF / 64, CE), b256, 0, stream>>>(
      w2, f_w2t, nullptr, CF, CD);
  // expert GEMM2: BN=128, split-K=4
  moe_gemm_kernel<0, 0><<<dim3(CD / 128, MAXTILES, 4), dim3(512), 0, stream>>>(
      f_hid, nullptr, nullptr, f_w2t, nullptr, nullptr, f_partg2, MAXROWS, CD,
      CF, i_tile, i_total);
  combine_g2_kernel<<<CT, b256, 0, stream>>>(f_partg2, MAXROWS, 4, b2, i_tile,
                                             i_rowof, f_topp, f_x1, out);
}

// Round 19
// 296.780 us; speedup vs baseline: 1.2425x; 1.0481x over previous
//
#include <hip/hip_runtime.h>
#include <math.h>

// Problem constants
#define CB 2
#define CS 512
#define CD 1024
#define CH 16
#define CHD 64
#define CF 4096
#define CE 8
#define CK 2
#define CT (CB*CS)      // 1024 tokens
#define CBH (CB*CH)     // 32 (batch*heads)
#define CEPS 1e-6f
#define QKVP 3072       // packed q|k|v row pitch
#define MAXROWS 3072    // 2048 + 8*127 padded to 128
#define MAXTILES (MAXROWS/128)

typedef __attribute__((ext_vector_type(8))) short bf16x8;
typedef __attribute__((ext_vector_type(4))) float f32x4;

__device__ __forceinline__ short f2bf(float f) {
  unsigned u = __float_as_uint(f);
  unsigned r = (u + 0x7FFF + ((u >> 16) & 1)) >> 16;
  return (short)r;
}
__device__ __forceinline__ float bf2f(short h) {
  return __uint_as_float(((unsigned)(unsigned short)h) << 16);
}

__device__ __forceinline__ void gload_lds16(const void* g, void* l) {
  __builtin_amdgcn_global_load_lds(
      (const __attribute__((address_space(1))) unsigned int*)g,
      (__attribute__((address_space(3))) unsigned int*)l, 16, 0, 0);
}

// ---------------------------------------------------------------------------
// Tiled transpose+convert, 64x64 tile, 16B short8 stores:
// W[e][Kd][Nd] f32 -> Wth[e][Nd][Kd] bf16 (+ optional lo plane).
__global__ __launch_bounds__(256) void transpose_convert_kernel(
    const float* __restrict__ W, short* __restrict__ Wth,
    short* __restrict__ Wtl, int Kd, int Nd) {
  int e = blockIdx.z;
  const float* Wb = W + (size_t)e * Kd * Nd;
  size_t obase = (size_t)e * Kd * Nd;
  int n0 = blockIdx.x * 64, k0 = blockIdx.y * 64;
  __shared__ float t[64][65];
  int tid = threadIdx.x;
#pragma unroll
  for (int i = 0; i < 4; ++i) {
    int idx = i * 256 + tid;
    int r = idx >> 4, c4 = (idx & 15) * 4;
    float4 v = *(const float4*)(Wb + (size_t)(k0 + r) * Nd + n0 + c4);
    t[r][c4] = v.x; t[r][c4 + 1] = v.y; t[r][c4 + 2] = v.z; t[r][c4 + 3] = v.w;
  }
  __syncthreads();
  int n = tid >> 2, k16 = (tid & 3) * 16;
  short th[16], tl[16];
#pragma unroll
  for (int j = 0; j < 16; ++j) {
    float v = t[k16 + j][n];
    short hi = f2bf(v);
    th[j] = hi;
    tl[j] = f2bf(v - bf2f(hi));
  }
  size_t oo = obase + (size_t)(n0 + n) * Kd + k0 + k16;
  ((int4*)(Wth + oo))[0] = ((int4*)th)[0];
  ((int4*)(Wth + oo + 8))[0] = ((int4*)th)[1];
  if (Wtl) {
    ((int4*)(Wtl + oo))[0] = ((int4*)tl)[0];
    ((int4*)(Wtl + oo + 8))[0] = ((int4*)tl)[1];
  }
}

// Four DxD transposes (wq,wk,wv,wo), bias packing (z==4), rmsnorm1 (z==5).
struct TPtrs {
  const float* w[4];
  short* hh[4];
  short* ll[4];
  const float* bq;
  const float* bk;
  const float* bv;
  float* bqkv;
  const float* xin;
  const float* n1w;
  short* hH;
  short* hL;
};
__global__ __launch_bounds__(256) void transpose4_kernel(TPtrs p) {
  int z = blockIdx.z;
  int tid = threadIdx.x;
  if (z == 4) {
    // bias packing: 12 blocks x 256 threads cover QKVP=3072
    if (blockIdx.y == 0 && blockIdx.x < 12) {
      int i = blockIdx.x * 256 + tid;
      if (i < QKVP)
        p.bqkv[i] =
            (i < 1024) ? p.bq[i] : (i < 2048 ? p.bk[i - 1024] : p.bv[i - 2048]);
    }
    return;
  }
  if (z == 5) {
    // rmsnorm1 hi/lo: 256 blocks x 4 tokens each
    __shared__ float red[4];
    __shared__ float s_scale;
    int bid = blockIdx.y * 16 + blockIdx.x;
    int lane = tid & 63, wid = tid >> 6;
    for (int tt = 0; tt < 4; ++tt) {
      int t = bid * 4 + tt;
      float4 xv = ((const float4*)(p.xin + (size_t)t * CD))[tid];
      float ss = xv.x*xv.x + xv.y*xv.y + xv.z*xv.z + xv.w*xv.w;
      for (int off = 32; off > 0; off >>= 1) ss += __shfl_down(ss, off);
      if (lane == 0) red[wid] = ss;
      __syncthreads();
      if (tid == 0) {
        float tot = red[0] + red[1] + red[2] + red[3];
        s_scale = rsqrtf(tot / (float)CD + CEPS);
      }
      __syncthreads();
      float sc = s_scale;
      float4 wv = ((const float4*)p.n1w)[tid];
      float o[4] = {xv.x * sc * wv.x, xv.y * sc * wv.y,
                    xv.z * sc * wv.z, xv.w * sc * wv.w};
      short4 hi, lo;
      short* hp = (short*)&hi; short* lp = (short*)&lo;
#pragma unroll
      for (int i = 0; i < 4; ++i) {
        short h = f2bf(o[i]);
        hp[i] = h;
        lp[i] = f2bf(o[i] - bf2f(h));
      }
      ((short4*)(p.hH + (size_t)t * CD))[tid] = hi;
      ((short4*)(p.hL + (size_t)t * CD))[tid] = lo;
      __syncthreads();
    }
    return;
  }
  const float* Wb = p.w[z];
  short* Wth = p.hh[z];
  short* Wtl = p.ll[z];
  int n0 = blockIdx.x * 64, k0 = blockIdx.y * 64;
  __shared__ float t[64][65];
#pragma unroll
  for (int i = 0; i < 4; ++i) {
    int idx = i * 256 + tid;
    int r = idx >> 4, c4 = (idx & 15) * 4;
    float4 v = *(const float4*)(Wb + (size_t)(k0 + r) * CD + n0 + c4);
    t[r][c4] = v.x; t[r][c4 + 1] = v.y; t[r][c4 + 2] = v.z; t[r][c4 + 3] = v.w;
  }
  __syncthreads();
  int n = tid >> 2, k16 = (tid & 3) * 16;
  short th[16], tl[16];
#pragma unroll
  for (int j = 0; j < 16; ++j) {
    float v = t[k16 + j][n];
    short hi = f2bf(v);
    th[j] = hi;
    tl[j] = f2bf(v - bf2f(hi));
  }
  size_t oo = (size_t)(n0 + n) * CD + k0 + k16;
  ((int4*)(Wth + oo))[0] = ((int4*)th)[0];
  ((int4*)(Wth + oo + 8))[0] = ((int4*)th)[1];
  ((int4*)(Wtl + oo))[0] = ((int4*)tl)[0];
  ((int4*)(Wtl + oo + 8))[0] = ((int4*)tl)[1];
}

// ---------------------------------------------------------------------------
// MoE grouped GEMM: BM=128, BN=128, BK=64, 8 waves (2x4; wave out 64x32).
// LDS 64KB -> 2 blocks/CU. A source optionally row_map-indirect.
template <int SILU, int OUTBF>
__global__ __launch_bounds__(512) void moe_gemm_kernel(
    const short* __restrict__ A, const int* __restrict__ row_map,
    const short* __restrict__ zrow, const short* __restrict__ Bt,
    const float* __restrict__ bias, void* __restrict__ Cout,
    float* __restrict__ part, int partM, int N, int K,
    const int* __restrict__ tile_e, const int* __restrict__ total_rows) {
  __shared__ __align__(16) short A0[128 * 64], A1[128 * 64];
  __shared__ __align__(16) short B0[128 * 64], B1[128 * 64];
  int tid = threadIdx.x;
  int m0 = blockIdx.y * 128, n0 = blockIdx.x * 128;
  if (m0 >= *total_rows) return;
  int e = tile_e[blockIdx.y];
  const short* Bb = Bt + (size_t)e * N * K;
  const float* biasb = bias ? bias + (size_t)e * N : nullptr;
  int kz = blockIdx.z;
  int kchunk = K / gridDim.z;
  int kbeg = kz * kchunk;
  int nsteps = kchunk >> 6;
  int lane = tid & 63, w = tid >> 6;
  int wr = w >> 2, wc = w & 3;
  int l15 = lane & 15, l4 = lane >> 4;
  f32x4 acc[4][2] = {};

  const short* aB[2];
#pragma unroll
  for (int i = 0; i < 2; ++i) {
    int r = (i * 512 + tid) >> 3;
    int grow = m0 + r;
    if (row_map) {
      int tok = row_map[grow];
      aB[i] = (tok < 0) ? zrow : A + (size_t)tok * K;
    } else {
      aB[i] = A + (size_t)grow * K;
    }
  }

#define STAGE(AS_, BS_, KK)                                                   \
  {                                                                           \
    _Pragma("unroll") for (int i = 0; i < 2; ++i) {                           \
      int c = i * 512 + tid;                                                  \
      int r = c >> 3, gs = c & 7;                                             \
      int g = gs ^ (r & 7);                                                   \
      gload_lds16(aB[i] + (KK) + g * 8, &AS_[c * 8]);                         \
    }                                                                         \
    _Pragma("unroll") for (int i = 0; i < 2; ++i) {                           \
      int c = i * 512 + tid;                                                  \
      int r = c >> 3, gs = c & 7;                                             \
      int g = gs ^ (r & 7);                                                   \
      gload_lds16(Bb + (size_t)(n0 + r) * K + (KK) + g * 8, &BS_[c * 8]);     \
    }                                                                         \
  }

#define COMPUTE(AS_, BS_)                                                     \
  {                                                                           \
    _Pragma("unroll") for (int ks = 0; ks < 2; ++ks) {                        \
      bf16x8 a[4], b[2];                                                      \
      _Pragma("unroll") for (int m = 0; m < 4; ++m) {                         \
        int row = wr * 64 + m * 16 + l15;                                     \
        int slot = (ks * 4 + l4) ^ (row & 7);                                 \
        a[m] = *(const bf16x8*)&AS_[(row * 8 + slot) * 8];                    \
      }                                                                       \
      _Pragma("unroll") for (int n = 0; n < 2; ++n) {                         \
        int row = wc * 32 + n * 16 + l15;                                     \
        int slot = (ks * 4 + l4) ^ (row & 7);                                 \
        b[n] = *(const bf16x8*)&BS_[(row * 8 + slot) * 8];                    \
      }                                                                       \
      _Pragma("unroll") for (int m = 0; m < 4; ++m)                           \
      _Pragma("unroll") for (int n = 0; n < 2; ++n)                           \
        acc[m][n] = __builtin_amdgcn_mfma_f32_16x16x32_bf16(a[m], b[n],       \
                                                            acc[m][n], 0, 0, 0); \
    }                                                                         \
  }

  STAGE(A0, B0, kbeg);
  __syncthreads();
  for (int s = 0; s < nsteps; s += 2) {
    int k0 = kbeg + (s << 6);
    bool has1 = (s + 1 < nsteps), has2 = (s + 2 < nsteps);
    if (has1) STAGE(A1, B1, k0 + 64);
    COMPUTE(A0, B0);
    __syncthreads();
    if (has1) {
      if (has2) STAGE(A0, B0, k0 + 128);
      COMPUTE(A1, B1);
      __syncthreads();
    }
  }
#undef STAGE
#undef COMPUTE

  if (gridDim.z > 1) {
#pragma unroll
    for (int m = 0; m < 4; ++m) {
      int row = m0 + wr * 64 + m * 16 + l4 * 4;
#pragma unroll
      for (int n = 0; n < 2; ++n) {
        int col = n0 + wc * 32 + n * 16 + l15;
#pragma unroll
        for (int q = 0; q < 4; ++q)
          part[((size_t)kz * partM + row + q) * N + col] = acc[m][n][q];
      }
    }
    return;
  }
  float* outf = (float*)Cout;
  short* outb = (short*)Cout;
#pragma unroll
  for (int m = 0; m < 4; ++m) {
    int row = m0 + wr * 64 + m * 16 + l4 * 4;
#pragma unroll
    for (int n = 0; n < 2; ++n) {
      int col = n0 + wc * 32 + n * 16 + l15;
      float bv = biasb[col];
#pragma unroll
      for (int q = 0; q < 4; ++q) {
        float v = acc[m][n][q] + bv;
        if (SILU) v = v / (1.f + __expf(-v));
        if (OUTBF) outb[(size_t)(row + q) * N + col] = f2bf(v);
        else outf[(size_t)(row + q) * N + col] = v;
      }
    }
  }
}

// ---------------------------------------------------------------------------
// Attention MFMA GEMM: 128x128, BK=32, 4 waves, hi/lo reg-staged.
// gridDim.z>1: split-K partials. gridDim.z==1: direct fp32 out + bias.
template <int LO>
__global__ __launch_bounds__(256) void mfma_gemm_kernel(
    const short* __restrict__ Ah, const short* __restrict__ Al,
    const short* __restrict__ Bh, const short* __restrict__ Bl,
    const float* __restrict__ bias, float* __restrict__ dout,
    float* __restrict__ part, int partM, int N, int K) {
  __shared__ short As0[4096], Bs0[4096], As1[4096], Bs1[4096];
  __shared__ short Als0[LO ? 4096 : 64], Bls0[LO ? 4096 : 64];
  __shared__ short Als1[LO ? 4096 : 64], Bls1[LO ? 4096 : 64];
  int tid = threadIdx.x;
  int m0 = blockIdx.y * 128, n0 = blockIdx.x * 128;
  int kz = blockIdx.z;
  int kchunk = K / gridDim.z;
  int kbeg = kz * kchunk;
  int nsteps = kchunk >> 5;
  int lane = tid & 63, w = tid >> 6;
  int wr = w >> 1, wc = w & 1;
  int l15 = lane & 15, l4 = lane >> 4;
  int xorl = (l15 & 3) ^ ((l15 >> 2) & 3);
  f32x4 acc[4][4] = {};
  bf16x8 vA0[2], vB0[2], vAl0[2], vBl0[2];
  bf16x8 vA1[2], vB1[2], vAl1[2], vBl1[2];

#define LOAD_SET(VA, VB, VAL, VBL, KK)                                        \
  {                                                                           \
    _Pragma("unroll") for (int ic = 0; ic < 2; ++ic) {                        \
      int c = ic * 256 + tid;                                                 \
      int r = c >> 2, g = c & 3;                                              \
      size_t ao = (size_t)(m0 + r) * K + (KK) + g * 8;                        \
      size_t bo = (size_t)(n0 + r) * K + (KK) + g * 8;                        \
      VA[ic] = *(const bf16x8*)(Ah + ao);                                     \
      VB[ic] = *(const bf16x8*)(Bh + bo);                                     \
      if (LO) {                                                               \
        VAL[ic] = *(const bf16x8*)(Al + ao);                                  \
        VBL[ic] = *(const bf16x8*)(Bl + bo);                                  \
      }                                                                       \
    }                                                                         \
  }

#define WRITE_SET(AS_, BS_, ALS_, BLS_, VA, VB, VAL, VBL)                     \
  {                                                                           \
    _Pragma("unroll") for (int ic = 0; ic < 2; ++ic) {                        \
      int c = ic * 256 + tid;                                                 \
      int r = c >> 2, g = c & 3;                                              \
      int ch = (r * 4 + (g ^ (r & 3) ^ ((r >> 2) & 3))) * 8;                  \
      *(bf16x8*)&AS_[ch] = VA[ic];                                            \
      *(bf16x8*)&BS_[ch] = VB[ic];                                            \
      if (LO) {                                                               \
        *(bf16x8*)&ALS_[ch] = VAL[ic];                                        \
        *(bf16x8*)&BLS_[ch] = VBL[ic];                                        \
      }                                                                       \
    }                                                                         \
  }

#define COMPUTE_SET(AS_, BS_, ALS_, BLS_)                                     \
  {                                                                           \
    bf16x8 ah[4], al[4];                                                      \
    _Pragma("unroll") for (int m = 0; m < 4; ++m) {                           \
      int row = wr * 64 + m * 16 + l15;                                       \
      int idx = (row * 4 + (l4 ^ xorl)) * 8;                                  \
      ah[m] = *(const bf16x8*)&AS_[idx];                                      \
      if (LO) al[m] = *(const bf16x8*)&ALS_[idx];                             \
    }                                                                         \
    _Pragma("unroll") for (int n = 0; n < 4; ++n) {                           \
      int row = wc * 64 + n * 16 + l15;                                       \
      int idx = (row * 4 + (l4 ^ xorl)) * 8;                                  \
      bf16x8 bhn = *(const bf16x8*)&BS_[idx];                                 \
      bf16x8 bln;                                                             \
      if (LO) bln = *(const bf16x8*)&BLS_[idx];                               \
      _Pragma("unroll") for (int m = 0; m < 4; ++m) {                         \
        acc[m][n] = __builtin_amdgcn_mfma_f32_16x16x32_bf16(ah[m], bhn,       \
                                                            acc[m][n], 0, 0, 0); \
        if (LO) {                                                             \
          acc[m][n] = __builtin_amdgcn_mfma_f32_16x16x32_bf16(al[m], bhn,     \
                                                              acc[m][n], 0, 0, 0); \
          acc[m][n] = __builtin_amdgcn_mfma_f32_16x16x32_bf16(ah[m], bln,     \
                                                              acc[m][n], 0, 0, 0); \
        }                                                                     \
      }                                                                       \
    }                                                                         \
  }

  LOAD_SET(vA0, vB0, vAl0, vBl0, kbeg);
  WRITE_SET(As0, Bs0, Als0, Bls0, vA0, vB0, vAl0, vBl0);
  __syncthreads();
  for (int s = 0; s < nsteps; s += 2) {
    int k0 = kbeg + (s << 5);
    bool has1 = (s + 1 < nsteps), has2 = (s + 2 < nsteps);
    if (has1) LOAD_SET(vA1, vB1, vAl1, vBl1, k0 + 32);
    COMPUTE_SET(As0, Bs0, Als0, Bls0);
    if (has1) WRITE_SET(As1, Bs1, Als1, Bls1, vA1, vB1, vAl1, vBl1);
    __syncthreads();
    if (has1) {
      if (has2) LOAD_SET(vA0, vB0, vAl0, vBl0, k0 + 64);
      COMPUTE_SET(As1, Bs1, Als1, Bls1);
      if (has2) WRITE_SET(As0, Bs0, Als0, Bls0, vA0, vB0, vAl0, vBl0);
      __syncthreads();
    }
  }
#undef LOAD_SET
#undef WRITE_SET
#undef COMPUTE_SET

  if (gridDim.z > 1) {
#pragma unroll
    for (int m = 0; m < 4; ++m) {
      int row = m0 + wr * 64 + m * 16 + l4 * 4;
#pragma unroll
      for (int n = 0; n < 4; ++n) {
        int col = n0 + wc * 64 + n * 16 + l15;
#pragma unroll
        for (int q = 0; q < 4; ++q)
          part[((size_t)kz * partM + row + q) * N + col] = acc[m][n][q];
      }
    }
    return;
  }
  // direct out: acc + bias (fp32)
#pragma unroll
  for (int m = 0; m < 4; ++m) {
    int row = m0 + wr * 64 + m * 16 + l4 * 4;
#pragma unroll
    for (int n = 0; n < 4; ++n) {
      int col = n0 + wc * 64 + n * 16 + l15;
      float bv = bias[col];
#pragma unroll
      for (int q = 0; q < 4; ++q)
        dout[(size_t)(row + q) * N + col] = acc[m][n][q] + bv;
    }
  }
}

// ---------------------------------------------------------------------------
// Attention epilogue (fused): WO split-K reduce + residual + rmsnorm2 +
// router. h2 written directly as bf16 (feeds MoE GEMM1's gathered A).
__global__ __launch_bounds__(256) void attn_epilogue_kernel(
    const float* __restrict__ part, const float* __restrict__ bo,
    const float* __restrict__ x, const float* __restrict__ n2w,
    const float* __restrict__ wr, const float* __restrict__ br,
    float* __restrict__ x1, short* __restrict__ h2b, int* __restrict__ top_i,
    float* __restrict__ top_p, float* __restrict__ probs_out) {
  int t = blockIdx.x;
  int tid = threadIdx.x;
  int c = tid * 4;
  float4 s = *(const float4*)(part + (size_t)t * CD + c);
#pragma unroll
  for (int z = 1; z < 4; ++z) {
    float4 p = *(const float4*)(part + ((size_t)z * CT + t) * CD + c);
    s.x += p.x; s.y += p.y; s.z += p.z; s.w += p.w;
  }
  float4 bv = *(const float4*)(bo + c);
  float4 xv = *(const float4*)(x + (size_t)t * CD + c);
  s.x += bv.x + xv.x; s.y += bv.y + xv.y;
  s.z += bv.z + xv.z; s.w += bv.w + xv.w;
  *(float4*)(x1 + (size_t)t * CD + c) = s;
  float ss = s.x*s.x + s.y*s.y + s.z*s.z + s.w*s.w;
  for (int off = 32; off > 0; off >>= 1) ss += __shfl_down(ss, off);
  __shared__ float red[4];
  __shared__ float s_scale;
  int lane = tid & 63, wid = tid >> 6;
  if (lane == 0) red[wid] = ss;
  __syncthreads();
  if (tid == 0) {
    float tot = red[0] + red[1] + red[2] + red[3];
    s_scale = rsqrtf(tot / (float)CD + CEPS);
  }
  __syncthreads();
  float sc = s_scale;
  float4 wv = *(const float4*)(n2w + c);
  float hv[4] = {s.x * sc * wv.x, s.y * sc * wv.y,
                 s.z * sc * wv.z, s.w * sc * wv.w};
  short4 hb = make_short4(f2bf(hv[0]), f2bf(hv[1]), f2bf(hv[2]), f2bf(hv[3]));
  ((short4*)(h2b + (size_t)t * CD))[tid] = hb;
  float a[CE] = {};
#pragma unroll
  for (int j = 0; j < 4; ++j) {
    const float* wrow = wr + (size_t)(c + j) * CE;
#pragma unroll
    for (int e = 0; e < CE; ++e) a[e] += hv[j] * wrow[e];
  }
  __shared__ float red8[256][CE];
#pragma unroll
  for (int e = 0; e < CE; ++e) red8[tid][e] = a[e];
  __syncthreads();
  for (int st = 128; st > 0; st >>= 1) {
    if (tid < st) {
#pragma unroll
      for (int e = 0; e < CE; ++e) red8[tid][e] += red8[tid + st][e];
    }
    __syncthreads();
  }
  if (tid == 0) {
    float probs[CE];
    float mx = -1e30f;
#pragma unroll
    for (int e = 0; e < CE; ++e) {
      probs[e] = red8[0][e] + br[e];
      mx = fmaxf(mx, probs[e]);
    }
    float sum = 0.f;
#pragma unroll
    for (int e = 0; e < CE; ++e) { probs[e] = __expf(probs[e] - mx); sum += probs[e]; }
    float inv = 1.0f / sum;
#pragma unroll
    for (int e = 0; e < CE; ++e) {
      probs[e] *= inv;
      probs_out[t * CE + e] = probs[e];
    }
    int i1 = 0;
#pragma unroll
    for (int e = 1; e < CE; ++e) if (probs[e] > probs[i1]) i1 = e;
    int i2 = (i1 == 0) ? 1 : 0;
#pragma unroll
    for (int e = 0; e < CE; ++e)
      if (e != i1 && probs[e] > probs[i2]) i2 = e;
    float p1 = probs[i1], p2 = probs[i2];
    float s12 = p1 + p2;
    top_i[t * 2 + 0] = i1;
    top_i[t * 2 + 1] = i2;
    top_p[t * 2 + 0] = p1 / s12;
    top_p[t * 2 + 1] = p2 / s12;
  }
}

// ---------------------------------------------------------------------------
// Fused attention v5c: v5b compute, 1-D grid of 512 with a COMPLEMENTARY
// causal-load swizzle. All 512 blocks are co-resident (2/CU); under
// round-robin block->CU assignment, blocks id and id+256 land on the same
// CU. Old (16,32) grid paired SAME-qt blocks (16-vs-2-tile CU imbalance);
// new map pairs qt with 15-qt so every CU gets T(qt)+T(15-qt) = 9 tiles.
// Pure index permutation: each (qt,bh) computed once, numerics identical.
__global__ __launch_bounds__(256) void fused_attn_kernel(
    const float* __restrict__ qkv, short* __restrict__ ctxh,
    short* __restrict__ ctxl) {
  __shared__ float Qs[32][68];    // Q tile
  __shared__ float KVs[64 * 68];  // K (stride 65) then V (stride 68)
  __shared__ float Pt[32][68];    // per-tile P (stride 68 for float4 reads)
  int id = blockIdx.x;
  int half = id >> 8;             // 0 or 1
  int qt0 = id & 15;
  int qt = half ? (15 - qt0) : qt0;
  int bh = ((id >> 4) & 15) + half * 16;
  int b = bh / CH, h = bh % CH;
  int qrow0 = qt * 32;
  int ktmax = (qrow0 + 31) >> 6;
  int tid = threadIdx.x;
  int cg = tid & 31, rg = tid >> 5;
  int r0 = rg * 4;

  // stage Q [32][64]
#pragma unroll
  for (int it = 0; it < 2; ++it) {
    int idx = it * 256 + tid;
    int r = idx >> 4, c4 = (idx & 15) * 4;
    *(float4*)&Qs[r][c4] = *(const float4*)(
        qkv + (size_t)(b * CS + qrow0 + r) * QKVP + h * CHD + c4);
  }

  float m_i[4], l_i[4], O[4][2];
#pragma unroll
  for (int i = 0; i < 4; ++i) {
    m_i[i] = -1e30f;
    l_i[i] = 0.f;
    O[i][0] = 0.f;
    O[i][1] = 0.f;
  }

  for (int kt = 0; kt <= ktmax; ++kt) {
    __syncthreads();  // prev tile's PV reads of KVs(V)/Pt done
    // stage K (scalar, stride 65)
#pragma unroll
    for (int it = 0; it < 4; ++it) {
      int idx = it * 256 + tid;
      int r = idx >> 4, c4 = (idx & 15) * 4;
      const float* src =
          qkv + (size_t)(b * CS + kt * 64 + r) * QKVP + h * CHD;
      float4 kv = *(const float4*)(src + 1024 + c4);
      KVs[r * 65 + c4 + 0] = kv.x;
      KVs[r * 65 + c4 + 1] = kv.y;
      KVs[r * 65 + c4 + 2] = kv.z;
      KVs[r * 65 + c4 + 3] = kv.w;
    }
    __syncthreads();

    // scores: s[4 rows][2 cols]
    float s[4][2] = {};
#pragma unroll 4
    for (int d = 0; d < 64; ++d) {
      float q0 = Qs[r0 + 0][d];
      float q1 = Qs[r0 + 1][d];
      float q2 = Qs[r0 + 2][d];
      float q3 = Qs[r0 + 3][d];
      float k0 = KVs[(cg * 2 + 0) * 65 + d];
      float k1 = KVs[(cg * 2 + 1) * 65 + d];
      s[0][0] += q0 * k0; s[0][1] += q0 * k1;
      s[1][0] += q1 * k0; s[1][1] += q1 * k1;
      s[2][0] += q2 * k0; s[2][1] += q2 * k1;
      s[3][0] += q3 * k0; s[3][1] += q3 * k1;
    }

    // online softmax update (per row, reduce over 32-lane col group)
#pragma unroll
    for (int i = 0; i < 4; ++i) {
      int gr = qrow0 + r0 + i;
      int gc0 = kt * 64 + cg * 2;
      float s0 = (gc0 + 0 > gr) ? -1e30f : s[i][0] * 0.125f;
      float s1 = (gc0 + 1 > gr) ? -1e30f : s[i][1] * 0.125f;
      float tmax = fmaxf(s0, s1);
#pragma unroll
      for (int off = 16; off > 0; off >>= 1)
        tmax = fmaxf(tmax, __shfl_xor(tmax, off));
      float newm = fmaxf(m_i[i], tmax);
      float p0 = __expf(s0 - newm);
      float p1 = __expf(s1 - newm);
      float tsum = p0 + p1;
#pragma unroll
      for (int off = 16; off > 0; off >>= 1) tsum += __shfl_xor(tsum, off);
      float scale = __expf(m_i[i] - newm);
      l_i[i] = l_i[i] * scale + tsum;
      m_i[i] = newm;
      O[i][0] *= scale;
      O[i][1] *= scale;
      *(float2*)&Pt[r0 + i][cg * 2] = make_float2(p0, p1);
    }
    __syncthreads();  // all K reads + Pt writes done

    // stage V into the same buffer (float4, stride 68)
#pragma unroll
    for (int it = 0; it < 4; ++it) {
      int idx = it * 256 + tid;
      int r = idx >> 4, c4 = (idx & 15) * 4;
      *(float4*)&KVs[r * 68 + c4] = *(const float4*)(
          qkv + (size_t)(b * CS + kt * 64 + r) * QKVP + 2048 + h * CHD + c4);
    }
    __syncthreads();

    // PV: per 4-c chunk, float4 P reads; same FMA order as scalar version.
#pragma unroll 2
    for (int c4 = 0; c4 < 64; c4 += 4) {
      float4 pr[4];
#pragma unroll
      for (int i = 0; i < 4; ++i) pr[i] = *(const float4*)&Pt[r0 + i][c4];
      float pv[4][4] = {{pr[0].x, pr[0].y, pr[0].z, pr[0].w},
                        {pr[1].x, pr[1].y, pr[1].z, pr[1].w},
                        {pr[2].x, pr[2].y, pr[2].z, pr[2].w},
                        {pr[3].x, pr[3].y, pr[3].z, pr[3].w}};
#pragma unroll
      for (int j = 0; j < 4; ++j) {
        int c = c4 + j;
        float v0 = KVs[c * 68 + cg];
        float v1 = KVs[c * 68 + cg + 32];
        O[0][0] += pv[0][j] * v0; O[0][1] += pv[0][j] * v1;
        O[1][0] += pv[1][j] * v0; O[1][1] += pv[1][j] * v1;
        O[2][0] += pv[2][j] * v0; O[2][1] += pv[2][j] * v1;
        O[3][0] += pv[3][j] * v0; O[3][1] += pv[3][j] * v1;
      }
    }
  }

  // epilogue: normalize by l, write hi/lo bf16 planes
#pragma unroll
  for (int i = 0; i < 4; ++i) {
    float inv = 1.0f / l_i[i];
#pragma unroll
    for (int jd = 0; jd < 2; ++jd) {
      int dv = cg + 32 * jd;
      size_t oi = (size_t)(b * CS + qrow0 + r0 + i) * CD + h * CHD + dv;
      float v = O[i][jd] * inv;
      short hi = f2bf(v);
      ctxh[oi] = hi;
      ctxl[oi] = f2bf(v - bf2f(hi));
    }
  }
}

// ---------------------------------------------------------------------------
// Finalize+gather (1 block): counts/psum, offsets, tile map, aux loss, zrow,
// row_map init, then the gather itself via LDS cursors (order-invariant:
// row content depends only on token, so any within-expert permutation yields
// bitwise-identical output).
__global__ __launch_bounds__(256) void finalize_kernel(
    const int* __restrict__ top_i, const float* __restrict__ probs,
    int* __restrict__ tile_e, int* __restrict__ total_padded,
    int* __restrict__ row_map, int* __restrict__ row_of,
    short* __restrict__ zrow, float* __restrict__ aux_out) {
  int tid = threadIdx.x;
  __shared__ float redp[256][CE];
  __shared__ int redc[256][CE];
  __shared__ int s_off[CE + 1];
  __shared__ int s_cur[CE];
  float lp[CE] = {};
  int lc[CE] = {};
  for (int t = tid; t < CT; t += 256) {
    lc[top_i[t * 2 + 0]]++;
    lc[top_i[t * 2 + 1]]++;
#pragma unroll
    for (int e = 0; e < CE; ++e) lp[e] += probs[t * CE + e];
  }
#pragma unroll
  for (int e = 0; e < CE; ++e) { redp[tid][e] = lp[e]; redc[tid][e] = lc[e]; }
  __syncthreads();
  for (int s = 128; s > 0; s >>= 1) {
    if (tid < s) {
#pragma unroll
      for (int e = 0; e < CE; ++e) {
        redp[tid][e] += redp[tid + s][e];
        redc[tid][e] += redc[tid + s][e];
      }
    }
    __syncthreads();
  }
  if (tid == 0) {
    int o = 0;
    for (int e = 0; e < CE; ++e) {
      s_off[e] = o;
      o += ((redc[0][e] + 127) >> 7) << 7;
    }
    s_off[CE] = o;
    *total_padded = o;
    int nt = o >> 7;
    for (int i = 0; i < nt; ++i) {
      int e = 0;
      while (e < CE - 1 && i * 128 >= s_off[e + 1]) e++;
      tile_e[i] = e;
    }
    float aux = 0.f;
    for (int e = 0; e < CE; ++e)
      aux += ((float)redc[0][e] / (float)(CT * CK)) * (redp[0][e] / (float)CT);
    aux_out[0] = aux * (float)CE;
  }
  if (tid < CE) s_cur[tid] = 0;
  ((short4*)zrow)[tid] = make_short4(0, 0, 0, 0);  // 256*4 = 1024 shorts
  __syncthreads();
  for (int i = tid; i < MAXROWS; i += 256) row_map[i] = -1;
  __syncthreads();
  // gather: assign rows within expert segments (LDS cursors)
  for (int idx = tid; idx < CT * CK; idx += 256) {
    int e = top_i[idx];
    int pos = s_off[e] + atomicAdd(&s_cur[e], 1);
    row_map[pos] = idx >> 1;
    row_of[idx] = pos;
  }
}

// Fused GEMM2-reduce + combine: per token, read only its 2 routed rows'
// partials, add b2[e], weight, residual.
__global__ __launch_bounds__(256) void combine_g2_kernel(
    const float* __restrict__ part, int partM, int nz,
    const float* __restrict__ b2, const int* __restrict__ tile_e,
    const int* __restrict__ row_of, const float* __restrict__ top_p,
    const float* __restrict__ x1, float* __restrict__ out) {
  int t = blockIdx.x;
  int c = threadIdx.x * 4;
  float4 r = *(const float4*)(x1 + (size_t)t * CD + c);
#pragma unroll
  for (int s = 0; s < CK; ++s) {
    int row = row_of[t * 2 + s];
    int e = tile_e[row >> 7];
    float w = top_p[t * 2 + s];
    float4 acc = *(const float4*)(part + (size_t)row * CD + c);
    for (int z = 1; z < nz; ++z) {
      float4 p = *(const float4*)(part + ((size_t)z * partM + row) * CD + c);
      acc.x += p.x; acc.y += p.y; acc.z += p.z; acc.w += p.w;
    }
    float4 bv = *(const float4*)(b2 + (size_t)e * CD + c);
    r.x += w * (acc.x + bv.x);
    r.y += w * (acc.y + bv.y);
    r.z += w * (acc.z + bv.z);
    r.w += w * (acc.w + bv.w);
  }
  *(float4*)(out + (size_t)t * CD + c) = r;
}

// ---------------------------------------------------------------------------
extern "C" void kernel_launch(void* const* d_in, const int* in_sizes, int n_in,
                              void* d_out, int out_size, void* d_ws,
                              size_t ws_size, hipStream_t stream) {
  const float* x   = (const float*)d_in[0];
  const float* n1w = (const float*)d_in[1];
  const float* n2w = (const float*)d_in[2];
  const float* wq  = (const float*)d_in[3];
  const float* bq  = (const float*)d_in[4];
  const float* wk  = (const float*)d_in[5];
  const float* bk  = (const float*)d_in[6];
  const float* wv  = (const float*)d_in[7];
  const float* bv  = (const float*)d_in[8];
  const float* wo  = (const float*)d_in[9];
  const float* bo  = (const float*)d_in[10];
  const float* wr  = (const float*)d_in[11];
  const float* br  = (const float*)d_in[12];
  const float* w1  = (const float*)d_in[13];
  const float* b1  = (const float*)d_in[14];
  const float* w2  = (const float*)d_in[15];
  const float* b2  = (const float*)d_in[16];
  float* out = (float*)d_out;

  char* base = (char*)d_ws;
  size_t off = 0;
  auto alloc = [&](size_t bytes) -> void* {
    void* p = base + off;
    off += (bytes + 255) & ~(size_t)255;
    return p;
  };
  float* f_x1   = (float*)alloc((size_t)CT * CD * 4);
  short* f_h2b  = (short*)alloc((size_t)CT * CD * 2);   // bf16 h2 (MoE input)
  short* f_hid  = (short*)alloc((size_t)MAXROWS * CF * 2);
  short* f_hh   = (short*)alloc((size_t)CT * CD * 2);
  short* f_hl   = (short*)alloc((size_t)CT * CD * 2);
  short* f_wqkvh = (short*)alloc((size_t)QKVP * CD * 2);
  short* f_wqkvl = (short*)alloc((size_t)QKVP * CD * 2);
  float* f_qkv  = (float*)alloc((size_t)CT * QKVP * 4);
  short* f_ctxh = (short*)alloc((size_t)CT * CD * 2);
  short* f_ctxl = (short*)alloc((size_t)CT * CD * 2);
  short* f_woth = (short*)alloc((size_t)CD * CD * 2);
  short* f_wotl = (short*)alloc((size_t)CD * CD * 2);
  float* f_bqkv = (float*)alloc(QKVP * 4);
  float* f_topp = (float*)alloc(CT * CK * 4);
  float* f_probs = (float*)alloc(CT * CE * 4);
  short* f_zrow = (short*)alloc(CD * 2);
  int* i_topi   = (int*)alloc(CT * CK * 4);
  int* i_rowof  = (int*)alloc(CT * CK * 4);
  int* i_rowmap = (int*)alloc(MAXROWS * 4);
  int* i_tile   = (int*)alloc(MAXTILES * 4);
  int* i_total  = (int*)alloc(4);
  // G (64MB): w1t -> w2t (sequential reuse)
  short* f_wG = (short*)alloc((size_t)CE * CD * CF * 2);
  short* f_w1t = f_wG;
  short* f_w2t = f_wG;
  // Rs (48MB): WO partials -> GEMM2 partials (disjoint)
  void* Rs = alloc((size_t)4 * MAXROWS * CD * 4);
  float* f_partwo = (float*)Rs;
  float* f_partg2 = (float*)Rs;

  dim3 b256(256);

  TPtrs tp;
  tp.w[0] = wq; tp.w[1] = wk; tp.w[2] = wv; tp.w[3] = wo;
  tp.hh[0] = f_wqkvh + 0 * (size_t)CD * CD;
  tp.hh[1] = f_wqkvh + 1 * (size_t)CD * CD;
  tp.hh[2] = f_wqkvh + 2 * (size_t)CD * CD;
  tp.hh[3] = f_woth;
  tp.ll[0] = f_wqkvl + 0 * (size_t)CD * CD;
  tp.ll[1] = f_wqkvl + 1 * (size_t)CD * CD;
  tp.ll[2] = f_wqkvl + 2 * (size_t)CD * CD;
  tp.ll[3] = f_wotl;
  tp.bq = bq; tp.bk = bk; tp.bv = bv; tp.bqkv = f_bqkv;
  tp.xin = x; tp.n1w = n1w; tp.hH = f_hh; tp.hL = f_hl;
  // z: 0-3 = wq/wk/wv/wo transposes, 4 = bias pack, 5 = rmsnorm1
  transpose4_kernel<<<dim3(16, 16, 6), b256, 0, stream>>>(tp);
  transpose_convert_kernel<<<dim3(CF / 64, CD / 64, CE), b256, 0, stream>>>(
      w1, f_w1t, nullptr, CD, CF);

  // ---- attention ----
  // QKV: split-K=1, bias fused, direct fp32 out (no reduce pass)
  mfma_gemm_kernel<1><<<dim3(QKVP / 128, CT / 128, 1), b256, 0, stream>>>(
      f_hh, f_hl, f_wqkvh, f_wqkvl, f_bqkv, f_qkv, nullptr, CT, QKVP, CD);
  fused_attn_kernel<<<dim3(512), b256, 0, stream>>>(f_qkv, f_ctxh, f_ctxl);
  mfma_gemm_kernel<1><<<dim3(CD / 128, CT / 128, 4), b256, 0, stream>>>(
      f_ctxh, f_ctxl, f_woth, f_wotl, nullptr, nullptr, f_partwo, CT, CD, CD);
  attn_epilogue_kernel<<<CT, b256, 0, stream>>>(f_partwo, bo, x, n2w, wr, br,
                                                f_x1, f_h2b, i_topi, f_topp,
                                                f_probs);

  // ---- MoE ----
  finalize_kernel<<<1, 256, 0, stream>>>(i_topi, f_probs, i_tile, i_total,
                                         i_rowmap, i_rowof, f_zrow,
                                         out + (size_t)CT * CD);

  // expert GEMM1: A gathered via row_map from bf16 h2 (no Xg materialization)
  moe_gemm_kernel<1, 1><<<dim3(CF / 128, MAXTILES, 1), dim3(512), 0, stream>>>(
      f_h2b, i_rowmap, f_zrow, f_w1t, b1, f_hid, nullptr, 0, CF, CD, i_tile,
      i_total);
  transpose_convert_kernel<<<dim3(CD / 64, CF / 64, CE), b256, 0, stream>>>(
      w2, f_w2t, nullptr, CF, CD);
  // expert GEMM2: BN=128, split-K=4
  moe_gemm_kernel<0, 0><<<dim3(CD / 128, MAXTILES, 4), dim3(512), 0, stream>>>(
      f_hid, nullptr, nullptr, f_w2t, nullptr, nullptr, f_partg2, MAXROWS, CD,
      CF, i_tile, i_total);
  combine_g2_kernel<<<CT, b256, 0, stream>>>(f_partg2, MAXROWS, 4, b2, i_tile,
                                             i_rowof, f_topp, f_x1, out);
}

// Round 20
// 290.000 us; speedup vs baseline: 1.2715x; 1.0234x over previous
//
#include <hip/hip_runtime.h>
#include <math.h>

// Problem constants
#define CB 2
#define CS 512
#define CD 1024
#define CH 16
#define CHD 64
#define CF 4096
#define CE 8
#define CK 2
#define CT (CB*CS)      // 1024 tokens
#define CBH (CB*CH)     // 32 (batch*heads)
#define CEPS 1e-6f
#define QKVP 3072       // packed q|k|v row pitch
#define MAXROWS 3072    // 2048 + 8*127 padded to 128
#define MAXTILES (MAXROWS/128)

typedef __attribute__((ext_vector_type(8))) short bf16x8;
typedef __attribute__((ext_vector_type(4))) float f32x4;

__device__ __forceinline__ short f2bf(float f) {
  unsigned u = __float_as_uint(f);
  unsigned r = (u + 0x7FFF + ((u >> 16) & 1)) >> 16;
  return (short)r;
}
__device__ __forceinline__ float bf2f(short h) {
  return __uint_as_float(((unsigned)(unsigned short)h) << 16);
}

__device__ __forceinline__ void gload_lds16(const void* g, void* l) {
  __builtin_amdgcn_global_load_lds(
      (const __attribute__((address_space(1))) unsigned int*)g,
      (__attribute__((address_space(3))) unsigned int*)l, 16, 0, 0);
}

// ---------------------------------------------------------------------------
// Tiled transpose+convert, 64x64 tile, 16B short8 stores:
// W[e][Kd][Nd] f32 -> Wth[e][Nd][Kd] bf16 (+ optional lo plane).
__global__ __launch_bounds__(256) void transpose_convert_kernel(
    const float* __restrict__ W, short* __restrict__ Wth,
    short* __restrict__ Wtl, int Kd, int Nd) {
  int e = blockIdx.z;
  const float* Wb = W + (size_t)e * Kd * Nd;
  size_t obase = (size_t)e * Kd * Nd;
  int n0 = blockIdx.x * 64, k0 = blockIdx.y * 64;
  __shared__ float t[64][65];
  int tid = threadIdx.x;
#pragma unroll
  for (int i = 0; i < 4; ++i) {
    int idx = i * 256 + tid;
    int r = idx >> 4, c4 = (idx & 15) * 4;
    float4 v = *(const float4*)(Wb + (size_t)(k0 + r) * Nd + n0 + c4);
    t[r][c4] = v.x; t[r][c4 + 1] = v.y; t[r][c4 + 2] = v.z; t[r][c4 + 3] = v.w;
  }
  __syncthreads();
  int n = tid >> 2, k16 = (tid & 3) * 16;
  short th[16], tl[16];
#pragma unroll
  for (int j = 0; j < 16; ++j) {
    float v = t[k16 + j][n];
    short hi = f2bf(v);
    th[j] = hi;
    tl[j] = f2bf(v - bf2f(hi));
  }
  size_t oo = obase + (size_t)(n0 + n) * Kd + k0 + k16;
  ((int4*)(Wth + oo))[0] = ((int4*)th)[0];
  ((int4*)(Wth + oo + 8))[0] = ((int4*)th)[1];
  if (Wtl) {
    ((int4*)(Wtl + oo))[0] = ((int4*)tl)[0];
    ((int4*)(Wtl + oo + 8))[0] = ((int4*)tl)[1];
  }
}

// Four DxD transposes (wq,wk,wv,wo), bias packing (z==4), rmsnorm1 (z==5).
struct TPtrs {
  const float* w[4];
  short* hh[4];
  short* ll[4];
  const float* bq;
  const float* bk;
  const float* bv;
  float* bqkv;
  const float* xin;
  const float* n1w;
  short* hH;
  short* hL;
};
__global__ __launch_bounds__(256) void transpose4_kernel(TPtrs p) {
  int z = blockIdx.z;
  int tid = threadIdx.x;
  if (z == 4) {
    // bias packing: 12 blocks x 256 threads cover QKVP=3072
    if (blockIdx.y == 0 && blockIdx.x < 12) {
      int i = blockIdx.x * 256 + tid;
      if (i < QKVP)
        p.bqkv[i] =
            (i < 1024) ? p.bq[i] : (i < 2048 ? p.bk[i - 1024] : p.bv[i - 2048]);
    }
    return;
  }
  if (z == 5) {
    // rmsnorm1 hi/lo: 256 blocks x 4 tokens each
    __shared__ float red[4];
    __shared__ float s_scale;
    int bid = blockIdx.y * 16 + blockIdx.x;
    int lane = tid & 63, wid = tid >> 6;
    for (int tt = 0; tt < 4; ++tt) {
      int t = bid * 4 + tt;
      float4 xv = ((const float4*)(p.xin + (size_t)t * CD))[tid];
      float ss = xv.x*xv.x + xv.y*xv.y + xv.z*xv.z + xv.w*xv.w;
      for (int off = 32; off > 0; off >>= 1) ss += __shfl_down(ss, off);
      if (lane == 0) red[wid] = ss;
      __syncthreads();
      if (tid == 0) {
        float tot = red[0] + red[1] + red[2] + red[3];
        s_scale = rsqrtf(tot / (float)CD + CEPS);
      }
      __syncthreads();
      float sc = s_scale;
      float4 wv = ((const float4*)p.n1w)[tid];
      float o[4] = {xv.x * sc * wv.x, xv.y * sc * wv.y,
                    xv.z * sc * wv.z, xv.w * sc * wv.w};
      short4 hi, lo;
      short* hp = (short*)&hi; short* lp = (short*)&lo;
#pragma unroll
      for (int i = 0; i < 4; ++i) {
        short h = f2bf(o[i]);
        hp[i] = h;
        lp[i] = f2bf(o[i] - bf2f(h));
      }
      ((short4*)(p.hH + (size_t)t * CD))[tid] = hi;
      ((short4*)(p.hL + (size_t)t * CD))[tid] = lo;
      __syncthreads();
    }
    return;
  }
  const float* Wb = p.w[z];
  short* Wth = p.hh[z];
  short* Wtl = p.ll[z];
  int n0 = blockIdx.x * 64, k0 = blockIdx.y * 64;
  __shared__ float t[64][65];
#pragma unroll
  for (int i = 0; i < 4; ++i) {
    int idx = i * 256 + tid;
    int r = idx >> 4, c4 = (idx & 15) * 4;
    float4 v = *(const float4*)(Wb + (size_t)(k0 + r) * CD + n0 + c4);
    t[r][c4] = v.x; t[r][c4 + 1] = v.y; t[r][c4 + 2] = v.z; t[r][c4 + 3] = v.w;
  }
  __syncthreads();
  int n = tid >> 2, k16 = (tid & 3) * 16;
  short th[16], tl[16];
#pragma unroll
  for (int j = 0; j < 16; ++j) {
    float v = t[k16 + j][n];
    short hi = f2bf(v);
    th[j] = hi;
    tl[j] = f2bf(v - bf2f(hi));
  }
  size_t oo = (size_t)(n0 + n) * CD + k0 + k16;
  ((int4*)(Wth + oo))[0] = ((int4*)th)[0];
  ((int4*)(Wth + oo + 8))[0] = ((int4*)th)[1];
  ((int4*)(Wtl + oo))[0] = ((int4*)tl)[0];
  ((int4*)(Wtl + oo + 8))[0] = ((int4*)tl)[1];
}

// ---------------------------------------------------------------------------
// MoE grouped GEMM: BM=128, BN=128, BK=64, 8 waves (2x4; wave out 64x32).
// LDS 64KB -> 2 blocks/CU. A source optionally row_map-indirect.
template <int SILU, int OUTBF>
__global__ __launch_bounds__(512) void moe_gemm_kernel(
    const short* __restrict__ A, const int* __restrict__ row_map,
    const short* __restrict__ zrow, const short* __restrict__ Bt,
    const float* __restrict__ bias, void* __restrict__ Cout,
    float* __restrict__ part, int partM, int N, int K,
    const int* __restrict__ tile_e, const int* __restrict__ total_rows) {
  __shared__ __align__(16) short A0[128 * 64], A1[128 * 64];
  __shared__ __align__(16) short B0[128 * 64], B1[128 * 64];
  int tid = threadIdx.x;
  int m0 = blockIdx.y * 128, n0 = blockIdx.x * 128;
  if (m0 >= *total_rows) return;
  int e = tile_e[blockIdx.y];
  const short* Bb = Bt + (size_t)e * N * K;
  const float* biasb = bias ? bias + (size_t)e * N : nullptr;
  int kz = blockIdx.z;
  int kchunk = K / gridDim.z;
  int kbeg = kz * kchunk;
  int nsteps = kchunk >> 6;
  int lane = tid & 63, w = tid >> 6;
  int wr = w >> 2, wc = w & 3;
  int l15 = lane & 15, l4 = lane >> 4;
  f32x4 acc[4][2] = {};

  const short* aB[2];
#pragma unroll
  for (int i = 0; i < 2; ++i) {
    int r = (i * 512 + tid) >> 3;
    int grow = m0 + r;
    if (row_map) {
      int tok = row_map[grow];
      aB[i] = (tok < 0) ? zrow : A + (size_t)tok * K;
    } else {
      aB[i] = A + (size_t)grow * K;
    }
  }

#define STAGE(AS_, BS_, KK)                                                   \
  {                                                                           \
    _Pragma("unroll") for (int i = 0; i < 2; ++i) {                           \
      int c = i * 512 + tid;                                                  \
      int r = c >> 3, gs = c & 7;                                             \
      int g = gs ^ (r & 7);                                                   \
      gload_lds16(aB[i] + (KK) + g * 8, &AS_[c * 8]);                         \
    }                                                                         \
    _Pragma("unroll") for (int i = 0; i < 2; ++i) {                           \
      int c = i * 512 + tid;                                                  \
      int r = c >> 3, gs = c & 7;                                             \
      int g = gs ^ (r & 7);                                                   \
      gload_lds16(Bb + (size_t)(n0 + r) * K + (KK) + g * 8, &BS_[c * 8]);     \
    }                                                                         \
  }

#define COMPUTE(AS_, BS_)                                                     \
  {                                                                           \
    _Pragma("unroll") for (int ks = 0; ks < 2; ++ks) {                        \
      bf16x8 a[4], b[2];                                                      \
      _Pragma("unroll") for (int m = 0; m < 4; ++m) {                         \
        int row = wr * 64 + m * 16 + l15;                                     \
        int slot = (ks * 4 + l4) ^ (row & 7);                                 \
        a[m] = *(const bf16x8*)&AS_[(row * 8 + slot) * 8];                    \
      }                                                                       \
      _Pragma("unroll") for (int n = 0; n < 2; ++n) {                         \
        int row = wc * 32 + n * 16 + l15;                                     \
        int slot = (ks * 4 + l4) ^ (row & 7);                                 \
        b[n] = *(const bf16x8*)&BS_[(row * 8 + slot) * 8];                    \
      }                                                                       \
      _Pragma("unroll") for (int m = 0; m < 4; ++m)                           \
      _Pragma("unroll") for (int n = 0; n < 2; ++n)                           \
        acc[m][n] = __builtin_amdgcn_mfma_f32_16x16x32_bf16(a[m], b[n],       \
                                                            acc[m][n], 0, 0, 0); \
    }                                                                         \
  }

  STAGE(A0, B0, kbeg);
  __syncthreads();
  for (int s = 0; s < nsteps; s += 2) {
    int k0 = kbeg + (s << 6);
    bool has1 = (s + 1 < nsteps), has2 = (s + 2 < nsteps);
    if (has1) STAGE(A1, B1, k0 + 64);
    COMPUTE(A0, B0);
    __syncthreads();
    if (has1) {
      if (has2) STAGE(A0, B0, k0 + 128);
      COMPUTE(A1, B1);
      __syncthreads();
    }
  }
#undef STAGE
#undef COMPUTE

  if (gridDim.z > 1) {
#pragma unroll
    for (int m = 0; m < 4; ++m) {
      int row = m0 + wr * 64 + m * 16 + l4 * 4;
#pragma unroll
      for (int n = 0; n < 2; ++n) {
        int col = n0 + wc * 32 + n * 16 + l15;
#pragma unroll
        for (int q = 0; q < 4; ++q)
          part[((size_t)kz * partM + row + q) * N + col] = acc[m][n][q];
      }
    }
    return;
  }
  float* outf = (float*)Cout;
  short* outb = (short*)Cout;
#pragma unroll
  for (int m = 0; m < 4; ++m) {
    int row = m0 + wr * 64 + m * 16 + l4 * 4;
#pragma unroll
    for (int n = 0; n < 2; ++n) {
      int col = n0 + wc * 32 + n * 16 + l15;
      float bv = biasb[col];
#pragma unroll
      for (int q = 0; q < 4; ++q) {
        float v = acc[m][n][q] + bv;
        if (SILU) v = v / (1.f + __expf(-v));
        if (OUTBF) outb[(size_t)(row + q) * N + col] = f2bf(v);
        else outf[(size_t)(row + q) * N + col] = v;
      }
    }
  }
}

// ---------------------------------------------------------------------------
// Attention MFMA GEMM v2: BM=128, BN=64, BK=32, 4 waves (4x1; wave out
// 32x64, acc[2][4]), hi/lo reg-staged. LDS 48KB -> 3 blocks/CU (was 64KB/2);
// QKV grid 192->384 blocks, WO 256->512 -> full CU fill + overlap.
// Numerics bit-identical (same per-element K-chain and MFMA order).
// gridDim.z>1: split-K partials. gridDim.z==1: direct fp32 out + bias.
template <int LO>
__global__ __launch_bounds__(256) void mfma_gemm_kernel(
    const short* __restrict__ Ah, const short* __restrict__ Al,
    const short* __restrict__ Bh, const short* __restrict__ Bl,
    const float* __restrict__ bias, float* __restrict__ dout,
    float* __restrict__ part, int partM, int N, int K) {
  __shared__ short As0[4096], Bs0[2048], As1[4096], Bs1[2048];
  __shared__ short Als0[LO ? 4096 : 64], Bls0[LO ? 2048 : 64];
  __shared__ short Als1[LO ? 4096 : 64], Bls1[LO ? 2048 : 64];
  int tid = threadIdx.x;
  int m0 = blockIdx.y * 128, n0 = blockIdx.x * 64;
  int kz = blockIdx.z;
  int kchunk = K / gridDim.z;
  int kbeg = kz * kchunk;
  int nsteps = kchunk >> 5;
  int lane = tid & 63, w = tid >> 6;
  int wr = w;  // 4x1 wave grid: wave out rows wr*32..+31, cols 0..63
  int l15 = lane & 15, l4 = lane >> 4;
  int xorl = (l15 & 3) ^ ((l15 >> 2) & 3);
  f32x4 acc[2][4] = {};
  bf16x8 vA0[2], vAl0[2], vA1[2], vAl1[2];
  bf16x8 vB0, vBl0, vB1, vBl1;

#define LOAD_SET(VA, VB, VAL, VBL, KK)                                        \
  {                                                                           \
    _Pragma("unroll") for (int ic = 0; ic < 2; ++ic) {                        \
      int c = ic * 256 + tid;                                                 \
      int r = c >> 2, g = c & 3;                                              \
      size_t ao = (size_t)(m0 + r) * K + (KK) + g * 8;                        \
      VA[ic] = *(const bf16x8*)(Ah + ao);                                     \
      if (LO) VAL[ic] = *(const bf16x8*)(Al + ao);                            \
    }                                                                         \
    {                                                                         \
      int r = tid >> 2, g = tid & 3;                                          \
      size_t bo = (size_t)(n0 + r) * K + (KK) + g * 8;                        \
      VB = *(const bf16x8*)(Bh + bo);                                         \
      if (LO) VBL = *(const bf16x8*)(Bl + bo);                                \
    }                                                                         \
  }

#define WRITE_SET(AS_, BS_, ALS_, BLS_, VA, VB, VAL, VBL)                     \
  {                                                                           \
    _Pragma("unroll") for (int ic = 0; ic < 2; ++ic) {                        \
      int c = ic * 256 + tid;                                                 \
      int r = c >> 2, g = c & 3;                                              \
      int ch = (r * 4 + (g ^ (r & 3) ^ ((r >> 2) & 3))) * 8;                  \
      *(bf16x8*)&AS_[ch] = VA[ic];                                            \
      if (LO) *(bf16x8*)&ALS_[ch] = VAL[ic];                                  \
    }                                                                         \
    {                                                                         \
      int r = tid >> 2, g = tid & 3;                                          \
      int ch = (r * 4 + (g ^ (r & 3) ^ ((r >> 2) & 3))) * 8;                  \
      *(bf16x8*)&BS_[ch] = VB;                                                \
      if (LO) *(bf16x8*)&BLS_[ch] = VBL;                                      \
    }                                                                         \
  }

#define COMPUTE_SET(AS_, BS_, ALS_, BLS_)                                     \
  {                                                                           \
    bf16x8 ah[2], al[2];                                                      \
    _Pragma("unroll") for (int m = 0; m < 2; ++m) {                           \
      int row = wr * 32 + m * 16 + l15;                                       \
      int idx = (row * 4 + (l4 ^ xorl)) * 8;                                  \
      ah[m] = *(const bf16x8*)&AS_[idx];                                      \
      if (LO) al[m] = *(const bf16x8*)&ALS_[idx];                             \
    }                                                                         \
    _Pragma("unroll") for (int n = 0; n < 4; ++n) {                           \
      int row = n * 16 + l15;                                                 \
      int idx = (row * 4 + (l4 ^ xorl)) * 8;                                  \
      bf16x8 bhn = *(const bf16x8*)&BS_[idx];                                 \
      bf16x8 bln;                                                             \
      if (LO) bln = *(const bf16x8*)&BLS_[idx];                               \
      _Pragma("unroll") for (int m = 0; m < 2; ++m) {                         \
        acc[m][n] = __builtin_amdgcn_mfma_f32_16x16x32_bf16(ah[m], bhn,       \
                                                            acc[m][n], 0, 0, 0); \
        if (LO) {                                                             \
          acc[m][n] = __builtin_amdgcn_mfma_f32_16x16x32_bf16(al[m], bhn,     \
                                                              acc[m][n], 0, 0, 0); \
          acc[m][n] = __builtin_amdgcn_mfma_f32_16x16x32_bf16(ah[m], bln,     \
                                                              acc[m][n], 0, 0, 0); \
        }                                                                     \
      }                                                                       \
    }                                                                         \
  }

  LOAD_SET(vA0, vB0, vAl0, vBl0, kbeg);
  WRITE_SET(As0, Bs0, Als0, Bls0, vA0, vB0, vAl0, vBl0);
  __syncthreads();
  for (int s = 0; s < nsteps; s += 2) {
    int k0 = kbeg + (s << 5);
    bool has1 = (s + 1 < nsteps), has2 = (s + 2 < nsteps);
    if (has1) LOAD_SET(vA1, vB1, vAl1, vBl1, k0 + 32);
    COMPUTE_SET(As0, Bs0, Als0, Bls0);
    if (has1) WRITE_SET(As1, Bs1, Als1, Bls1, vA1, vB1, vAl1, vBl1);
    __syncthreads();
    if (has1) {
      if (has2) LOAD_SET(vA0, vB0, vAl0, vBl0, k0 + 64);
      COMPUTE_SET(As1, Bs1, Als1, Bls1);
      if (has2) WRITE_SET(As0, Bs0, Als0, Bls0, vA0, vB0, vAl0, vBl0);
      __syncthreads();
    }
  }
#undef LOAD_SET
#undef WRITE_SET
#undef COMPUTE_SET

  if (gridDim.z > 1) {
#pragma unroll
    for (int m = 0; m < 2; ++m) {
      int row = m0 + wr * 32 + m * 16 + l4 * 4;
#pragma unroll
      for (int n = 0; n < 4; ++n) {
        int col = n0 + n * 16 + l15;
#pragma unroll
        for (int q = 0; q < 4; ++q)
          part[((size_t)kz * partM + row + q) * N + col] = acc[m][n][q];
      }
    }
    return;
  }
  // direct out: acc + bias (fp32)
#pragma unroll
  for (int m = 0; m < 2; ++m) {
    int row = m0 + wr * 32 + m * 16 + l4 * 4;
#pragma unroll
    for (int n = 0; n < 4; ++n) {
      int col = n0 + n * 16 + l15;
      float bv = bias[col];
#pragma unroll
      for (int q = 0; q < 4; ++q)
        dout[(size_t)(row + q) * N + col] = acc[m][n][q] + bv;
    }
  }
}

// ---------------------------------------------------------------------------
// Attention epilogue (fused): WO split-K reduce + residual + rmsnorm2 +
// router. h2 written directly as bf16 (feeds MoE GEMM1's gathered A).
__global__ __launch_bounds__(256) void attn_epilogue_kernel(
    const float* __restrict__ part, const float* __restrict__ bo,
    const float* __restrict__ x, const float* __restrict__ n2w,
    const float* __restrict__ wr, const float* __restrict__ br,
    float* __restrict__ x1, short* __restrict__ h2b, int* __restrict__ top_i,
    float* __restrict__ top_p, float* __restrict__ probs_out) {
  int t = blockIdx.x;
  int tid = threadIdx.x;
  int c = tid * 4;
  float4 s = *(const float4*)(part + (size_t)t * CD + c);
#pragma unroll
  for (int z = 1; z < 4; ++z) {
    float4 p = *(const float4*)(part + ((size_t)z * CT + t) * CD + c);
    s.x += p.x; s.y += p.y; s.z += p.z; s.w += p.w;
  }
  float4 bv = *(const float4*)(bo + c);
  float4 xv = *(const float4*)(x + (size_t)t * CD + c);
  s.x += bv.x + xv.x; s.y += bv.y + xv.y;
  s.z += bv.z + xv.z; s.w += bv.w + xv.w;
  *(float4*)(x1 + (size_t)t * CD + c) = s;
  float ss = s.x*s.x + s.y*s.y + s.z*s.z + s.w*s.w;
  for (int off = 32; off > 0; off >>= 1) ss += __shfl_down(ss, off);
  __shared__ float red[4];
  __shared__ float s_scale;
  int lane = tid & 63, wid = tid >> 6;
  if (lane == 0) red[wid] = ss;
  __syncthreads();
  if (tid == 0) {
    float tot = red[0] + red[1] + red[2] + red[3];
    s_scale = rsqrtf(tot / (float)CD + CEPS);
  }
  __syncthreads();
  float sc = s_scale;
  float4 wv = *(const float4*)(n2w + c);
  float hv[4] = {s.x * sc * wv.x, s.y * sc * wv.y,
                 s.z * sc * wv.z, s.w * sc * wv.w};
  short4 hb = make_short4(f2bf(hv[0]), f2bf(hv[1]), f2bf(hv[2]), f2bf(hv[3]));
  ((short4*)(h2b + (size_t)t * CD))[tid] = hb;
  float a[CE] = {};
#pragma unroll
  for (int j = 0; j < 4; ++j) {
    const float* wrow = wr + (size_t)(c + j) * CE;
#pragma unroll
    for (int e = 0; e < CE; ++e) a[e] += hv[j] * wrow[e];
  }
  __shared__ float red8[256][CE];
#pragma unroll
  for (int e = 0; e < CE; ++e) red8[tid][e] = a[e];
  __syncthreads();
  for (int st = 128; st > 0; st >>= 1) {
    if (tid < st) {
#pragma unroll
      for (int e = 0; e < CE; ++e) red8[tid][e] += red8[tid + st][e];
    }
    __syncthreads();
  }
  if (tid == 0) {
    float probs[CE];
    float mx = -1e30f;
#pragma unroll
    for (int e = 0; e < CE; ++e) {
      probs[e] = red8[0][e] + br[e];
      mx = fmaxf(mx, probs[e]);
    }
    float sum = 0.f;
#pragma unroll
    for (int e = 0; e < CE; ++e) { probs[e] = __expf(probs[e] - mx); sum += probs[e]; }
    float inv = 1.0f / sum;
#pragma unroll
    for (int e = 0; e < CE; ++e) {
      probs[e] *= inv;
      probs_out[t * CE + e] = probs[e];
    }
    int i1 = 0;
#pragma unroll
    for (int e = 1; e < CE; ++e) if (probs[e] > probs[i1]) i1 = e;
    int i2 = (i1 == 0) ? 1 : 0;
#pragma unroll
    for (int e = 0; e < CE; ++e)
      if (e != i1 && probs[e] > probs[i2]) i2 = e;
    float p1 = probs[i1], p2 = probs[i2];
    float s12 = p1 + p2;
    top_i[t * 2 + 0] = i1;
    top_i[t * 2 + 1] = i2;
    top_p[t * 2 + 0] = p1 / s12;
    top_p[t * 2 + 1] = p2 / s12;
  }
}

// ---------------------------------------------------------------------------
// Fused attention v5c (unchanged from round 19): flash online softmax,
// K/V LDS time-share, complementary causal-load swizzle over 1-D grid 512.
__global__ __launch_bounds__(256) void fused_attn_kernel(
    const float* __restrict__ qkv, short* __restrict__ ctxh,
    short* __restrict__ ctxl) {
  __shared__ float Qs[32][68];    // Q tile
  __shared__ float KVs[64 * 68];  // K (stride 65) then V (stride 68)
  __shared__ float Pt[32][68];    // per-tile P (stride 68 for float4 reads)
  int id = blockIdx.x;
  int half = id >> 8;             // 0 or 1
  int qt0 = id & 15;
  int qt = half ? (15 - qt0) : qt0;
  int bh = ((id >> 4) & 15) + half * 16;
  int b = bh / CH, h = bh % CH;
  int qrow0 = qt * 32;
  int ktmax = (qrow0 + 31) >> 6;
  int tid = threadIdx.x;
  int cg = tid & 31, rg = tid >> 5;
  int r0 = rg * 4;

  // stage Q [32][64]
#pragma unroll
  for (int it = 0; it < 2; ++it) {
    int idx = it * 256 + tid;
    int r = idx >> 4, c4 = (idx & 15) * 4;
    *(float4*)&Qs[r][c4] = *(const float4*)(
        qkv + (size_t)(b * CS + qrow0 + r) * QKVP + h * CHD + c4);
  }

  float m_i[4], l_i[4], O[4][2];
#pragma unroll
  for (int i = 0; i < 4; ++i) {
    m_i[i] = -1e30f;
    l_i[i] = 0.f;
    O[i][0] = 0.f;
    O[i][1] = 0.f;
  }

  for (int kt = 0; kt <= ktmax; ++kt) {
    __syncthreads();  // prev tile's PV reads of KVs(V)/Pt done
    // stage K (scalar, stride 65)
#pragma unroll
    for (int it = 0; it < 4; ++it) {
      int idx = it * 256 + tid;
      int r = idx >> 4, c4 = (idx & 15) * 4;
      const float* src =
          qkv + (size_t)(b * CS + kt * 64 + r) * QKVP + h * CHD;
      float4 kv = *(const float4*)(src + 1024 + c4);
      KVs[r * 65 + c4 + 0] = kv.x;
      KVs[r * 65 + c4 + 1] = kv.y;
      KVs[r * 65 + c4 + 2] = kv.z;
      KVs[r * 65 + c4 + 3] = kv.w;
    }
    __syncthreads();

    // scores: s[4 rows][2 cols]
    float s[4][2] = {};
#pragma unroll 4
    for (int d = 0; d < 64; ++d) {
      float q0 = Qs[r0 + 0][d];
      float q1 = Qs[r0 + 1][d];
      float q2 = Qs[r0 + 2][d];
      float q3 = Qs[r0 + 3][d];
      float k0 = KVs[(cg * 2 + 0) * 65 + d];
      float k1 = KVs[(cg * 2 + 1) * 65 + d];
      s[0][0] += q0 * k0; s[0][1] += q0 * k1;
      s[1][0] += q1 * k0; s[1][1] += q1 * k1;
      s[2][0] += q2 * k0; s[2][1] += q2 * k1;
      s[3][0] += q3 * k0; s[3][1] += q3 * k1;
    }

    // online softmax update (per row, reduce over 32-lane col group)
#pragma unroll
    for (int i = 0; i < 4; ++i) {
      int gr = qrow0 + r0 + i;
      int gc0 = kt * 64 + cg * 2;
      float s0 = (gc0 + 0 > gr) ? -1e30f : s[i][0] * 0.125f;
      float s1 = (gc0 + 1 > gr) ? -1e30f : s[i][1] * 0.125f;
      float tmax = fmaxf(s0, s1);
#pragma unroll
      for (int off = 16; off > 0; off >>= 1)
        tmax = fmaxf(tmax, __shfl_xor(tmax, off));
      float newm = fmaxf(m_i[i], tmax);
      float p0 = __expf(s0 - newm);
      float p1 = __expf(s1 - newm);
      float tsum = p0 + p1;
#pragma unroll
      for (int off = 16; off > 0; off >>= 1) tsum += __shfl_xor(tsum, off);
      float scale = __expf(m_i[i] - newm);
      l_i[i] = l_i[i] * scale + tsum;
      m_i[i] = newm;
      O[i][0] *= scale;
      O[i][1] *= scale;
      *(float2*)&Pt[r0 + i][cg * 2] = make_float2(p0, p1);
    }
    __syncthreads();  // all K reads + Pt writes done

    // stage V into the same buffer (float4, stride 68)
#pragma unroll
    for (int it = 0; it < 4; ++it) {
      int idx = it * 256 + tid;
      int r = idx >> 4, c4 = (idx & 15) * 4;
      *(float4*)&KVs[r * 68 + c4] = *(const float4*)(
          qkv + (size_t)(b * CS + kt * 64 + r) * QKVP + 2048 + h * CHD + c4);
    }
    __syncthreads();

    // PV: per 4-c chunk, float4 P reads; same FMA order as scalar version.
#pragma unroll 2
    for (int c4 = 0; c4 < 64; c4 += 4) {
      float4 pr[4];
#pragma unroll
      for (int i = 0; i < 4; ++i) pr[i] = *(const float4*)&Pt[r0 + i][c4];
      float pv[4][4] = {{pr[0].x, pr[0].y, pr[0].z, pr[0].w},
                        {pr[1].x, pr[1].y, pr[1].z, pr[1].w},
                        {pr[2].x, pr[2].y, pr[2].z, pr[2].w},
                        {pr[3].x, pr[3].y, pr[3].z, pr[3].w}};
#pragma unroll
      for (int j = 0; j < 4; ++j) {
        int c = c4 + j;
        float v0 = KVs[c * 68 + cg];
        float v1 = KVs[c * 68 + cg + 32];
        O[0][0] += pv[0][j] * v0; O[0][1] += pv[0][j] * v1;
        O[1][0] += pv[1][j] * v0; O[1][1] += pv[1][j] * v1;
        O[2][0] += pv[2][j] * v0; O[2][1] += pv[2][j] * v1;
        O[3][0] += pv[3][j] * v0; O[3][1] += pv[3][j] * v1;
      }
    }
  }

  // epilogue: normalize by l, write hi/lo bf16 planes
#pragma unroll
  for (int i = 0; i < 4; ++i) {
    float inv = 1.0f / l_i[i];
#pragma unroll
    for (int jd = 0; jd < 2; ++jd) {
      int dv = cg + 32 * jd;
      size_t oi = (size_t)(b * CS + qrow0 + r0 + i) * CD + h * CHD + dv;
      float v = O[i][jd] * inv;
      short hi = f2bf(v);
      ctxh[oi] = hi;
      ctxl[oi] = f2bf(v - bf2f(hi));
    }
  }
}

// ---------------------------------------------------------------------------
// Finalize+gather (1 block): counts/psum, offsets, tile map, aux loss, zrow,
// row_map init, then the gather itself via LDS cursors (order-invariant:
// row content depends only on token, so any within-expert permutation yields
// bitwise-identical output).
__global__ __launch_bounds__(256) void finalize_kernel(
    const int* __restrict__ top_i, const float* __restrict__ probs,
    int* __restrict__ tile_e, int* __restrict__ total_padded,
    int* __restrict__ row_map, int* __restrict__ row_of,
    short* __restrict__ zrow, float* __restrict__ aux_out) {
  int tid = threadIdx.x;
  __shared__ float redp[256][CE];
  __shared__ int redc[256][CE];
  __shared__ int s_off[CE + 1];
  __shared__ int s_cur[CE];
  float lp[CE] = {};
  int lc[CE] = {};
  for (int t = tid; t < CT; t += 256) {
    lc[top_i[t * 2 + 0]]++;
    lc[top_i[t * 2 + 1]]++;
#pragma unroll
    for (int e = 0; e < CE; ++e) lp[e] += probs[t * CE + e];
  }
#pragma unroll
  for (int e = 0; e < CE; ++e) { redp[tid][e] = lp[e]; redc[tid][e] = lc[e]; }
  __syncthreads();
  for (int s = 128; s > 0; s >>= 1) {
    if (tid < s) {
#pragma unroll
      for (int e = 0; e < CE; ++e) {
        redp[tid][e] += redp[tid + s][e];
        redc[tid][e] += redc[tid + s][e];
      }
    }
    __syncthreads();
  }
  if (tid == 0) {
    int o = 0;
    for (int e = 0; e < CE; ++e) {
      s_off[e] = o;
      o += ((redc[0][e] + 127) >> 7) << 7;
    }
    s_off[CE] = o;
    *total_padded = o;
    int nt = o >> 7;
    for (int i = 0; i < nt; ++i) {
      int e = 0;
      while (e < CE - 1 && i * 128 >= s_off[e + 1]) e++;
      tile_e[i] = e;
    }
    float aux = 0.f;
    for (int e = 0; e < CE; ++e)
      aux += ((float)redc[0][e] / (float)(CT * CK)) * (redp[0][e] / (float)CT);
    aux_out[0] = aux * (float)CE;
  }
  if (tid < CE) s_cur[tid] = 0;
  ((short4*)zrow)[tid] = make_short4(0, 0, 0, 0);  // 256*4 = 1024 shorts
  __syncthreads();
  for (int i = tid; i < MAXROWS; i += 256) row_map[i] = -1;
  __syncthreads();
  // gather: assign rows within expert segments (LDS cursors)
  for (int idx = tid; idx < CT * CK; idx += 256) {
    int e = top_i[idx];
    int pos = s_off[e] + atomicAdd(&s_cur[e], 1);
    row_map[pos] = idx >> 1;
    row_of[idx] = pos;
  }
}

// Fused GEMM2-reduce + combine: per token, read only its 2 routed rows'
// partials, add b2[e], weight, residual.
__global__ __launch_bounds__(256) void combine_g2_kernel(
    const float* __restrict__ part, int partM, int nz,
    const float* __restrict__ b2, const int* __restrict__ tile_e,
    const int* __restrict__ row_of, const float* __restrict__ top_p,
    const float* __restrict__ x1, float* __restrict__ out) {
  int t = blockIdx.x;
  int c = threadIdx.x * 4;
  float4 r = *(const float4*)(x1 + (size_t)t * CD + c);
#pragma unroll
  for (int s = 0; s < CK; ++s) {
    int row = row_of[t * 2 + s];
    int e = tile_e[row >> 7];
    float w = top_p[t * 2 + s];
    float4 acc = *(const float4*)(part + (size_t)row * CD + c);
    for (int z = 1; z < nz; ++z) {
      float4 p = *(const float4*)(part + ((size_t)z * partM + row) * CD + c);
      acc.x += p.x; acc.y += p.y; acc.z += p.z; acc.w += p.w;
    }
    float4 bv = *(const float4*)(b2 + (size_t)e * CD + c);
    r.x += w * (acc.x + bv.x);
    r.y += w * (acc.y + bv.y);
    r.z += w * (acc.z + bv.z);
    r.w += w * (acc.w + bv.w);
  }
  *(float4*)(out + (size_t)t * CD + c) = r;
}

// ---------------------------------------------------------------------------
extern "C" void kernel_launch(void* const* d_in, const int* in_sizes, int n_in,
                              void* d_out, int out_size, void* d_ws,
                              size_t ws_size, hipStream_t stream) {
  const float* x   = (const float*)d_in[0];
  const float* n1w = (const float*)d_in[1];
  const float* n2w = (const float*)d_in[2];
  const float* wq  = (const float*)d_in[3];
  const float* bq  = (const float*)d_in[4];
  const float* wk  = (const float*)d_in[5];
  const float* bk  = (const float*)d_in[6];
  const float* wv  = (const float*)d_in[7];
  const float* bv  = (const float*)d_in[8];
  const float* wo  = (const float*)d_in[9];
  const float* bo  = (const float*)d_in[10];
  const float* wr  = (const float*)d_in[11];
  const float* br  = (const float*)d_in[12];
  const float* w1  = (const float*)d_in[13];
  const float* b1  = (const float*)d_in[14];
  const float* w2  = (const float*)d_in[15];
  const float* b2  = (const float*)d_in[16];
  float* out = (float*)d_out;

  char* base = (char*)d_ws;
  size_t off = 0;
  auto alloc = [&](size_t bytes) -> void* {
    void* p = base + off;
    off += (bytes + 255) & ~(size_t)255;
    return p;
  };
  float* f_x1   = (float*)alloc((size_t)CT * CD * 4);
  short* f_h2b  = (short*)alloc((size_t)CT * CD * 2);   // bf16 h2 (MoE input)
  short* f_hid  = (short*)alloc((size_t)MAXROWS * CF * 2);
  short* f_hh   = (short*)alloc((size_t)CT * CD * 2);
  short* f_hl   = (short*)alloc((size_t)CT * CD * 2);
  short* f_wqkvh = (short*)alloc((size_t)QKVP * CD * 2);
  short* f_wqkvl = (short*)alloc((size_t)QKVP * CD * 2);
  float* f_qkv  = (float*)alloc((size_t)CT * QKVP * 4);
  short* f_ctxh = (short*)alloc((size_t)CT * CD * 2);
  short* f_ctxl = (short*)alloc((size_t)CT * CD * 2);
  short* f_woth = (short*)alloc((size_t)CD * CD * 2);
  short* f_wotl = (short*)alloc((size_t)CD * CD * 2);
  float* f_bqkv = (float*)alloc(QKVP * 4);
  float* f_topp = (float*)alloc(CT * CK * 4);
  float* f_probs = (float*)alloc(CT * CE * 4);
  short* f_zrow = (short*)alloc(CD * 2);
  int* i_topi   = (int*)alloc(CT * CK * 4);
  int* i_rowof  = (int*)alloc(CT * CK * 4);
  int* i_rowmap = (int*)alloc(MAXROWS * 4);
  int* i_tile   = (int*)alloc(MAXTILES * 4);
  int* i_total  = (int*)alloc(4);
  // G (64MB): w1t -> w2t (sequential reuse)
  short* f_wG = (short*)alloc((size_t)CE * CD * CF * 2);
  short* f_w1t = f_wG;
  short* f_w2t = f_wG;
  // Rs (48MB): WO partials -> GEMM2 partials (disjoint)
  void* Rs = alloc((size_t)4 * MAXROWS * CD * 4);
  float* f_partwo = (float*)Rs;
  float* f_partg2 = (float*)Rs;

  dim3 b256(256);

  TPtrs tp;
  tp.w[0] = wq; tp.w[1] = wk; tp.w[2] = wv; tp.w[3] = wo;
  tp.hh[0] = f_wqkvh + 0 * (size_t)CD * CD;
  tp.hh[1] = f_wqkvh + 1 * (size_t)CD * CD;
  tp.hh[2] = f_wqkvh + 2 * (size_t)CD * CD;
  tp.hh[3] = f_woth;
  tp.ll[0] = f_wqkvl + 0 * (size_t)CD * CD;
  tp.ll[1] = f_wqkvl + 1 * (size_t)CD * CD;
  tp.ll[2] = f_wqkvl + 2 * (size_t)CD * CD;
  tp.ll[3] = f_wotl;
  tp.bq = bq; tp.bk = bk; tp.bv = bv; tp.bqkv = f_bqkv;
  tp.xin = x; tp.n1w = n1w; tp.hH = f_hh; tp.hL = f_hl;
  // z: 0-3 = wq/wk/wv/wo transposes, 4 = bias pack, 5 = rmsnorm1
  transpose4_kernel<<<dim3(16, 16, 6), b256, 0, stream>>>(tp);
  transpose_convert_kernel<<<dim3(CF / 64, CD / 64, CE), b256, 0, stream>>>(
      w1, f_w1t, nullptr, CD, CF);

  // ---- attention ----
  // QKV: BN=64 -> 384 blocks; bias fused, direct fp32 out
  mfma_gemm_kernel<1><<<dim3(QKVP / 64, CT / 128, 1), b256, 0, stream>>>(
      f_hh, f_hl, f_wqkvh, f_wqkvl, f_bqkv, f_qkv, nullptr, CT, QKVP, CD);
  fused_attn_kernel<<<dim3(512), b256, 0, stream>>>(f_qkv, f_ctxh, f_ctxl);
  // WO: BN=64, split-K=4 -> 512 blocks
  mfma_gemm_kernel<1><<<dim3(CD / 64, CT / 128, 4), b256, 0, stream>>>(
      f_ctxh, f_ctxl, f_woth, f_wotl, nullptr, nullptr, f_partwo, CT, CD, CD);
  attn_epilogue_kernel<<<CT, b256, 0, stream>>>(f_partwo, bo, x, n2w, wr, br,
                                                f_x1, f_h2b, i_topi, f_topp,
                                                f_probs);

  // ---- MoE ----
  finalize_kernel<<<1, 256, 0, stream>>>(i_topi, f_probs, i_tile, i_total,
                                         i_rowmap, i_rowof, f_zrow,
                                         out + (size_t)CT * CD);

  // expert GEMM1: A gathered via row_map from bf16 h2 (no Xg materialization)
  moe_gemm_kernel<1, 1><<<dim3(CF / 128, MAXTILES, 1), dim3(512), 0, stream>>>(
      f_h2b, i_rowmap, f_zrow, f_w1t, b1, f_hid, nullptr, 0, CF, CD, i_tile,
      i_total);
  transpose_convert_kernel<<<dim3(CD / 64, CF / 64, CE), b256, 0, stream>>>(
      w2, f_w2t, nullptr, CF, CD);
  // expert GEMM2: BN=128, split-K=4
  moe_gemm_kernel<0, 0><<<dim3(CD / 128, MAXTILES, 4), dim3(512), 0, stream>>>(
      f_hid, nullptr, nullptr, f_w2t, nullptr, nullptr, f_partg2, MAXROWS, CD,
      CF, i_tile, i_total);
  combine_g2_kernel<<<CT, b256, 0, stream>>>(f_partg2, MAXROWS, 4, b2, i_tile,
                                             i_rowof, f_topp, f_x1, out);
}

// Round 21
// 287.273 us; speedup vs baseline: 1.2836x; 1.0095x over previous
//
#include <hip/hip_runtime.h>
#include <math.h>

// Problem constants
#define CB 2
#define CS 512
#define CD 1024
#define CH 16
#define CHD 64
#define CF 4096
#define CE 8
#define CK 2
#define CT (CB*CS)      // 1024 tokens
#define CBH (CB*CH)     // 32 (batch*heads)
#define CEPS 1e-6f
#define QKVP 3072       // packed q|k|v row pitch
#define MAXROWS 3072    // 2048 + 8*127 padded to 128
#define MAXTILES (MAXROWS/128)

typedef __attribute__((ext_vector_type(8))) short bf16x8;
typedef __attribute__((ext_vector_type(4))) float f32x4;

__device__ __forceinline__ short f2bf(float f) {
  unsigned u = __float_as_uint(f);
  unsigned r = (u + 0x7FFF + ((u >> 16) & 1)) >> 16;
  return (short)r;
}
__device__ __forceinline__ float bf2f(short h) {
  return __uint_as_float(((unsigned)(unsigned short)h) << 16);
}

__device__ __forceinline__ void gload_lds16(const void* g, void* l) {
  __builtin_amdgcn_global_load_lds(
      (const __attribute__((address_space(1))) unsigned int*)g,
      (__attribute__((address_space(3))) unsigned int*)l, 16, 0, 0);
}

// ---------------------------------------------------------------------------
// Tiled transpose+convert, 64x64 tile, 16B short8 stores:
// W[e][Kd][Nd] f32 -> Wth[e][Nd][Kd] bf16 (+ optional lo plane).
__global__ __launch_bounds__(256) void transpose_convert_kernel(
    const float* __restrict__ W, short* __restrict__ Wth,
    short* __restrict__ Wtl, int Kd, int Nd) {
  int e = blockIdx.z;
  const float* Wb = W + (size_t)e * Kd * Nd;
  size_t obase = (size_t)e * Kd * Nd;
  int n0 = blockIdx.x * 64, k0 = blockIdx.y * 64;
  __shared__ float t[64][65];
  int tid = threadIdx.x;
#pragma unroll
  for (int i = 0; i < 4; ++i) {
    int idx = i * 256 + tid;
    int r = idx >> 4, c4 = (idx & 15) * 4;
    float4 v = *(const float4*)(Wb + (size_t)(k0 + r) * Nd + n0 + c4);
    t[r][c4] = v.x; t[r][c4 + 1] = v.y; t[r][c4 + 2] = v.z; t[r][c4 + 3] = v.w;
  }
  __syncthreads();
  int n = tid >> 2, k16 = (tid & 3) * 16;
  short th[16], tl[16];
#pragma unroll
  for (int j = 0; j < 16; ++j) {
    float v = t[k16 + j][n];
    short hi = f2bf(v);
    th[j] = hi;
    tl[j] = f2bf(v - bf2f(hi));
  }
  size_t oo = obase + (size_t)(n0 + n) * Kd + k0 + k16;
  ((int4*)(Wth + oo))[0] = ((int4*)th)[0];
  ((int4*)(Wth + oo + 8))[0] = ((int4*)th)[1];
  if (Wtl) {
    ((int4*)(Wtl + oo))[0] = ((int4*)tl)[0];
    ((int4*)(Wtl + oo + 8))[0] = ((int4*)tl)[1];
  }
}

// Four DxD transposes (wq,wk,wv,wo), bias packing (z==4), rmsnorm1 (z==5).
struct TPtrs {
  const float* w[4];
  short* hh[4];
  short* ll[4];
  const float* bq;
  const float* bk;
  const float* bv;
  float* bqkv;
  const float* xin;
  const float* n1w;
  short* hH;
  short* hL;
};
__global__ __launch_bounds__(256) void transpose4_kernel(TPtrs p) {
  int z = blockIdx.z;
  int tid = threadIdx.x;
  if (z == 4) {
    // bias packing: 12 blocks x 256 threads cover QKVP=3072
    if (blockIdx.y == 0 && blockIdx.x < 12) {
      int i = blockIdx.x * 256 + tid;
      if (i < QKVP)
        p.bqkv[i] =
            (i < 1024) ? p.bq[i] : (i < 2048 ? p.bk[i - 1024] : p.bv[i - 2048]);
    }
    return;
  }
  if (z == 5) {
    // rmsnorm1 hi/lo: 256 blocks x 4 tokens each
    __shared__ float red[4];
    __shared__ float s_scale;
    int bid = blockIdx.y * 16 + blockIdx.x;
    int lane = tid & 63, wid = tid >> 6;
    for (int tt = 0; tt < 4; ++tt) {
      int t = bid * 4 + tt;
      float4 xv = ((const float4*)(p.xin + (size_t)t * CD))[tid];
      float ss = xv.x*xv.x + xv.y*xv.y + xv.z*xv.z + xv.w*xv.w;
      for (int off = 32; off > 0; off >>= 1) ss += __shfl_down(ss, off);
      if (lane == 0) red[wid] = ss;
      __syncthreads();
      if (tid == 0) {
        float tot = red[0] + red[1] + red[2] + red[3];
        s_scale = rsqrtf(tot / (float)CD + CEPS);
      }
      __syncthreads();
      float sc = s_scale;
      float4 wv = ((const float4*)p.n1w)[tid];
      float o[4] = {xv.x * sc * wv.x, xv.y * sc * wv.y,
                    xv.z * sc * wv.z, xv.w * sc * wv.w};
      short4 hi, lo;
      short* hp = (short*)&hi; short* lp = (short*)&lo;
#pragma unroll
      for (int i = 0; i < 4; ++i) {
        short h = f2bf(o[i]);
        hp[i] = h;
        lp[i] = f2bf(o[i] - bf2f(h));
      }
      ((short4*)(p.hH + (size_t)t * CD))[tid] = hi;
      ((short4*)(p.hL + (size_t)t * CD))[tid] = lo;
      __syncthreads();
    }
    return;
  }
  const float* Wb = p.w[z];
  short* Wth = p.hh[z];
  short* Wtl = p.ll[z];
  int n0 = blockIdx.x * 64, k0 = blockIdx.y * 64;
  __shared__ float t[64][65];
#pragma unroll
  for (int i = 0; i < 4; ++i) {
    int idx = i * 256 + tid;
    int r = idx >> 4, c4 = (idx & 15) * 4;
    float4 v = *(const float4*)(Wb + (size_t)(k0 + r) * CD + n0 + c4);
    t[r][c4] = v.x; t[r][c4 + 1] = v.y; t[r][c4 + 2] = v.z; t[r][c4 + 3] = v.w;
  }
  __syncthreads();
  int n = tid >> 2, k16 = (tid & 3) * 16;
  short th[16], tl[16];
#pragma unroll
  for (int j = 0; j < 16; ++j) {
    float v = t[k16 + j][n];
    short hi = f2bf(v);
    th[j] = hi;
    tl[j] = f2bf(v - bf2f(hi));
  }
  size_t oo = (size_t)(n0 + n) * CD + k0 + k16;
  ((int4*)(Wth + oo))[0] = ((int4*)th)[0];
  ((int4*)(Wth + oo + 8))[0] = ((int4*)th)[1];
  ((int4*)(Wtl + oo))[0] = ((int4*)tl)[0];
  ((int4*)(Wtl + oo + 8))[0] = ((int4*)tl)[1];
}

// ---------------------------------------------------------------------------
// MoE grouped GEMM: BM=128, BN templated (64 or 128), BK=64, 8 waves (2x4;
// wave out 64 x 16*NF, NF=BN/64). BN=64: LDS 48KB -> 3 blocks/CU (24 waves).
// A source optionally row_map-indirect. Numerics bit-identical to BN=128
// (same per-element K-chain and MFMA order; only block->column map changes).
template <int SILU, int OUTBF, int BN>
__global__ __launch_bounds__(512) void moe_gemm_kernel(
    const short* __restrict__ A, const int* __restrict__ row_map,
    const short* __restrict__ zrow, const short* __restrict__ Bt,
    const float* __restrict__ bias, void* __restrict__ Cout,
    float* __restrict__ part, int partM, int N, int K,
    const int* __restrict__ tile_e, const int* __restrict__ total_rows) {
  constexpr int NF = BN / 64;  // n-frags per wave
  __shared__ __align__(16) short A0[128 * 64], A1[128 * 64];
  __shared__ __align__(16) short B0[BN * 64], B1[BN * 64];
  int tid = threadIdx.x;
  int m0 = blockIdx.y * 128, n0 = blockIdx.x * BN;
  if (m0 >= *total_rows) return;
  int e = tile_e[blockIdx.y];
  const short* Bb = Bt + (size_t)e * N * K;
  const float* biasb = bias ? bias + (size_t)e * N : nullptr;
  int kz = blockIdx.z;
  int kchunk = K / gridDim.z;
  int kbeg = kz * kchunk;
  int nsteps = kchunk >> 6;
  int lane = tid & 63, w = tid >> 6;
  int wr = w >> 2, wc = w & 3;
  int l15 = lane & 15, l4 = lane >> 4;
  f32x4 acc[4][NF] = {};

  const short* aB[2];
#pragma unroll
  for (int i = 0; i < 2; ++i) {
    int r = (i * 512 + tid) >> 3;
    int grow = m0 + r;
    if (row_map) {
      int tok = row_map[grow];
      aB[i] = (tok < 0) ? zrow : A + (size_t)tok * K;
    } else {
      aB[i] = A + (size_t)grow * K;
    }
  }

#define STAGE(AS_, BS_, KK)                                                   \
  {                                                                           \
    _Pragma("unroll") for (int i = 0; i < 2; ++i) {                           \
      int c = i * 512 + tid;                                                  \
      int r = c >> 3, gs = c & 7;                                             \
      int g = gs ^ (r & 7);                                                   \
      gload_lds16(aB[i] + (KK) + g * 8, &AS_[c * 8]);                         \
    }                                                                         \
    _Pragma("unroll") for (int i = 0; i < NF; ++i) {                          \
      int c = i * 512 + tid;                                                  \
      int r = c >> 3, gs = c & 7;                                             \
      int g = gs ^ (r & 7);                                                   \
      gload_lds16(Bb + (size_t)(n0 + r) * K + (KK) + g * 8, &BS_[c * 8]);     \
    }                                                                         \
  }

#define COMPUTE(AS_, BS_)                                                     \
  {                                                                           \
    _Pragma("unroll") for (int ks = 0; ks < 2; ++ks) {                        \
      bf16x8 a[4], b[NF];                                                     \
      _Pragma("unroll") for (int m = 0; m < 4; ++m) {                         \
        int row = wr * 64 + m * 16 + l15;                                     \
        int slot = (ks * 4 + l4) ^ (row & 7);                                 \
        a[m] = *(const bf16x8*)&AS_[(row * 8 + slot) * 8];                    \
      }                                                                       \
      _Pragma("unroll") for (int n = 0; n < NF; ++n) {                        \
        int row = wc * 16 * NF + n * 16 + l15;                                \
        int slot = (ks * 4 + l4) ^ (row & 7);                                 \
        b[n] = *(const bf16x8*)&BS_[(row * 8 + slot) * 8];                    \
      }                                                                       \
      _Pragma("unroll") for (int m = 0; m < 4; ++m)                           \
      _Pragma("unroll") for (int n = 0; n < NF; ++n)                          \
        acc[m][n] = __builtin_amdgcn_mfma_f32_16x16x32_bf16(a[m], b[n],       \
                                                            acc[m][n], 0, 0, 0); \
    }                                                                         \
  }

  STAGE(A0, B0, kbeg);
  __syncthreads();
  for (int s = 0; s < nsteps; s += 2) {
    int k0 = kbeg + (s << 6);
    bool has1 = (s + 1 < nsteps), has2 = (s + 2 < nsteps);
    if (has1) STAGE(A1, B1, k0 + 64);
    COMPUTE(A0, B0);
    __syncthreads();
    if (has1) {
      if (has2) STAGE(A0, B0, k0 + 128);
      COMPUTE(A1, B1);
      __syncthreads();
    }
  }
#undef STAGE
#undef COMPUTE

  if (gridDim.z > 1) {
#pragma unroll
    for (int m = 0; m < 4; ++m) {
      int row = m0 + wr * 64 + m * 16 + l4 * 4;
#pragma unroll
      for (int n = 0; n < NF; ++n) {
        int col = n0 + wc * 16 * NF + n * 16 + l15;
#pragma unroll
        for (int q = 0; q < 4; ++q)
          part[((size_t)kz * partM + row + q) * N + col] = acc[m][n][q];
      }
    }
    return;
  }
  float* outf = (float*)Cout;
  short* outb = (short*)Cout;
#pragma unroll
  for (int m = 0; m < 4; ++m) {
    int row = m0 + wr * 64 + m * 16 + l4 * 4;
#pragma unroll
    for (int n = 0; n < NF; ++n) {
      int col = n0 + wc * 16 * NF + n * 16 + l15;
      float bv = biasb[col];
#pragma unroll
      for (int q = 0; q < 4; ++q) {
        float v = acc[m][n][q] + bv;
        if (SILU) v = v / (1.f + __expf(-v));
        if (OUTBF) outb[(size_t)(row + q) * N + col] = f2bf(v);
        else outf[(size_t)(row + q) * N + col] = v;
      }
    }
  }
}

// ---------------------------------------------------------------------------
// Attention MFMA GEMM v2: BM=128, BN=64, BK=32, 4 waves (4x1; wave out
// 32x64, acc[2][4]), hi/lo reg-staged. LDS 48KB -> 3 blocks/CU.
// gridDim.z>1: split-K partials. gridDim.z==1: direct fp32 out + bias.
template <int LO>
__global__ __launch_bounds__(256) void mfma_gemm_kernel(
    const short* __restrict__ Ah, const short* __restrict__ Al,
    const short* __restrict__ Bh, const short* __restrict__ Bl,
    const float* __restrict__ bias, float* __restrict__ dout,
    float* __restrict__ part, int partM, int N, int K) {
  __shared__ short As0[4096], Bs0[2048], As1[4096], Bs1[2048];
  __shared__ short Als0[LO ? 4096 : 64], Bls0[LO ? 2048 : 64];
  __shared__ short Als1[LO ? 4096 : 64], Bls1[LO ? 2048 : 64];
  int tid = threadIdx.x;
  int m0 = blockIdx.y * 128, n0 = blockIdx.x * 64;
  int kz = blockIdx.z;
  int kchunk = K / gridDim.z;
  int kbeg = kz * kchunk;
  int nsteps = kchunk >> 5;
  int lane = tid & 63, w = tid >> 6;
  int wr = w;  // 4x1 wave grid: wave out rows wr*32..+31, cols 0..63
  int l15 = lane & 15, l4 = lane >> 4;
  int xorl = (l15 & 3) ^ ((l15 >> 2) & 3);
  f32x4 acc[2][4] = {};
  bf16x8 vA0[2], vAl0[2], vA1[2], vAl1[2];
  bf16x8 vB0, vBl0, vB1, vBl1;

#define LOAD_SET(VA, VB, VAL, VBL, KK)                                        \
  {                                                                           \
    _Pragma("unroll") for (int ic = 0; ic < 2; ++ic) {                        \
      int c = ic * 256 + tid;                                                 \
      int r = c >> 2, g = c & 3;                                              \
      size_t ao = (size_t)(m0 + r) * K + (KK) + g * 8;                        \
      VA[ic] = *(const bf16x8*)(Ah + ao);                                     \
      if (LO) VAL[ic] = *(const bf16x8*)(Al + ao);                            \
    }                                                                         \
    {                                                                         \
      int r = tid >> 2, g = tid & 3;                                          \
      size_t bo = (size_t)(n0 + r) * K + (KK) + g * 8;                        \
      VB = *(const bf16x8*)(Bh + bo);                                         \
      if (LO) VBL = *(const bf16x8*)(Bl + bo);                                \
    }                                                                         \
  }

#define WRITE_SET(AS_, BS_, ALS_, BLS_, VA, VB, VAL, VBL)                     \
  {                                                                           \
    _Pragma("unroll") for (int ic = 0; ic < 2; ++ic) {                        \
      int c = ic * 256 + tid;                                                 \
      int r = c >> 2, g = c & 3;                                              \
      int ch = (r * 4 + (g ^ (r & 3) ^ ((r >> 2) & 3))) * 8;                  \
      *(bf16x8*)&AS_[ch] = VA[ic];                                            \
      if (LO) *(bf16x8*)&ALS_[ch] = VAL[ic];                                  \
    }                                                                         \
    {                                                                         \
      int r = tid >> 2, g = tid & 3;                                          \
      int ch = (r * 4 + (g ^ (r & 3) ^ ((r >> 2) & 3))) * 8;                  \
      *(bf16x8*)&BS_[ch] = VB;                                                \
      if (LO) *(bf16x8*)&BLS_[ch] = VBL;                                      \
    }                                                                         \
  }

#define COMPUTE_SET(AS_, BS_, ALS_, BLS_)                                     \
  {                                                                           \
    bf16x8 ah[2], al[2];                                                      \
    _Pragma("unroll") for (int m = 0; m < 2; ++m) {                           \
      int row = wr * 32 + m * 16 + l15;                                       \
      int idx = (row * 4 + (l4 ^ xorl)) * 8;                                  \
      ah[m] = *(const bf16x8*)&AS_[idx];                                      \
      if (LO) al[m] = *(const bf16x8*)&ALS_[idx];                             \
    }                                                                         \
    _Pragma("unroll") for (int n = 0; n < 4; ++n) {                           \
      int row = n * 16 + l15;                                                 \
      int idx = (row * 4 + (l4 ^ xorl)) * 8;                                  \
      bf16x8 bhn = *(const bf16x8*)&BS_[idx];                                 \
      bf16x8 bln;                                                             \
      if (LO) bln = *(const bf16x8*)&BLS_[idx];                               \
      _Pragma("unroll") for (int m = 0; m < 2; ++m) {                         \
        acc[m][n] = __builtin_amdgcn_mfma_f32_16x16x32_bf16(ah[m], bhn,       \
                                                            acc[m][n], 0, 0, 0); \
        if (LO) {                                                             \
          acc[m][n] = __builtin_amdgcn_mfma_f32_16x16x32_bf16(al[m], bhn,     \
                                                              acc[m][n], 0, 0, 0); \
          acc[m][n] = __builtin_amdgcn_mfma_f32_16x16x32_bf16(ah[m], bln,     \
                                                              acc[m][n], 0, 0, 0); \
        }                                                                     \
      }                                                                       \
    }                                                                         \
  }

  LOAD_SET(vA0, vB0, vAl0, vBl0, kbeg);
  WRITE_SET(As0, Bs0, Als0, Bls0, vA0, vB0, vAl0, vBl0);
  __syncthreads();
  for (int s = 0; s < nsteps; s += 2) {
    int k0 = kbeg + (s << 5);
    bool has1 = (s + 1 < nsteps), has2 = (s + 2 < nsteps);
    if (has1) LOAD_SET(vA1, vB1, vAl1, vBl1, k0 + 32);
    COMPUTE_SET(As0, Bs0, Als0, Bls0);
    if (has1) WRITE_SET(As1, Bs1, Als1, Bls1, vA1, vB1, vAl1, vBl1);
    __syncthreads();
    if (has1) {
      if (has2) LOAD_SET(vA0, vB0, vAl0, vBl0, k0 + 64);
      COMPUTE_SET(As1, Bs1, Als1, Bls1);
      if (has2) WRITE_SET(As0, Bs0, Als0, Bls0, vA0, vB0, vAl0, vBl0);
      __syncthreads();
    }
  }
#undef LOAD_SET
#undef WRITE_SET
#undef COMPUTE_SET

  if (gridDim.z > 1) {
#pragma unroll
    for (int m = 0; m < 2; ++m) {
      int row = m0 + wr * 32 + m * 16 + l4 * 4;
#pragma unroll
      for (int n = 0; n < 4; ++n) {
        int col = n0 + n * 16 + l15;
#pragma unroll
        for (int q = 0; q < 4; ++q)
          part[((size_t)kz * partM + row + q) * N + col] = acc[m][n][q];
      }
    }
    return;
  }
  // direct out: acc + bias (fp32)
#pragma unroll
  for (int m = 0; m < 2; ++m) {
    int row = m0 + wr * 32 + m * 16 + l4 * 4;
#pragma unroll
    for (int n = 0; n < 4; ++n) {
      int col = n0 + n * 16 + l15;
      float bv = bias[col];
#pragma unroll
      for (int q = 0; q < 4; ++q)
        dout[(size_t)(row + q) * N + col] = acc[m][n][q] + bv;
    }
  }
}

// ---------------------------------------------------------------------------
// Attention epilogue (fused): WO split-K reduce + residual + rmsnorm2 +
// router. h2 written directly as bf16 (feeds MoE GEMM1's gathered A).
__global__ __launch_bounds__(256) void attn_epilogue_kernel(
    const float* __restrict__ part, const float* __restrict__ bo,
    const float* __restrict__ x, const float* __restrict__ n2w,
    const float* __restrict__ wr, const float* __restrict__ br,
    float* __restrict__ x1, short* __restrict__ h2b, int* __restrict__ top_i,
    float* __restrict__ top_p, float* __restrict__ probs_out) {
  int t = blockIdx.x;
  int tid = threadIdx.x;
  int c = tid * 4;
  float4 s = *(const float4*)(part + (size_t)t * CD + c);
#pragma unroll
  for (int z = 1; z < 4; ++z) {
    float4 p = *(const float4*)(part + ((size_t)z * CT + t) * CD + c);
    s.x += p.x; s.y += p.y; s.z += p.z; s.w += p.w;
  }
  float4 bv = *(const float4*)(bo + c);
  float4 xv = *(const float4*)(x + (size_t)t * CD + c);
  s.x += bv.x + xv.x; s.y += bv.y + xv.y;
  s.z += bv.z + xv.z; s.w += bv.w + xv.w;
  *(float4*)(x1 + (size_t)t * CD + c) = s;
  float ss = s.x*s.x + s.y*s.y + s.z*s.z + s.w*s.w;
  for (int off = 32; off > 0; off >>= 1) ss += __shfl_down(ss, off);
  __shared__ float red[4];
  __shared__ float s_scale;
  int lane = tid & 63, wid = tid >> 6;
  if (lane == 0) red[wid] = ss;
  __syncthreads();
  if (tid == 0) {
    float tot = red[0] + red[1] + red[2] + red[3];
    s_scale = rsqrtf(tot / (float)CD + CEPS);
  }
  __syncthreads();
  float sc = s_scale;
  float4 wv = *(const float4*)(n2w + c);
  float hv[4] = {s.x * sc * wv.x, s.y * sc * wv.y,
                 s.z * sc * wv.z, s.w * sc * wv.w};
  short4 hb = make_short4(f2bf(hv[0]), f2bf(hv[1]), f2bf(hv[2]), f2bf(hv[3]));
  ((short4*)(h2b + (size_t)t * CD))[tid] = hb;
  float a[CE] = {};
#pragma unroll
  for (int j = 0; j < 4; ++j) {
    const float* wrow = wr + (size_t)(c + j) * CE;
#pragma unroll
    for (int e = 0; e < CE; ++e) a[e] += hv[j] * wrow[e];
  }
  __shared__ float red8[256][CE];
#pragma unroll
  for (int e = 0; e < CE; ++e) red8[tid][e] = a[e];
  __syncthreads();
  for (int st = 128; st > 0; st >>= 1) {
    if (tid < st) {
#pragma unroll
      for (int e = 0; e < CE; ++e) red8[tid][e] += red8[tid + st][e];
    }
    __syncthreads();
  }
  if (tid == 0) {
    float probs[CE];
    float mx = -1e30f;
#pragma unroll
    for (int e = 0; e < CE; ++e) {
      probs[e] = red8[0][e] + br[e];
      mx = fmaxf(mx, probs[e]);
    }
    float sum = 0.f;
#pragma unroll
    for (int e = 0; e < CE; ++e) { probs[e] = __expf(probs[e] - mx); sum += probs[e]; }
    float inv = 1.0f / sum;
#pragma unroll
    for (int e = 0; e < CE; ++e) {
      probs[e] *= inv;
      probs_out[t * CE + e] = probs[e];
    }
    int i1 = 0;
#pragma unroll
    for (int e = 1; e < CE; ++e) if (probs[e] > probs[i1]) i1 = e;
    int i2 = (i1 == 0) ? 1 : 0;
#pragma unroll
    for (int e = 0; e < CE; ++e)
      if (e != i1 && probs[e] > probs[i2]) i2 = e;
    float p1 = probs[i1], p2 = probs[i2];
    float s12 = p1 + p2;
    top_i[t * 2 + 0] = i1;
    top_i[t * 2 + 1] = i2;
    top_p[t * 2 + 0] = p1 / s12;
    top_p[t * 2 + 1] = p2 / s12;
  }
}

// ---------------------------------------------------------------------------
// Fused attention v5c (unchanged): flash online softmax, K/V LDS time-share,
// complementary causal-load swizzle over 1-D grid 512.
__global__ __launch_bounds__(256) void fused_attn_kernel(
    const float* __restrict__ qkv, short* __restrict__ ctxh,
    short* __restrict__ ctxl) {
  __shared__ float Qs[32][68];    // Q tile
  __shared__ float KVs[64 * 68];  // K (stride 65) then V (stride 68)
  __shared__ float Pt[32][68];    // per-tile P (stride 68 for float4 reads)
  int id = blockIdx.x;
  int half = id >> 8;             // 0 or 1
  int qt0 = id & 15;
  int qt = half ? (15 - qt0) : qt0;
  int bh = ((id >> 4) & 15) + half * 16;
  int b = bh / CH, h = bh % CH;
  int qrow0 = qt * 32;
  int ktmax = (qrow0 + 31) >> 6;
  int tid = threadIdx.x;
  int cg = tid & 31, rg = tid >> 5;
  int r0 = rg * 4;

  // stage Q [32][64]
#pragma unroll
  for (int it = 0; it < 2; ++it) {
    int idx = it * 256 + tid;
    int r = idx >> 4, c4 = (idx & 15) * 4;
    *(float4*)&Qs[r][c4] = *(const float4*)(
        qkv + (size_t)(b * CS + qrow0 + r) * QKVP + h * CHD + c4);
  }

  float m_i[4], l_i[4], O[4][2];
#pragma unroll
  for (int i = 0; i < 4; ++i) {
    m_i[i] = -1e30f;
    l_i[i] = 0.f;
    O[i][0] = 0.f;
    O[i][1] = 0.f;
  }

  for (int kt = 0; kt <= ktmax; ++kt) {
    __syncthreads();  // prev tile's PV reads of KVs(V)/Pt done
    // stage K (scalar, stride 65)
#pragma unroll
    for (int it = 0; it < 4; ++it) {
      int idx = it * 256 + tid;
      int r = idx >> 4, c4 = (idx & 15) * 4;
      const float* src =
          qkv + (size_t)(b * CS + kt * 64 + r) * QKVP + h * CHD;
      float4 kv = *(const float4*)(src + 1024 + c4);
      KVs[r * 65 + c4 + 0] = kv.x;
      KVs[r * 65 + c4 + 1] = kv.y;
      KVs[r * 65 + c4 + 2] = kv.z;
      KVs[r * 65 + c4 + 3] = kv.w;
    }
    __syncthreads();

    // scores: s[4 rows][2 cols]
    float s[4][2] = {};
#pragma unroll 4
    for (int d = 0; d < 64; ++d) {
      float q0 = Qs[r0 + 0][d];
      float q1 = Qs[r0 + 1][d];
      float q2 = Qs[r0 + 2][d];
      float q3 = Qs[r0 + 3][d];
      float k0 = KVs[(cg * 2 + 0) * 65 + d];
      float k1 = KVs[(cg * 2 + 1) * 65 + d];
      s[0][0] += q0 * k0; s[0][1] += q0 * k1;
      s[1][0] += q1 * k0; s[1][1] += q1 * k1;
      s[2][0] += q2 * k0; s[2][1] += q2 * k1;
      s[3][0] += q3 * k0; s[3][1] += q3 * k1;
    }

    // online softmax update (per row, reduce over 32-lane col group)
#pragma unroll
    for (int i = 0; i < 4; ++i) {
      int gr = qrow0 + r0 + i;
      int gc0 = kt * 64 + cg * 2;
      float s0 = (gc0 + 0 > gr) ? -1e30f : s[i][0] * 0.125f;
      float s1 = (gc0 + 1 > gr) ? -1e30f : s[i][1] * 0.125f;
      float tmax = fmaxf(s0, s1);
#pragma unroll
      for (int off = 16; off > 0; off >>= 1)
        tmax = fmaxf(tmax, __shfl_xor(tmax, off));
      float newm = fmaxf(m_i[i], tmax);
      float p0 = __expf(s0 - newm);
      float p1 = __expf(s1 - newm);
      float tsum = p0 + p1;
#pragma unroll
      for (int off = 16; off > 0; off >>= 1) tsum += __shfl_xor(tsum, off);
      float scale = __expf(m_i[i] - newm);
      l_i[i] = l_i[i] * scale + tsum;
      m_i[i] = newm;
      O[i][0] *= scale;
      O[i][1] *= scale;
      *(float2*)&Pt[r0 + i][cg * 2] = make_float2(p0, p1);
    }
    __syncthreads();  // all K reads + Pt writes done

    // stage V into the same buffer (float4, stride 68)
#pragma unroll
    for (int it = 0; it < 4; ++it) {
      int idx = it * 256 + tid;
      int r = idx >> 4, c4 = (idx & 15) * 4;
      *(float4*)&KVs[r * 68 + c4] = *(const float4*)(
          qkv + (size_t)(b * CS + kt * 64 + r) * QKVP + 2048 + h * CHD + c4);
    }
    __syncthreads();

    // PV: per 4-c chunk, float4 P reads; same FMA order as scalar version.
#pragma unroll 2
    for (int c4 = 0; c4 < 64; c4 += 4) {
      float4 pr[4];
#pragma unroll
      for (int i = 0; i < 4; ++i) pr[i] = *(const float4*)&Pt[r0 + i][c4];
      float pv[4][4] = {{pr[0].x, pr[0].y, pr[0].z, pr[0].w},
                        {pr[1].x, pr[1].y, pr[1].z, pr[1].w},
                        {pr[2].x, pr[2].y, pr[2].z, pr[2].w},
                        {pr[3].x, pr[3].y, pr[3].z, pr[3].w}};
#pragma unroll
      for (int j = 0; j < 4; ++j) {
        int c = c4 + j;
        float v0 = KVs[c * 68 + cg];
        float v1 = KVs[c * 68 + cg + 32];
        O[0][0] += pv[0][j] * v0; O[0][1] += pv[0][j] * v1;
        O[1][0] += pv[1][j] * v0; O[1][1] += pv[1][j] * v1;
        O[2][0] += pv[2][j] * v0; O[2][1] += pv[2][j] * v1;
        O[3][0] += pv[3][j] * v0; O[3][1] += pv[3][j] * v1;
      }
    }
  }

  // epilogue: normalize by l, write hi/lo bf16 planes
#pragma unroll
  for (int i = 0; i < 4; ++i) {
    float inv = 1.0f / l_i[i];
#pragma unroll
    for (int jd = 0; jd < 2; ++jd) {
      int dv = cg + 32 * jd;
      size_t oi = (size_t)(b * CS + qrow0 + r0 + i) * CD + h * CHD + dv;
      float v = O[i][jd] * inv;
      short hi = f2bf(v);
      ctxh[oi] = hi;
      ctxl[oi] = f2bf(v - bf2f(hi));
    }
  }
}

// ---------------------------------------------------------------------------
// Finalize+gather (1 block): counts/psum, offsets, tile map, aux loss, zrow,
// row_map init, then the gather itself via LDS cursors (order-invariant:
// row content depends only on token, so any within-expert permutation yields
// bitwise-identical output).
__global__ __launch_bounds__(256) void finalize_kernel(
    const int* __restrict__ top_i, const float* __restrict__ probs,
    int* __restrict__ tile_e, int* __restrict__ total_padded,
    int* __restrict__ row_map, int* __restrict__ row_of,
    short* __restrict__ zrow, float* __restrict__ aux_out) {
  int tid = threadIdx.x;
  __shared__ float redp[256][CE];
  __shared__ int redc[256][CE];
  __shared__ int s_off[CE + 1];
  __shared__ int s_cur[CE];
  float lp[CE] = {};
  int lc[CE] = {};
  for (int t = tid; t < CT; t += 256) {
    lc[top_i[t * 2 + 0]]++;
    lc[top_i[t * 2 + 1]]++;
#pragma unroll
    for (int e = 0; e < CE; ++e) lp[e] += probs[t * CE + e];
  }
#pragma unroll
  for (int e = 0; e < CE; ++e) { redp[tid][e] = lp[e]; redc[tid][e] = lc[e]; }
  __syncthreads();
  for (int s = 128; s > 0; s >>= 1) {
    if (tid < s) {
#pragma unroll
      for (int e = 0; e < CE; ++e) {
        redp[tid][e] += redp[tid + s][e];
        redc[tid][e] += redc[tid + s][e];
      }
    }
    __syncthreads();
  }
  if (tid == 0) {
    int o = 0;
    for (int e = 0; e < CE; ++e) {
      s_off[e] = o;
      o += ((redc[0][e] + 127) >> 7) << 7;
    }
    s_off[CE] = o;
    *total_padded = o;
    int nt = o >> 7;
    for (int i = 0; i < nt; ++i) {
      int e = 0;
      while (e < CE - 1 && i * 128 >= s_off[e + 1]) e++;
      tile_e[i] = e;
    }
    float aux = 0.f;
    for (int e = 0; e < CE; ++e)
      aux += ((float)redc[0][e] / (float)(CT * CK)) * (redp[0][e] / (float)CT);
    aux_out[0] = aux * (float)CE;
  }
  if (tid < CE) s_cur[tid] = 0;
  ((short4*)zrow)[tid] = make_short4(0, 0, 0, 0);  // 256*4 = 1024 shorts
  __syncthreads();
  for (int i = tid; i < MAXROWS; i += 256) row_map[i] = -1;
  __syncthreads();
  // gather: assign rows within expert segments (LDS cursors)
  for (int idx = tid; idx < CT * CK; idx += 256) {
    int e = top_i[idx];
    int pos = s_off[e] + atomicAdd(&s_cur[e], 1);
    row_map[pos] = idx >> 1;
    row_of[idx] = pos;
  }
}

// Fused GEMM2-reduce + combine: per token, read only its 2 routed rows'
// partials, add b2[e], weight, residual.
__global__ __launch_bounds__(256) void combine_g2_kernel(
    const float* __restrict__ part, int partM, int nz,
    const float* __restrict__ b2, const int* __restrict__ tile_e,
    const int* __restrict__ row_of, const float* __restrict__ top_p,
    const float* __restrict__ x1, float* __restrict__ out) {
  int t = blockIdx.x;
  int c = threadIdx.x * 4;
  float4 r = *(const float4*)(x1 + (size_t)t * CD + c);
#pragma unroll
  for (int s = 0; s < CK; ++s) {
    int row = row_of[t * 2 + s];
    int e = tile_e[row >> 7];
    float w = top_p[t * 2 + s];
    float4 acc = *(const float4*)(part + (size_t)row * CD + c);
    for (int z = 1; z < nz; ++z) {
      float4 p = *(const float4*)(part + ((size_t)z * partM + row) * CD + c);
      acc.x += p.x; acc.y += p.y; acc.z += p.z; acc.w += p.w;
    }
    float4 bv = *(const float4*)(b2 + (size_t)e * CD + c);
    r.x += w * (acc.x + bv.x);
    r.y += w * (acc.y + bv.y);
    r.z += w * (acc.z + bv.z);
    r.w += w * (acc.w + bv.w);
  }
  *(float4*)(out + (size_t)t * CD + c) = r;
}

// ---------------------------------------------------------------------------
extern "C" void kernel_launch(void* const* d_in, const int* in_sizes, int n_in,
                              void* d_out, int out_size, void* d_ws,
                              size_t ws_size, hipStream_t stream) {
  const float* x   = (const float*)d_in[0];
  const float* n1w = (const float*)d_in[1];
  const float* n2w = (const float*)d_in[2];
  const float* wq  = (const float*)d_in[3];
  const float* bq  = (const float*)d_in[4];
  const float* wk  = (const float*)d_in[5];
  const float* bk  = (const float*)d_in[6];
  const float* wv  = (const float*)d_in[7];
  const float* bv  = (const float*)d_in[8];
  const float* wo  = (const float*)d_in[9];
  const float* bo  = (const float*)d_in[10];
  const float* wr  = (const float*)d_in[11];
  const float* br  = (const float*)d_in[12];
  const float* w1  = (const float*)d_in[13];
  const float* b1  = (const float*)d_in[14];
  const float* w2  = (const float*)d_in[15];
  const float* b2  = (const float*)d_in[16];
  float* out = (float*)d_out;

  char* base = (char*)d_ws;
  size_t off = 0;
  auto alloc = [&](size_t bytes) -> void* {
    void* p = base + off;
    off += (bytes + 255) & ~(size_t)255;
    return p;
  };
  float* f_x1   = (float*)alloc((size_t)CT * CD * 4);
  short* f_h2b  = (short*)alloc((size_t)CT * CD * 2);   // bf16 h2 (MoE input)
  short* f_hid  = (short*)alloc((size_t)MAXROWS * CF * 2);
  short* f_hh   = (short*)alloc((size_t)CT * CD * 2);
  short* f_hl   = (short*)alloc((size_t)CT * CD * 2);
  short* f_wqkvh = (short*)alloc((size_t)QKVP * CD * 2);
  short* f_wqkvl = (short*)alloc((size_t)QKVP * CD * 2);
  float* f_qkv  = (float*)alloc((size_t)CT * QKVP * 4);
  short* f_ctxh = (short*)alloc((size_t)CT * CD * 2);
  short* f_ctxl = (short*)alloc((size_t)CT * CD * 2);
  short* f_woth = (short*)alloc((size_t)CD * CD * 2);
  short* f_wotl = (short*)alloc((size_t)CD * CD * 2);
  float* f_bqkv = (float*)alloc(QKVP * 4);
  float* f_topp = (float*)alloc(CT * CK * 4);
  float* f_probs = (float*)alloc(CT * CE * 4);
  short* f_zrow = (short*)alloc(CD * 2);
  int* i_topi   = (int*)alloc(CT * CK * 4);
  int* i_rowof  = (int*)alloc(CT * CK * 4);
  int* i_rowmap = (int*)alloc(MAXROWS * 4);
  int* i_tile   = (int*)alloc(MAXTILES * 4);
  int* i_total  = (int*)alloc(4);
  // G (64MB): w1t -> w2t (sequential reuse)
  short* f_wG = (short*)alloc((size_t)CE * CD * CF * 2);
  short* f_w1t = f_wG;
  short* f_w2t = f_wG;
  // Rs (48MB): WO partials -> GEMM2 partials (disjoint)
  void* Rs = alloc((size_t)4 * MAXROWS * CD * 4);
  float* f_partwo = (float*)Rs;
  float* f_partg2 = (float*)Rs;

  dim3 b256(256);

  TPtrs tp;
  tp.w[0] = wq; tp.w[1] = wk; tp.w[2] = wv; tp.w[3] = wo;
  tp.hh[0] = f_wqkvh + 0 * (size_t)CD * CD;
  tp.hh[1] = f_wqkvh + 1 * (size_t)CD * CD;
  tp.hh[2] = f_wqkvh + 2 * (size_t)CD * CD;
  tp.hh[3] = f_woth;
  tp.ll[0] = f_wqkvl + 0 * (size_t)CD * CD;
  tp.ll[1] = f_wqkvl + 1 * (size_t)CD * CD;
  tp.ll[2] = f_wqkvl + 2 * (size_t)CD * CD;
  tp.ll[3] = f_wotl;
  tp.bq = bq; tp.bk = bk; tp.bv = bv; tp.bqkv = f_bqkv;
  tp.xin = x; tp.n1w = n1w; tp.hH = f_hh; tp.hL = f_hl;
  // z: 0-3 = wq/wk/wv/wo transposes, 4 = bias pack, 5 = rmsnorm1
  transpose4_kernel<<<dim3(16, 16, 6), b256, 0, stream>>>(tp);
  transpose_convert_kernel<<<dim3(CF / 64, CD / 64, CE), b256, 0, stream>>>(
      w1, f_w1t, nullptr, CD, CF);

  // ---- attention ----
  // QKV: BN=64 -> 384 blocks; bias fused, direct fp32 out
  mfma_gemm_kernel<1><<<dim3(QKVP / 64, CT / 128, 1), b256, 0, stream>>>(
      f_hh, f_hl, f_wqkvh, f_wqkvl, f_bqkv, f_qkv, nullptr, CT, QKVP, CD);
  fused_attn_kernel<<<dim3(512), b256, 0, stream>>>(f_qkv, f_ctxh, f_ctxl);
  // WO: BN=64, split-K=4 -> 512 blocks
  mfma_gemm_kernel<1><<<dim3(CD / 64, CT / 128, 4), b256, 0, stream>>>(
      f_ctxh, f_ctxl, f_woth, f_wotl, nullptr, nullptr, f_partwo, CT, CD, CD);
  attn_epilogue_kernel<<<CT, b256, 0, stream>>>(f_partwo, bo, x, n2w, wr, br,
                                                f_x1, f_h2b, i_topi, f_topp,
                                                f_probs);

  // ---- MoE ----
  finalize_kernel<<<1, 256, 0, stream>>>(i_topi, f_probs, i_tile, i_total,
                                         i_rowmap, i_rowof, f_zrow,
                                         out + (size_t)CT * CD);

  // expert GEMM1: BN=64 -> 3 blocks/CU; A gathered via row_map from bf16 h2
  moe_gemm_kernel<1, 1, 64><<<dim3(CF / 64, MAXTILES, 1), dim3(512), 0,
                              stream>>>(f_h2b, i_rowmap, f_zrow, f_w1t, b1,
                                        f_hid, nullptr, 0, CF, CD, i_tile,
                                        i_total);
  transpose_convert_kernel<<<dim3(CD / 64, CF / 64, CE), b256, 0, stream>>>(
      w2, f_w2t, nullptr, CF, CD);
  // expert GEMM2: BN=64, split-K=4 -> 3 blocks/CU
  moe_gemm_kernel<0, 0, 64><<<dim3(CD / 64, MAXTILES, 4), dim3(512), 0,
                              stream>>>(f_hid, nullptr, nullptr, f_w2t,
                                        nullptr, nullptr, f_partg2, MAXROWS,
                                        CD, CF, i_tile, i_total);
  combine_g2_kernel<<<CT, b256, 0, stream>>>(f_partg2, MAXROWS, 4, b2, i_tile,
                                             i_rowof, f_topp, f_x1, out);
}